// Round 1
// baseline (3191.915 us; speedup 1.0000x reference)
//
#include <hip/hip_runtime.h>

#define B_   16
#define T_   3000
#define N_   128
#define WIN_ 30
#define WN_  100
#define D_   64
#define HID_ 128
#define K_   32
#define G4_  512   // 4*HID_

// ---------------------------------------------------------------------------
// Kernel 1: SignalRep — conv1(1->32,k5,p2) relu, conv2(32->32,k5,p2) relu,
// mean over 30, proj 32->64.  One block per (b,w) window; 4 waves x 32 seqs.
// ---------------------------------------------------------------------------
__global__ __launch_bounds__(256) void conv_kernel(
    const float* __restrict__ x, const float* __restrict__ w1,
    const float* __restrict__ b1, const float* __restrict__ w2,
    const float* __restrict__ b2, const float* __restrict__ pw,
    const float* __restrict__ pb, float* __restrict__ Hs)
{
    __shared__ float xs[WIN_ * 130];      // stride 130 breaks bank-stride-0
    __shared__ float w1s[160];
    __shared__ float w2t[5120];           // [ci*5+k][co] transposed
    __shared__ float h1s[4 * 32 * 34];    // per-wave [32][34] zero-padded
    const int tid = threadIdx.x;
    const int win = blockIdx.x;           // b*WN_ + w
    const int b = win / WN_, w = win - b * WN_;
    const float* xb = x + ((size_t)b * T_ + (size_t)w * WIN_) * N_;
    for (int i = tid; i < WIN_ * N_; i += 256) {
        int l = i >> 7, n = i & 127;
        xs[l * 130 + n] = xb[i];
    }
    for (int i = tid; i < 160; i += 256) w1s[i] = w1[i];
    for (int i = tid; i < 5120; i += 256) {
        int co = i / 160, r = i - co * 160;
        w2t[r * 32 + co] = w2[i];
    }
    const int lane = tid & 63, wid = tid >> 6;
    float* h1 = h1s + wid * (32 * 34);
    for (int i = lane; i < 128; i += 64) {          // zero pads 0,1,32,33
        int c = i >> 2, p = i & 3;
        h1[c * 34 + ((p < 2) ? p : (p + 30))] = 0.f;
    }
    __syncthreads();
    const int co = lane & 31, half = lane >> 5, t0 = half * 15;
    const float b2c = b2[co];
    for (int i = 0; i < 32; i++) {
        const int n = wid * 32 + i;
        // conv1: lanes cover (c,t) pairs, 960 = 15*64
        for (int it = 0; it < 15; it++) {
            int idx = lane + 64 * it;
            int c = idx / 30, t = idx - c * 30;
            float s = b1[c];
            #pragma unroll
            for (int k = 0; k < 5; k++) {
                int p = t + k - 2;
                float xv = ((unsigned)p < (unsigned)WIN_) ? xs[p * 130 + n] : 0.f;
                s += xv * w1s[c * 5 + k];
            }
            h1[c * 34 + 2 + t] = fmaxf(s, 0.f);
        }
        __builtin_amdgcn_wave_barrier();
        // conv2 + relu + mean: lane = (co, t-half); register-blocked
        float s2[15];
        #pragma unroll
        for (int tt = 0; tt < 15; tt++) s2[tt] = b2c;
        for (int ci = 0; ci < 32; ci++) {
            float hv[19];
            #pragma unroll
            for (int u = 0; u < 19; u++) hv[u] = h1[ci * 34 + t0 + u];
            #pragma unroll
            for (int k = 0; k < 5; k++) {
                float wv = w2t[(ci * 5 + k) * 32 + co];
                #pragma unroll
                for (int tt = 0; tt < 15; tt++) s2[tt] += hv[tt + k] * wv;
            }
        }
        float acc = 0.f;
        #pragma unroll
        for (int tt = 0; tt < 15; tt++) acc += fmaxf(s2[tt], 0.f);
        acc += __shfl_down(acc, 32);
        float m2 = acc * (1.f / 30.f);   // valid in lanes 0..31 (lane==co)
        // proj 32->64: lane j = output dim
        float o = pb[lane];
        for (int c = 0; c < 32; c++) {
            float mc = __shfl(m2, c);
            o += mc * pw[c * 64 + lane];
        }
        Hs[((size_t)win * N_ + n) * D_ + lane] = o;
        __builtin_amdgcn_wave_barrier();
    }
}

// ---------------------------------------------------------------------------
// Kernel 2: S = softmax_k(Hs @ proto^T). One 32-lane group per (b,w,n).
// ---------------------------------------------------------------------------
__global__ __launch_bounds__(256) void s_kernel(
    const float* __restrict__ Hs, const float* __restrict__ proto,
    float* __restrict__ S)
{
    const int tid = threadIdx.x;
    const int lane = tid & 63;
    const int gw = blockIdx.x * 4 + (tid >> 6);
    const int sub = lane >> 5, kk = lane & 31;
    const size_t nid = (size_t)gw * 2 + sub;          // 0..204799
    const float4* h4 = (const float4*)(Hs + nid * D_);
    const float4* p4 = (const float4*)(proto + (size_t)kk * D_);
    float l = 0.f;
    #pragma unroll
    for (int d = 0; d < D_ / 4; d++) {
        float4 a = h4[d], q = p4[d];
        l += a.x * q.x + a.y * q.y + a.z * q.z + a.w * q.w;
    }
    float m = l;
    for (int off = 16; off; off >>= 1) m = fmaxf(m, __shfl_xor(m, off));
    float e = expf(l - m);
    float s = e;
    for (int off = 16; off; off >>= 1) s += __shfl_xor(s, off);
    S[nid * K_ + kk] = e / s;
}

// ---------------------------------------------------------------------------
// Kernel 3: per-window corr -> AS -> Ac -> symmetrize+I -> D^-1/2 norm -> An
// One block per (b,w). A_seq never materialized in HBM.
// ---------------------------------------------------------------------------
__global__ __launch_bounds__(256) void corr_kernel(
    const float* __restrict__ x, const float* __restrict__ S,
    float* __restrict__ An)
{
    __shared__ float xs[WIN_ * N_];       // centered
    __shared__ float sinv[N_];
    __shared__ float Ss[N_ * K_];
    __shared__ float ASs[N_ * K_];
    __shared__ float Arow[4][N_];
    __shared__ float Acs[K_][K_ + 1];
    __shared__ float dinv[K_];
    const int tid = threadIdx.x;
    const int win = blockIdx.x;
    const int b = win / WN_, w = win - b * WN_;
    const float* xb = x + ((size_t)b * T_ + (size_t)w * WIN_) * N_;
    for (int i = tid; i < WIN_ * N_; i += 256) xs[i] = xb[i];
    for (int i = tid; i < N_ * K_; i += 256) Ss[i] = S[(size_t)win * N_ * K_ + i];
    __syncthreads();
    if (tid < N_) {
        int n = tid;
        float mean = 0.f;
        for (int l = 0; l < WIN_; l++) mean += xs[l * N_ + n];
        mean *= (1.f / WIN_);
        float var = 0.f;
        for (int l = 0; l < WIN_; l++) {
            float v = xs[l * N_ + n] - mean;
            xs[l * N_ + n] = v;
            var += v * v;
        }
        var *= (1.f / (WIN_ - 1 + 1e-8f));
        sinv[n] = rsqrtf(fmaxf(var, 1e-8f));
    }
    __syncthreads();
    const int lane = tid & 63, wid = tid >> 6;
    const int l32 = lane & 31, hf = lane >> 5;
    for (int n = wid; n < N_; n += 4) {
        float sn = sinv[n];
        #pragma unroll
        for (int mm = 0; mm < 2; mm++) {
            int m = lane + 64 * mm;
            float cov = 0.f;
            for (int l = 0; l < WIN_; l++) cov += xs[l * N_ + n] * xs[l * N_ + m];
            float a = cov * (1.f / (WIN_ - 1 + 1e-8f)) * sn * sinv[m];
            Arow[wid][m] = (m == n) ? 1.f : a;
        }
        __builtin_amdgcn_wave_barrier();
        float p = 0.f;
        for (int m = hf * 64; m < hf * 64 + 64; m++)
            p += Arow[wid][m] * Ss[m * K_ + l32];
        p += __shfl_down(p, 32);
        if (hf == 0) ASs[n * K_ + l32] = p;
        __builtin_amdgcn_wave_barrier();
    }
    __syncthreads();
    {   // Ac[k][l] = sum_n Ss[n][k] * ASs[n][l]
        int l = tid & 31, kb = tid >> 5;
        for (int r = 0; r < 4; r++) {
            int k = kb + 8 * r;
            float acc = 0.f;
            for (int n = 0; n < N_; n++) acc += Ss[n * K_ + k] * ASs[n * K_ + l];
            Acs[k][l] = acc;
        }
    }
    __syncthreads();
    float symv[4];
    {
        int l = tid & 31, kb = tid >> 5;
        for (int r = 0; r < 4; r++) {
            int k = kb + 8 * r;
            symv[r] = 0.5f * (Acs[k][l] + Acs[l][k]) + ((k == l) ? 1.f : 0.f);
        }
    }
    __syncthreads();
    {
        int l = tid & 31, kb = tid >> 5;
        for (int r = 0; r < 4; r++) Acs[kb + 8 * r][l] = symv[r];
    }
    __syncthreads();
    if (tid < K_) {
        float s = 0.f;
        for (int l = 0; l < K_; l++) s += Acs[tid][l];
        dinv[tid] = rsqrtf(fmaxf(s, 1e-8f));
    }
    __syncthreads();
    float* Anw = An + (size_t)win * K_ * K_;
    for (int i = tid; i < K_ * K_; i += 256) {
        int k = i >> 5, l = i & 31;
        Anw[i] = dinv[k] * Acs[k][l] * dinv[l];
    }
}

// ---------------------------------------------------------------------------
// Kernel 4: Xc[k][d] = sum_n S[n][k] * Hs[n][d], per window.
// ---------------------------------------------------------------------------
__global__ __launch_bounds__(256) void xc_kernel(
    const float* __restrict__ S, const float* __restrict__ Hs,
    float* __restrict__ Xc)
{
    __shared__ float Ss[N_ * K_];
    __shared__ float Hss[N_ * D_];
    const int tid = threadIdx.x;
    const int win = blockIdx.x;
    for (int i = tid; i < N_ * K_; i += 256) Ss[i] = S[(size_t)win * N_ * K_ + i];
    for (int i = tid; i < N_ * D_; i += 256) Hss[i] = Hs[(size_t)win * N_ * D_ + i];
    __syncthreads();
    const int dd = tid & 63, kb = tid >> 6;
    for (int r = 0; r < 8; r++) {
        int k = r * 4 + kb;
        float acc = 0.f;
        for (int n = 0; n < N_; n++) acc += Ss[n * K_ + k] * Hss[n * D_ + dd];
        Xc[((size_t)win * K_ + k) * D_ + dd] = acc;
    }
}

// ---------------------------------------------------------------------------
// Kernel 5: Hs mean over nodes -> Hsm[b,w,d]
// ---------------------------------------------------------------------------
__global__ __launch_bounds__(64) void hsmean_kernel(
    const float* __restrict__ Hs, float* __restrict__ Hsm)
{
    const int win = blockIdx.x, dd = threadIdx.x;
    float acc = 0.f;
    for (int n = 0; n < N_; n++) acc += Hs[((size_t)win * N_ + n) * D_ + dd];
    Hsm[(size_t)win * D_ + dd] = acc * (1.f / N_);
}

// ---------------------------------------------------------------------------
// Kernel 6: one GCLSTM step.  Grid = 16 b x 16 h-chunks (8 h each).
// g = A @ (X Wx + Hp Wh + b); LSTM gate update; writes Hn, C, k-mean of Hn.
// ---------------------------------------------------------------------------
__global__ __launch_bounds__(256) void step_kernel(
    const float* __restrict__ An, const float* __restrict__ Xc,
    const float* __restrict__ Wx, const float* __restrict__ bx,
    const float* __restrict__ Wh, const float* __restrict__ bh,
    const float* __restrict__ H, const float* __restrict__ H2,
    float* __restrict__ Hn, float* __restrict__ C,
    float* __restrict__ Hsqm, int t)
{
    __shared__ float A_s[K_ * 33];        // padded
    __shared__ float X_s[K_ * 65];        // padded
    __shared__ float Hp_s[K_ * 129];      // padded
    __shared__ float Wxs[D_ * 32];
    __shared__ float Whs[HID_ * 32];
    __shared__ float bs[32];
    __shared__ float tmp[K_ * 32];
    __shared__ float gs[K_ * 32];
    __shared__ float red[K_][8];
    const int tid = threadIdx.x;
    const int b = blockIdx.x >> 4;
    const int hc = blockIdx.x & 15;
    const int h0 = hc * 8;
    const float* Anb = An + ((size_t)b * WN_ + t) * K_ * K_;
    const float* Xb  = Xc + ((size_t)b * WN_ + t) * K_ * D_;
    for (int i = tid; i < K_ * K_; i += 256) A_s[(i >> 5) * 33 + (i & 31)] = Anb[i];
    for (int i = tid; i < K_ * D_; i += 256) X_s[(i >> 6) * 65 + (i & 63)] = Xb[i];
    const float coef = (t == 0) ? 1.f : 2.f;
    const float dn = (t == 0) ? 1.f : ((t == 1) ? 0.5f : (1.f / 3.f));
    const float* Hb  = H  + (size_t)b * K_ * HID_;
    const float* H2b = H2 + (size_t)b * K_ * HID_;
    for (int i = tid; i < K_ * HID_; i += 256)
        Hp_s[(i >> 7) * 129 + (i & 127)] = (coef * Hb[i] + H2b[i]) * dn;
    for (int i = tid; i < D_ * 32; i += 256) {
        int d = i >> 5, jj = i & 31;
        int jg = (jj >> 3) * HID_ + h0 + (jj & 7);
        Wxs[i] = Wx[d * G4_ + jg];
    }
    for (int i = tid; i < HID_ * 32; i += 256) {
        int h = i >> 5, jj = i & 31;
        int jg = (jj >> 3) * HID_ + h0 + (jj & 7);
        Whs[i] = Wh[h * G4_ + jg];
    }
    if (tid < 32) {
        int jg = (tid >> 3) * HID_ + h0 + (tid & 7);
        bs[tid] = bx[jg] + bh[jg];
    }
    __syncthreads();
    {   // tmp[m][jj] = b + X[m]@Wx + Hp[m]@Wh ; thread = (m, jq of 4 j)
        const int jq = tid & 7, m = tid >> 3;
        float4 acc = make_float4(bs[jq * 4], bs[jq * 4 + 1],
                                 bs[jq * 4 + 2], bs[jq * 4 + 3]);
        const float4* Wx4 = (const float4*)Wxs;
        const float4* Wh4 = (const float4*)Whs;
        for (int d = 0; d < D_; d++) {
            float xv = X_s[m * 65 + d];
            float4 wv = Wx4[d * 8 + jq];
            acc.x += xv * wv.x; acc.y += xv * wv.y;
            acc.z += xv * wv.z; acc.w += xv * wv.w;
        }
        for (int h = 0; h < HID_; h++) {
            float hv = Hp_s[m * 129 + h];
            float4 wv = Wh4[h * 8 + jq];
            acc.x += hv * wv.x; acc.y += hv * wv.y;
            acc.z += hv * wv.z; acc.w += hv * wv.w;
        }
        ((float4*)tmp)[m * 8 + jq] = acc;
    }
    __syncthreads();
    {   // g[k][jj] = sum_m A[k][m] tmp[m][jj]
        const int jq = tid & 7, k = tid >> 3;
        float4 acc = make_float4(0.f, 0.f, 0.f, 0.f);
        const float4* t4 = (const float4*)tmp;
        for (int m = 0; m < K_; m++) {
            float av = A_s[k * 33 + m];
            float4 tv = t4[m * 8 + jq];
            acc.x += av * tv.x; acc.y += av * tv.y;
            acc.z += av * tv.z; acc.w += av * tv.w;
        }
        ((float4*)gs)[k * 8 + jq] = acc;
    }
    __syncthreads();
    {   // LSTM update for (k, hh)
        const int hh = tid & 7, k = tid >> 3;
        float gi = gs[k * 32 + hh];
        float gf = gs[k * 32 + 8 + hh];
        float go = gs[k * 32 + 16 + hh];
        float gc = gs[k * 32 + 24 + hh];
        size_t off = (size_t)b * K_ * HID_ + (size_t)k * HID_ + h0 + hh;
        float c_old = C[off];
        float si = 1.f / (1.f + expf(-gi));
        float sf = 1.f / (1.f + expf(-gf));
        float so = 1.f / (1.f + expf(-go));
        float cn = sf * c_old + si * tanhf(gc);
        float hn = so * tanhf(cn);
        C[off] = cn;
        Hn[off] = hn;
        red[k][hh] = hn;
    }
    __syncthreads();
    if (tid < 8) {
        float s = 0.f;
        for (int k = 0; k < K_; k++) s += red[k][tid];
        Hsqm[((size_t)b * WN_ + t) * HID_ + h0 + tid] = s * (1.f / K_);
    }
}

// ---------------------------------------------------------------------------
// Kernel 7: temporal attention pooling + classifier.  One block per b.
// ---------------------------------------------------------------------------
__global__ __launch_bounds__(128) void final_kernel(
    const float* __restrict__ Hsqm, const float* __restrict__ Hsm,
    const float* __restrict__ q_t, const float* __restrict__ q_s,
    const float* __restrict__ cls_w, const float* __restrict__ cls_b,
    float* __restrict__ out)
{
    __shared__ float red[128];
    __shared__ float sc[WN_];
    __shared__ float wt[WN_];
    __shared__ float smv;
    const int b = blockIdx.x, tid = threadIdx.x;
    // ||q_t||
    float v = q_t[tid];
    red[tid] = v * v;
    __syncthreads();
    for (int off = 64; off; off >>= 1) {
        if (tid < off) red[tid] += red[tid + off];
        __syncthreads();
    }
    const float qtn = sqrtf(red[0]) + 1e-8f;
    __syncthreads();
    // ||q_s||
    float v2 = (tid < D_) ? q_s[tid] : 0.f;
    red[tid] = v2 * v2;
    __syncthreads();
    for (int off = 64; off; off >>= 1) {
        if (tid < off) red[tid] += red[tid + off];
        __syncthreads();
    }
    const float qsn = sqrtf(red[0]) + 1e-8f;
    __syncthreads();
    // graph branch
    if (tid < WN_) {
        float s = 0.f;
        const float* zr = Hsqm + ((size_t)b * WN_ + tid) * HID_;
        for (int h = 0; h < HID_; h++) s += zr[h] * q_t[h];
        sc[tid] = s / qtn;
    }
    __syncthreads();
    if (tid == 0) {
        float m = sc[0];
        for (int i = 1; i < WN_; i++) m = fmaxf(m, sc[i]);
        float s = 0.f;
        for (int i = 0; i < WN_; i++) { wt[i] = expf(sc[i] - m); s += wt[i]; }
        smv = 1.f / s;
    }
    __syncthreads();
    float part = 0.f;
    {
        float z = 0.f;
        for (int w = 0; w < WN_; w++)
            z += wt[w] * Hsqm[((size_t)b * WN_ + w) * HID_ + tid];
        part += z * smv * cls_w[tid];
    }
    __syncthreads();
    // signal branch
    if (tid < WN_) {
        float s = 0.f;
        const float* zr = Hsm + ((size_t)b * WN_ + tid) * D_;
        for (int dd = 0; dd < D_; dd++) s += zr[dd] * q_s[dd];
        sc[tid] = s / qsn;
    }
    __syncthreads();
    if (tid == 0) {
        float m = sc[0];
        for (int i = 1; i < WN_; i++) m = fmaxf(m, sc[i]);
        float s = 0.f;
        for (int i = 0; i < WN_; i++) { wt[i] = expf(sc[i] - m); s += wt[i]; }
        smv = 1.f / s;
    }
    __syncthreads();
    if (tid < D_) {
        float z = 0.f;
        for (int w = 0; w < WN_; w++)
            z += wt[w] * Hsm[((size_t)b * WN_ + w) * D_ + tid];
        part += z * smv * cls_w[HID_ + tid];
    }
    red[tid] = part;
    __syncthreads();
    for (int off = 64; off; off >>= 1) {
        if (tid < off) red[tid] += red[tid + off];
        __syncthreads();
    }
    if (tid == 0) out[b] = 1.f / (1.f + expf(-(red[0] + cls_b[0])));
}

// ---------------------------------------------------------------------------
extern "C" void kernel_launch(void* const* d_in, const int* in_sizes, int n_in,
                              void* d_out, int out_size, void* d_ws, size_t ws_size,
                              hipStream_t stream)
{
    (void)in_sizes; (void)n_in; (void)out_size; (void)ws_size;
    const float* x     = (const float*)d_in[0];
    const float* w1    = (const float*)d_in[1];
    const float* b1    = (const float*)d_in[2];
    const float* w2    = (const float*)d_in[3];
    const float* b2    = (const float*)d_in[4];
    const float* pw    = (const float*)d_in[5];
    const float* pb    = (const float*)d_in[6];
    const float* proto = (const float*)d_in[7];
    const float* Wx    = (const float*)d_in[8];
    const float* bx    = (const float*)d_in[9];
    const float* Wh    = (const float*)d_in[10];
    const float* bh    = (const float*)d_in[11];
    const float* q_t   = (const float*)d_in[12];
    const float* q_s   = (const float*)d_in[13];
    const float* clw   = (const float*)d_in[14];
    const float* clb   = (const float*)d_in[15];

    float* ws   = (float*)d_ws;
    float* Hs   = ws;                        // 16*100*128*64 = 13107200
    float* S    = Hs   + 13107200;           // 16*100*128*32 =  6553600
    float* An   = S    + 6553600;            // 16*100*32*32  =  1638400
    float* Xc   = An   + 1638400;            // 16*100*32*64  =  3276800
    float* Hsm  = Xc   + 3276800;            // 16*100*64     =   102400
    float* Hsqm = Hsm  + 102400;             // 16*100*128    =   204800
    float* Hb0  = Hsqm + 204800;             // 16*32*128     =    65536
    float* Hb1  = Hb0  + 65536;
    float* Cb   = Hb1  + 65536;              // total 25,079,808 floats (~95.7 MiB)

    conv_kernel<<<B_ * WN_, 256, 0, stream>>>(x, w1, b1, w2, b2, pw, pb, Hs);
    s_kernel<<<(B_ * WN_ * N_) / 8, 256, 0, stream>>>(Hs, proto, S);
    corr_kernel<<<B_ * WN_, 256, 0, stream>>>(x, S, An);
    xc_kernel<<<B_ * WN_, 256, 0, stream>>>(S, Hs, Xc);
    hsmean_kernel<<<B_ * WN_, 64, 0, stream>>>(Hs, Hsm);

    hipMemsetAsync(Hb0, 0, (size_t)3 * 65536 * sizeof(float), stream);

    for (int t = 0; t < WN_; t++) {
        const float* Hc = (t & 1) ? Hb0 : Hb1;   // H_{t-1}
        const float* Ho = (t & 1) ? Hb1 : Hb0;   // H_{t-2}
        float*       Hw = (t & 1) ? Hb1 : Hb0;   // write H_t
        step_kernel<<<B_ * 16, 256, 0, stream>>>(An, Xc, Wx, bx, Wh, bh,
                                                 Hc, Ho, Hw, Cb, Hsqm, t);
    }
    final_kernel<<<B_, 128, 0, stream>>>(Hsqm, Hsm, q_t, q_s, clw, clb,
                                         (float*)d_out);
}

// Round 2
// 2997.369 us; speedup vs baseline: 1.0649x; 1.0649x over previous
//
#include <hip/hip_runtime.h>

#define B_   16
#define T_   3000
#define N_   128
#define WIN_ 30
#define WN_  100
#define D_   64
#define HID_ 128
#define K_   32
#define G4_  512   // 4*HID_

typedef __attribute__((ext_vector_type(8))) short short8;
typedef __attribute__((ext_vector_type(4))) float floatx4;

__device__ __forceinline__ unsigned short f2bf(float f) {
    unsigned u = __float_as_uint(f);
    u += 0x7fffu + ((u >> 16) & 1u);
    return (unsigned short)(u >> 16);
}
__device__ __forceinline__ float bf2f(unsigned short h) {
    return __uint_as_float(((unsigned)h) << 16);
}
__device__ __forceinline__ float sigf(float x) { return 1.f / (1.f + __expf(-x)); }
__device__ __forceinline__ float tanhfast(float x) { return 2.f / (1.f + __expf(-2.f * x)) - 1.f; }

// ---------------------------------------------------------------------------
// Kernel 1: SignalRep — conv1, conv2, mean, proj.  One block per window,
// 4 waves x 32 seqs.  conv1: lane=(c,t-half), weights in regs.  conv2: h1
// broadcast float4 reads, padded w2 float4 layout.  Hs stored bf16.
// ---------------------------------------------------------------------------
__global__ __launch_bounds__(256) void conv_kernel(
    const float* __restrict__ x, const float* __restrict__ w1,
    const float* __restrict__ b1, const float* __restrict__ w2,
    const float* __restrict__ b2, const float* __restrict__ pw,
    const float* __restrict__ pb, unsigned short* __restrict__ Hs)
{
    __shared__ __align__(16) float xs_t[N_ * 33];      // [n][l]
    __shared__ __align__(16) float w2p4[32 * 33 * 4];  // [co][ci][k0..3]
    __shared__ float w2k4[32 * 33];                    // [co][ci] k=4
    __shared__ float w1s[160];
    __shared__ __align__(16) float h1s[4][32 * 36];    // per-wave [c][2+30+4]
    const int tid = threadIdx.x;
    const int win = blockIdx.x;
    const int b = win / WN_, w = win - b * WN_;
    const float* xb = x + ((size_t)b * T_ + (size_t)w * WIN_) * N_;
    for (int i = tid; i < WIN_ * N_; i += 256) {
        int l = i >> 7, n = i & 127;
        xs_t[n * 33 + l] = xb[i];
    }
    for (int i = tid; i < 5120; i += 256) {
        int co = i / 160, r = i - co * 160, ci = r / 5, k = r - ci * 5;
        if (k < 4) w2p4[(co * 33 + ci) * 4 + k] = w2[i];
        else       w2k4[co * 33 + ci] = w2[i];
    }
    for (int i = tid; i < 160; i += 256) w1s[i] = w1[i];
    const int lane = tid & 63, wid = tid >> 6;
    float* h1 = h1s[wid];
    for (int j = lane; j < 192; j += 64) {   // zero pads s in {0,1,32..35}
        int c = j / 6, pp = j % 6;
        int s = (pp < 2) ? pp : (30 + pp);
        h1[c * 36 + s] = 0.f;
    }
    __syncthreads();
    const int c1 = lane & 31, th1 = lane >> 5;
    float w1r[5];
    #pragma unroll
    for (int k = 0; k < 5; k++) w1r[k] = w1s[c1 * 5 + k];
    const float b1c = b1[c1];
    const int co = lane & 31, th2 = lane >> 5;
    const int s0 = th2 * 16;
    const int cnt = th2 ? 14 : 16;
    const float b2c = b2[co];
    const float pbv = pb[lane];

    for (int i = 0; i < 32; i++) {
        const int n = wid * 32 + i;
        // ---- conv1: lane (c1, th1) computes t = th1*15 + tt ----
        float xv[19];
        #pragma unroll
        for (int u = 0; u < 19; u++) {
            int p = th1 * 15 - 2 + u;
            xv[u] = ((unsigned)p < 30u) ? xs_t[n * 33 + p] : 0.f;
        }
        #pragma unroll
        for (int tt = 0; tt < 15; tt++) {
            float s = b1c;
            #pragma unroll
            for (int k = 0; k < 5; k++) s += xv[tt + k] * w1r[k];
            h1[c1 * 36 + 2 + th1 * 15 + tt] = fmaxf(s, 0.f);
        }
        __builtin_amdgcn_wave_barrier();
        // ---- conv2 + relu + mean ----
        float s2[16];
        #pragma unroll
        for (int tt = 0; tt < 16; tt++) s2[tt] = b2c;
        #pragma unroll 2
        for (int ci = 0; ci < 32; ci++) {
            float hv[20];
            const float4* hp = (const float4*)&h1[ci * 36 + s0];
            #pragma unroll
            for (int q = 0; q < 5; q++) {
                float4 t4 = hp[q];
                hv[q * 4 + 0] = t4.x; hv[q * 4 + 1] = t4.y;
                hv[q * 4 + 2] = t4.z; hv[q * 4 + 3] = t4.w;
            }
            float4 wv = *(const float4*)&w2p4[(co * 33 + ci) * 4];
            float w4 = w2k4[co * 33 + ci];
            #pragma unroll
            for (int tt = 0; tt < 16; tt++) {
                s2[tt] += hv[tt + 0] * wv.x + hv[tt + 1] * wv.y
                        + hv[tt + 2] * wv.z + hv[tt + 3] * wv.w
                        + hv[tt + 4] * w4;
            }
        }
        float acc = 0.f;
        #pragma unroll
        for (int tt = 0; tt < 16; tt++)
            if (tt < cnt) acc += fmaxf(s2[tt], 0.f);
        acc += __shfl_down(acc, 32);
        float m2 = acc * (1.f / 30.f);    // valid lanes 0..31
        float o = pbv;
        #pragma unroll 8
        for (int c = 0; c < 32; c++) o += __shfl(m2, c) * pw[c * 64 + lane];
        Hs[((size_t)win * N_ + n) * D_ + lane] = f2bf(o);
        __builtin_amdgcn_wave_barrier();
    }
}

// ---------------------------------------------------------------------------
// Kernel 2: S = softmax_k(Hs @ proto^T). One 32-lane group per (b,w,n).
// ---------------------------------------------------------------------------
__global__ __launch_bounds__(256) void s_kernel(
    const unsigned short* __restrict__ Hs, const float* __restrict__ proto,
    float* __restrict__ S)
{
    const int tid = threadIdx.x;
    const int lane = tid & 63;
    const int gw = blockIdx.x * 4 + (tid >> 6);
    const int sub = lane >> 5, kk = lane & 31;
    const size_t nid = (size_t)gw * 2 + sub;
    const unsigned short* h = Hs + nid * D_;
    const float* p = proto + (size_t)kk * D_;
    float l = 0.f;
    #pragma unroll
    for (int d = 0; d < D_; d++) l += bf2f(h[d]) * p[d];
    float m = l;
    for (int off = 16; off; off >>= 1) m = fmaxf(m, __shfl_xor(m, off));
    float e = expf(l - m);
    float s = e;
    for (int off = 16; off; off >>= 1) s += __shfl_xor(s, off);
    S[nid * K_ + kk] = e / s;
}

// ---------------------------------------------------------------------------
// Kernel 3: corr -> AS -> Ac -> normalize -> An (bf16 out)
// ---------------------------------------------------------------------------
__global__ __launch_bounds__(256) void corr_kernel(
    const float* __restrict__ x, const float* __restrict__ S,
    unsigned short* __restrict__ An)
{
    __shared__ float xs[WIN_ * N_];
    __shared__ float sinv[N_];
    __shared__ float Ss[N_ * K_];
    __shared__ float ASs[N_ * K_];
    __shared__ float Arow[4][N_];
    __shared__ float Acs[K_][K_ + 1];
    __shared__ float dinv[K_];
    const int tid = threadIdx.x;
    const int win = blockIdx.x;
    const int b = win / WN_, w = win - b * WN_;
    const float* xb = x + ((size_t)b * T_ + (size_t)w * WIN_) * N_;
    for (int i = tid; i < WIN_ * N_; i += 256) xs[i] = xb[i];
    for (int i = tid; i < N_ * K_; i += 256) Ss[i] = S[(size_t)win * N_ * K_ + i];
    __syncthreads();
    if (tid < N_) {
        int n = tid;
        float mean = 0.f;
        for (int l = 0; l < WIN_; l++) mean += xs[l * N_ + n];
        mean *= (1.f / WIN_);
        float var = 0.f;
        for (int l = 0; l < WIN_; l++) {
            float v = xs[l * N_ + n] - mean;
            xs[l * N_ + n] = v;
            var += v * v;
        }
        var *= (1.f / (WIN_ - 1 + 1e-8f));
        sinv[n] = rsqrtf(fmaxf(var, 1e-8f));
    }
    __syncthreads();
    const int lane = tid & 63, wid = tid >> 6;
    const int l32 = lane & 31, hf = lane >> 5;
    for (int n = wid; n < N_; n += 4) {
        float sn = sinv[n];
        #pragma unroll
        for (int mm = 0; mm < 2; mm++) {
            int m = lane + 64 * mm;
            float cov = 0.f;
            for (int l = 0; l < WIN_; l++) cov += xs[l * N_ + n] * xs[l * N_ + m];
            float a = cov * (1.f / (WIN_ - 1 + 1e-8f)) * sn * sinv[m];
            Arow[wid][m] = (m == n) ? 1.f : a;
        }
        __builtin_amdgcn_wave_barrier();
        float p = 0.f;
        for (int m = hf * 64; m < hf * 64 + 64; m++)
            p += Arow[wid][m] * Ss[m * K_ + l32];
        p += __shfl_down(p, 32);
        if (hf == 0) ASs[n * K_ + l32] = p;
        __builtin_amdgcn_wave_barrier();
    }
    __syncthreads();
    {
        int l = tid & 31, kb = tid >> 5;
        for (int r = 0; r < 4; r++) {
            int k = kb + 8 * r;
            float acc = 0.f;
            for (int n = 0; n < N_; n++) acc += Ss[n * K_ + k] * ASs[n * K_ + l];
            Acs[k][l] = acc;
        }
    }
    __syncthreads();
    float symv[4];
    {
        int l = tid & 31, kb = tid >> 5;
        for (int r = 0; r < 4; r++) {
            int k = kb + 8 * r;
            symv[r] = 0.5f * (Acs[k][l] + Acs[l][k]) + ((k == l) ? 1.f : 0.f);
        }
    }
    __syncthreads();
    {
        int l = tid & 31, kb = tid >> 5;
        for (int r = 0; r < 4; r++) Acs[kb + 8 * r][l] = symv[r];
    }
    __syncthreads();
    if (tid < K_) {
        float s = 0.f;
        for (int l = 0; l < K_; l++) s += Acs[tid][l];
        dinv[tid] = rsqrtf(fmaxf(s, 1e-8f));
    }
    __syncthreads();
    unsigned short* Anw = An + (size_t)win * K_ * K_;
    for (int i = tid; i < K_ * K_; i += 256) {
        int k = i >> 5, l = i & 31;
        Anw[i] = f2bf(dinv[k] * Acs[k][l] * dinv[l]);
    }
}

// ---------------------------------------------------------------------------
// Kernel 4: Xc[k][d] = sum_n S[n][k] * Hs[n][d], per window (fp32 out).
// ---------------------------------------------------------------------------
__global__ __launch_bounds__(256) void xc_kernel(
    const float* __restrict__ S, const unsigned short* __restrict__ Hs,
    float* __restrict__ Xc)
{
    __shared__ float Ss[N_ * K_];
    __shared__ float Hss[N_ * D_];
    const int tid = threadIdx.x;
    const int win = blockIdx.x;
    for (int i = tid; i < N_ * K_; i += 256) Ss[i] = S[(size_t)win * N_ * K_ + i];
    for (int i = tid; i < N_ * D_; i += 256) Hss[i] = bf2f(Hs[(size_t)win * N_ * D_ + i]);
    __syncthreads();
    const int dd = tid & 63, kb = tid >> 6;
    for (int r = 0; r < 8; r++) {
        int k = r * 4 + kb;
        float acc = 0.f;
        for (int n = 0; n < N_; n++) acc += Ss[n * K_ + k] * Hss[n * D_ + dd];
        Xc[((size_t)win * K_ + k) * D_ + dd] = acc;
    }
}

// ---------------------------------------------------------------------------
// Kernel 5: Hs mean over nodes -> Hsm[b,w,d] (fp32)
// ---------------------------------------------------------------------------
__global__ __launch_bounds__(64) void hsmean_kernel(
    const unsigned short* __restrict__ Hs, float* __restrict__ Hsm)
{
    const int win = blockIdx.x, dd = threadIdx.x;
    float acc = 0.f;
    for (int n = 0; n < N_; n++) acc += bf2f(Hs[((size_t)win * N_ + n) * D_ + dd]);
    Hsm[(size_t)win * D_ + dd] = acc * (1.f / N_);
}

// ---------------------------------------------------------------------------
// Kernel 6: Wh -> permuted transposed split-bf16  WhT[jj][h], jj = hcol*4+gate
// ---------------------------------------------------------------------------
__global__ __launch_bounds__(256) void whprep_kernel(
    const float* __restrict__ Wh, unsigned short* __restrict__ WhT_hi,
    unsigned short* __restrict__ WhT_lo)
{
    int i = blockIdx.x * 256 + threadIdx.x;   // 65536
    int jj = i >> 7, h = i & 127;
    int jg = (jj & 3) * HID_ + (jj >> 2);
    float v = Wh[h * G4_ + jg];
    unsigned short hi = f2bf(v);
    WhT_hi[i] = hi;
    WhT_lo[i] = f2bf(v - bf2f(hi));
}

// ---------------------------------------------------------------------------
// Kernel 7: XWx[b,t,c,jj] = (Xc @ Wx + bx + bh)[jg(jj)], bf16.  1 blk/window.
// ---------------------------------------------------------------------------
__global__ __launch_bounds__(256) void xwx_kernel(
    const float* __restrict__ Xc, const float* __restrict__ Wx,
    const float* __restrict__ bx, const float* __restrict__ bh,
    unsigned short* __restrict__ XWx)
{
    __shared__ __align__(16) float Xs[32 * 68];
    __shared__ __align__(16) float Wxs[64 * 132];
    __shared__ float bs[128];
    const int tid = threadIdx.x;
    const int win = blockIdx.x;
    for (int i = tid; i < 2048; i += 256) {
        int c = i >> 6, d = i & 63;
        Xs[c * 68 + d] = Xc[(size_t)win * 2048 + i];
    }
    const int c = tid >> 3, jq = tid & 7;
    for (int chunk = 0; chunk < 4; chunk++) {
        __syncthreads();
        for (int i = tid; i < 8192; i += 256) {
            int d = i >> 7, jl = i & 127;
            int jjg = chunk * 128 + jl;
            int jg = (jjg & 3) * HID_ + (jjg >> 2);
            Wxs[d * 132 + jl] = Wx[d * G4_ + jg];
        }
        if (tid < 128) {
            int jjg = chunk * 128 + tid;
            int jg = (jjg & 3) * HID_ + (jjg >> 2);
            bs[tid] = bx[jg] + bh[jg];
        }
        __syncthreads();
        float acc[16];
        #pragma unroll
        for (int j = 0; j < 16; j++) acc[j] = bs[jq * 16 + j];
        for (int d = 0; d < 64; d++) {
            float xv = Xs[c * 68 + d];
            const float4* wp = (const float4*)&Wxs[d * 132 + jq * 16];
            #pragma unroll
            for (int j4 = 0; j4 < 4; j4++) {
                float4 w4 = wp[j4];
                acc[j4 * 4 + 0] += xv * w4.x; acc[j4 * 4 + 1] += xv * w4.y;
                acc[j4 * 4 + 2] += xv * w4.z; acc[j4 * 4 + 3] += xv * w4.w;
            }
        }
        size_t base = ((size_t)win * 32 + c) * 512 + chunk * 128 + jq * 16;
        #pragma unroll
        for (int j = 0; j < 16; j++) XWx[base + j] = f2bf(acc[j]);
    }
}

// ---------------------------------------------------------------------------
// Kernel 8: fused 100-step GCLSTM scan.  One block per b, 1024 threads.
// tmp = XWx + Hp@Wh (MFMA, hi/lo 3-pass), g = An@tmp (MFMA, bf16),
// LSTM state in registers, Hsqm (k-mean of H) to global.
// ---------------------------------------------------------------------------
__global__ __launch_bounds__(1024) void scan_kernel(
    const unsigned short* __restrict__ An_bf,
    const unsigned short* __restrict__ XWx,
    const unsigned short* __restrict__ WhT_hi,
    const unsigned short* __restrict__ WhT_lo,
    float* __restrict__ Hsqm)
{
    __shared__ __align__(16) unsigned short HpHi[32 * 136];
    __shared__ __align__(16) unsigned short HpLo[32 * 136];
    __shared__ __align__(16) unsigned short AnS[32 * 40];
    __shared__ __align__(16) float Gs[32 * 260];     // aliases TmpT [256][40] bf16
    __shared__ float Red[16 * 128];
    unsigned short* TmpT = (unsigned short*)Gs;

    const int tid = threadIdx.x;
    const int lane = tid & 63;
    const int wv = tid >> 6;
    const int b = blockIdx.x;
    const int sc = tid >> 5, sh = tid & 31;
    const int l15 = lane & 15, quad = lane >> 4;
    const int r0a = quad << 2;      // C-row base within tile
    const int koff = quad << 3;     // K base within frag

    float Cst[4]  = {0.f, 0.f, 0.f, 0.f};
    float Hst[4]  = {0.f, 0.f, 0.f, 0.f};
    float H2st[4] = {0.f, 0.f, 0.f, 0.f};

    #pragma unroll 1
    for (int t = 0; t < WN_; t++) {
        const float coef  = (t == 0) ? 1.f : 2.f;
        const float dninv = (t == 0) ? 1.f : ((t == 1) ? 0.5f : (1.f / 3.f));
        #pragma unroll
        for (int q = 0; q < 4; q++) {
            int h = (q >> 1) * 64 + sh * 2 + (q & 1);
            float v = (coef * Hst[q] + H2st[q]) * dninv;
            unsigned short hi = f2bf(v);
            HpHi[sc * 136 + h] = hi;
            HpLo[sc * 136 + h] = f2bf(v - bf2f(hi));
        }
        AnS[sc * 40 + (tid & 31)] = An_bf[(size_t)(b * WN_ + t) * 1024 + tid];
        __syncthreads();

        for (int half = 0; half < 2; half++) {
            const int nt = wv;
            const int ccol = nt * 16 + l15;          // jj-local column
            const int jjg = half * 256 + ccol;       // global jj
            const size_t xbase = (size_t)(b * WN_ + t) * 16384;
            floatx4 acc0, acc1;
            #pragma unroll
            for (int r = 0; r < 4; r++) {
                acc0[r] = bf2f(XWx[xbase + (size_t)(r0a + r) * 512 + jjg]);
                acc1[r] = bf2f(XWx[xbase + (size_t)(16 + r0a + r) * 512 + jjg]);
            }
            #pragma unroll
            for (int kb = 0; kb < 4; kb++) {
                int k0 = kb * 32 + koff;
                short8 a0h = *(const short8*)&HpHi[l15 * 136 + k0];
                short8 a0l = *(const short8*)&HpLo[l15 * 136 + k0];
                short8 a1h = *(const short8*)&HpHi[(16 + l15) * 136 + k0];
                short8 a1l = *(const short8*)&HpLo[(16 + l15) * 136 + k0];
                size_t wb = (size_t)jjg * 128 + k0;
                short8 bh8 = *(const short8*)&WhT_hi[wb];
                short8 bl8 = *(const short8*)&WhT_lo[wb];
                acc0 = __builtin_amdgcn_mfma_f32_16x16x32_bf16(a0h, bh8, acc0, 0, 0, 0);
                acc0 = __builtin_amdgcn_mfma_f32_16x16x32_bf16(a0h, bl8, acc0, 0, 0, 0);
                acc0 = __builtin_amdgcn_mfma_f32_16x16x32_bf16(a0l, bh8, acc0, 0, 0, 0);
                acc1 = __builtin_amdgcn_mfma_f32_16x16x32_bf16(a1h, bh8, acc1, 0, 0, 0);
                acc1 = __builtin_amdgcn_mfma_f32_16x16x32_bf16(a1h, bl8, acc1, 0, 0, 0);
                acc1 = __builtin_amdgcn_mfma_f32_16x16x32_bf16(a1l, bh8, acc1, 0, 0, 0);
            }
            #pragma unroll
            for (int r = 0; r < 4; r++) {
                TmpT[ccol * 40 + r0a + r]      = f2bf(acc0[r]);
                TmpT[ccol * 40 + 16 + r0a + r] = f2bf(acc1[r]);
            }
            __syncthreads();
            short8 a20 = *(const short8*)&AnS[l15 * 40 + koff];
            short8 a21 = *(const short8*)&AnS[(16 + l15) * 40 + koff];
            short8 b2f = *(const short8*)&TmpT[ccol * 40 + koff];
            __syncthreads();
            floatx4 g0 = {0.f, 0.f, 0.f, 0.f};
            floatx4 g1 = {0.f, 0.f, 0.f, 0.f};
            g0 = __builtin_amdgcn_mfma_f32_16x16x32_bf16(a20, b2f, g0, 0, 0, 0);
            g1 = __builtin_amdgcn_mfma_f32_16x16x32_bf16(a21, b2f, g1, 0, 0, 0);
            #pragma unroll
            for (int r = 0; r < 4; r++) {
                Gs[(r0a + r) * 260 + ccol]      = g0[r];
                Gs[(16 + r0a + r) * 260 + ccol] = g1[r];
            }
            __syncthreads();
            float hnp[2];
            #pragma unroll
            for (int e = 0; e < 2; e++) {
                int hl = sh * 2 + e;
                int q = half * 2 + e;
                float4 g4 = *(const float4*)&Gs[sc * 260 + hl * 4];
                float cn = sigf(g4.y) * Cst[q] + sigf(g4.x) * tanhfast(g4.w);
                float hn = sigf(g4.z) * tanhfast(cn);
                Cst[q] = cn;
                H2st[q] = Hst[q];
                Hst[q] = hn;
                hnp[e] = hn;
            }
            float sr0 = hnp[0] + __shfl_xor(hnp[0], 32);
            float sr1 = hnp[1] + __shfl_xor(hnp[1], 32);
            if (lane < 32) {
                Red[wv * 128 + half * 64 + sh * 2]     = sr0;
                Red[wv * 128 + half * 64 + sh * 2 + 1] = sr1;
            }
            __syncthreads();
        }
        if (tid < 128) {
            float s = 0.f;
            #pragma unroll
            for (int w2 = 0; w2 < 16; w2++) s += Red[w2 * 128 + tid];
            Hsqm[(size_t)(b * WN_ + t) * 128 + tid] = s * (1.f / 32.f);
        }
        __syncthreads();
    }
}

// ---------------------------------------------------------------------------
// Kernel 9: temporal attention pooling + classifier.  One block per b.
// ---------------------------------------------------------------------------
__global__ __launch_bounds__(128) void final_kernel(
    const float* __restrict__ Hsqm, const float* __restrict__ Hsm,
    const float* __restrict__ q_t, const float* __restrict__ q_s,
    const float* __restrict__ cls_w, const float* __restrict__ cls_b,
    float* __restrict__ out)
{
    __shared__ float red[128];
    __shared__ float sc[WN_];
    __shared__ float wt[WN_];
    __shared__ float smv;
    const int b = blockIdx.x, tid = threadIdx.x;
    float v = q_t[tid];
    red[tid] = v * v;
    __syncthreads();
    for (int off = 64; off; off >>= 1) {
        if (tid < off) red[tid] += red[tid + off];
        __syncthreads();
    }
    const float qtn = sqrtf(red[0]) + 1e-8f;
    __syncthreads();
    float v2 = (tid < D_) ? q_s[tid] : 0.f;
    red[tid] = v2 * v2;
    __syncthreads();
    for (int off = 64; off; off >>= 1) {
        if (tid < off) red[tid] += red[tid + off];
        __syncthreads();
    }
    const float qsn = sqrtf(red[0]) + 1e-8f;
    __syncthreads();
    if (tid < WN_) {
        float s = 0.f;
        const float* zr = Hsqm + ((size_t)b * WN_ + tid) * HID_;
        for (int h = 0; h < HID_; h++) s += zr[h] * q_t[h];
        sc[tid] = s / qtn;
    }
    __syncthreads();
    if (tid == 0) {
        float m = sc[0];
        for (int i = 1; i < WN_; i++) m = fmaxf(m, sc[i]);
        float s = 0.f;
        for (int i = 0; i < WN_; i++) { wt[i] = expf(sc[i] - m); s += wt[i]; }
        smv = 1.f / s;
    }
    __syncthreads();
    float part = 0.f;
    {
        float z = 0.f;
        for (int w = 0; w < WN_; w++)
            z += wt[w] * Hsqm[((size_t)b * WN_ + w) * HID_ + tid];
        part += z * smv * cls_w[tid];
    }
    __syncthreads();
    if (tid < WN_) {
        float s = 0.f;
        const float* zr = Hsm + ((size_t)b * WN_ + tid) * D_;
        for (int dd = 0; dd < D_; dd++) s += zr[dd] * q_s[dd];
        sc[tid] = s / qsn;
    }
    __syncthreads();
    if (tid == 0) {
        float m = sc[0];
        for (int i = 1; i < WN_; i++) m = fmaxf(m, sc[i]);
        float s = 0.f;
        for (int i = 0; i < WN_; i++) { wt[i] = expf(sc[i] - m); s += wt[i]; }
        smv = 1.f / s;
    }
    __syncthreads();
    if (tid < D_) {
        float z = 0.f;
        for (int w = 0; w < WN_; w++)
            z += wt[w] * Hsm[((size_t)b * WN_ + w) * D_ + tid];
        part += z * smv * cls_w[HID_ + tid];
    }
    red[tid] = part;
    __syncthreads();
    for (int off = 64; off; off >>= 1) {
        if (tid < off) red[tid] += red[tid + off];
        __syncthreads();
    }
    if (tid == 0) out[b] = 1.f / (1.f + expf(-(red[0] + cls_b[0])));
}

// ---------------------------------------------------------------------------
extern "C" void kernel_launch(void* const* d_in, const int* in_sizes, int n_in,
                              void* d_out, int out_size, void* d_ws, size_t ws_size,
                              hipStream_t stream)
{
    (void)in_sizes; (void)n_in; (void)out_size; (void)ws_size;
    const float* x     = (const float*)d_in[0];
    const float* w1    = (const float*)d_in[1];
    const float* b1    = (const float*)d_in[2];
    const float* w2    = (const float*)d_in[3];
    const float* b2    = (const float*)d_in[4];
    const float* pw    = (const float*)d_in[5];
    const float* pb    = (const float*)d_in[6];
    const float* proto = (const float*)d_in[7];
    const float* Wx    = (const float*)d_in[8];
    const float* bx    = (const float*)d_in[9];
    const float* Wh    = (const float*)d_in[10];
    const float* bh    = (const float*)d_in[11];
    const float* q_t   = (const float*)d_in[12];
    const float* q_s   = (const float*)d_in[13];
    const float* clw   = (const float*)d_in[14];
    const float* clb   = (const float*)d_in[15];

    float* ws = (float*)d_ws;
    // layout (float slots):
    //   [0,            6553600)  Hs bf16 (13,107,200 ushorts)  ─┐ overlaid by
    //   [6553600,     13107200)  S fp32                         ─┘ XWx bf16 later
    //   [13107200,    16384000)  Xc fp32
    //   [16384000,    17203200)  An bf16 (1,638,400 ushorts)
    //   [17203200,    17305600)  Hsm fp32
    //   [17305600,    17510400)  Hsqm fp32
    //   [17510400,    17543168)  WhT_hi bf16 (65,536 ushorts)
    //   [17543168,    17575936)  WhT_lo bf16
    unsigned short* Hs_bf  = (unsigned short*)d_ws;
    float*          S      = ws + 6553600;
    float*          Xc     = ws + 13107200;
    unsigned short* An_bf  = (unsigned short*)(ws + 16384000);
    float*          Hsm    = ws + 17203200;
    float*          Hsqm   = ws + 17305600;
    unsigned short* WhT_hi = (unsigned short*)(ws + 17510400);
    unsigned short* WhT_lo = (unsigned short*)(ws + 17543168);
    unsigned short* XWx    = (unsigned short*)d_ws;   // overlays Hs+S

    conv_kernel<<<B_ * WN_, 256, 0, stream>>>(x, w1, b1, w2, b2, pw, pb, Hs_bf);
    s_kernel<<<(B_ * WN_ * N_) / 8, 256, 0, stream>>>(Hs_bf, proto, S);
    corr_kernel<<<B_ * WN_, 256, 0, stream>>>(x, S, An_bf);
    xc_kernel<<<B_ * WN_, 256, 0, stream>>>(S, Hs_bf, Xc);
    hsmean_kernel<<<B_ * WN_, 64, 0, stream>>>(Hs_bf, Hsm);
    whprep_kernel<<<256, 256, 0, stream>>>(Wh, WhT_hi, WhT_lo);
    xwx_kernel<<<B_ * WN_, 256, 0, stream>>>(Xc, Wx, bx, bh, XWx);
    scan_kernel<<<B_, 1024, 0, stream>>>(An_bf, XWx, WhT_hi, WhT_lo, Hsqm);
    final_kernel<<<B_, 128, 0, stream>>>(Hsqm, Hsm, q_t, q_s, clw, clb,
                                         (float*)d_out);
}

// Round 3
// 1933.485 us; speedup vs baseline: 1.6509x; 1.5502x over previous
//
#include <hip/hip_runtime.h>

#define B_   16
#define T_   3000
#define N_   128
#define WIN_ 30
#define WN_  100
#define D_   64
#define HID_ 128
#define K_   32
#define G4_  512   // 4*HID_

typedef __attribute__((ext_vector_type(8))) short short8;
typedef __attribute__((ext_vector_type(4))) float floatx4;

__device__ __forceinline__ unsigned short f2bf(float f) {
    unsigned u = __float_as_uint(f);
    u += 0x7fffu + ((u >> 16) & 1u);
    return (unsigned short)(u >> 16);
}
__device__ __forceinline__ float bf2f(unsigned short h) {
    return __uint_as_float(((unsigned)h) << 16);
}
__device__ __forceinline__ float sigf(float x) { return 1.f / (1.f + __expf(-x)); }
__device__ __forceinline__ float tanhfast(float x) { return 2.f / (1.f + __expf(-2.f * x)) - 1.f; }

// ---------------------------------------------------------------------------
// Kernel 1: SignalRep — conv1 (fp32 VALU), conv2 (bf16 MFMA, 5 shifted-dk
// passes, w2 hi/lo split), mean, proj.  One block per window; 16 groups of
// 8 sequences.  h1 in LDS as B-operand layout [seq][t'][ci], stride 40.
// ---------------------------------------------------------------------------
__global__ __launch_bounds__(256) void conv_kernel(
    const float* __restrict__ x, const float* __restrict__ w1,
    const float* __restrict__ b1, const float* __restrict__ w2,
    const float* __restrict__ b2, const float* __restrict__ pw,
    const float* __restrict__ pb, unsigned short* __restrict__ Hs)
{
    // h1: [8 seq][36 t'][40 ci+pad] bf16; t' = t+2, zeros at t' {0,1,32..35}
    __shared__ __align__(16) unsigned short h1s[8 * 36 * 40];   // 23040 B
    __shared__ __align__(16) unsigned short Cs[256 * 36];       // 18432 B [col][co+pad]
    __shared__ float xs[8 * 32];                                // [seq][t]
    __shared__ float pws[32 * 64];                              // proj weights
    __shared__ float means[8 * 33];
    const int tid = threadIdx.x;
    const int win = blockIdx.x;
    const int b = win / WN_, w = win - b * WN_;
    const float* xb = x + ((size_t)b * T_ + (size_t)w * WIN_) * N_;

    const int lane = tid & 63, wv = tid >> 6;
    const int l15 = lane & 15, quad = lane >> 4;
    const int mt = wv >> 1;           // m-tile (co block) for this wave
    const int ntp = wv & 1;           // ntile parity

    // ---- once-per-block staging ----
    for (int i = tid; i < 2048; i += 256) pws[i] = pw[i];
    for (int i = tid; i < 1920; i += 256) {       // zero h1 pad rows
        int s = i / 240, r = i % 240;
        int ti = r / 40, c = r % 40;
        int tp = (ti < 2) ? ti : (30 + ti);
        h1s[(s * 36 + tp) * 40 + c] = 0;
    }
    // A fragments: w2 rearranged per dk, hi/lo split (exact weights)
    short8 ahf[5], alf[5];
    #pragma unroll
    for (int dk = 0; dk < 5; dk++) {
        #pragma unroll
        for (int j = 0; j < 8; j++) {
            float v = w2[(mt * 16 + l15) * 160 + (quad * 8 + j) * 5 + dk];
            unsigned short hi = f2bf(v);
            ahf[dk][j] = (short)hi;
            alf[dk][j] = (short)f2bf(v - bf2f(hi));
        }
    }
    float b2v[4];
    #pragma unroll
    for (int r = 0; r < 4; r++) b2v[r] = b2[mt * 16 + quad * 4 + r];
    // conv1 per-thread constants: thread = (s = tid>>5, ci = tid&31)
    const int s1 = tid >> 5, ci1 = tid & 31;
    float w1r[5];
    #pragma unroll
    for (int k = 0; k < 5; k++) w1r[k] = w1[ci1 * 5 + k];
    const float b1v = b1[ci1];
    // mean/proj thread mapping
    const int d2 = tid & 31;                       // proj: d = 2*d2, 2*d2+1
    const float pbv0 = pb[2 * d2], pbv1 = pb[2 * d2 + 1];

    for (int g = 0; g < 16; g++) {
        const int n0 = g * 8;
        // ---- load xs[s][t] for this group's 8 sequences ----
        if (tid < 240) {
            int t = tid >> 3, s = tid & 7;
            xs[s * 32 + t] = xb[t * N_ + n0 + s];
        }
        __syncthreads();
        // ---- conv1: thread (s1, ci1) computes 30 t values ----
        {
            float xr[30];
            #pragma unroll
            for (int t = 0; t < 30; t++) xr[t] = xs[s1 * 32 + t];
            #pragma unroll
            for (int t = 0; t < 30; t++) {
                float acc = b1v;
                #pragma unroll
                for (int k = 0; k < 5; k++) {
                    int p = t + k - 2;
                    if (p >= 0 && p < 30) acc += xr[p] * w1r[k];
                }
                h1s[(s1 * 36 + 2 + t) * 40 + ci1] = f2bf(fmaxf(acc, 0.f));
            }
        }
        __syncthreads();
        // ---- conv2 via MFMA: wave owns mtile mt, ntiles ntp,ntp+2,... ----
        #pragma unroll 1
        for (int i = 0; i < 8; i++) {
            const int nt = ntp + 2 * i;
            const int c = nt * 16 + l15;           // column = seq*32 + tq
            const int s = c >> 5, tq = c & 31;
            floatx4 acc;
            #pragma unroll
            for (int r = 0; r < 4; r++) acc[r] = b2v[r];
            #pragma unroll
            for (int dk = 0; dk < 5; dk++) {
                short8 bfrag = *(const short8*)&h1s[(s * 36 + tq + dk) * 40 + quad * 8];
                acc = __builtin_amdgcn_mfma_f32_16x16x32_bf16(ahf[dk], bfrag, acc, 0, 0, 0);
                acc = __builtin_amdgcn_mfma_f32_16x16x32_bf16(alf[dk], bfrag, acc, 0, 0, 0);
            }
            if (tq < 30) {
                unsigned p0 = (unsigned)f2bf(fmaxf(acc[0], 0.f))
                            | ((unsigned)f2bf(fmaxf(acc[1], 0.f)) << 16);
                unsigned p1 = (unsigned)f2bf(fmaxf(acc[2], 0.f))
                            | ((unsigned)f2bf(fmaxf(acc[3], 0.f)) << 16);
                unsigned* cp = (unsigned*)&Cs[c * 36 + mt * 16 + quad * 4];
                cp[0] = p0; cp[1] = p1;
            }
        }
        __syncthreads();
        // ---- mean over t: thread (s1, ci1) == (seq, co) ----
        {
            float acc = 0.f;
            #pragma unroll
            for (int t = 0; t < 30; t++)
                acc += bf2f(Cs[(s1 * 32 + t) * 36 + ci1]);
            means[s1 * 33 + ci1] = acc * (1.f / 30.f);
        }
        __syncthreads();
        // ---- proj 32->64: thread (s1, d2) computes d = 2*d2, 2*d2+1 ----
        {
            float o0 = pbv0, o1 = pbv1;
            #pragma unroll 8
            for (int co = 0; co < 32; co++) {
                float m = means[s1 * 33 + co];
                o0 += m * pws[co * 64 + 2 * d2];
                o1 += m * pws[co * 64 + 2 * d2 + 1];
            }
            unsigned pk = (unsigned)f2bf(o0) | ((unsigned)f2bf(o1) << 16);
            unsigned* hp = (unsigned*)(Hs + (size_t)win * (N_ * D_) + (size_t)(n0 + s1) * D_);
            hp[d2] = pk;
        }
        __syncthreads();
    }
}

// ---------------------------------------------------------------------------
// Kernel 2: S = softmax_k(Hs @ proto^T). One 32-lane group per (b,w,n).
// ---------------------------------------------------------------------------
__global__ __launch_bounds__(256) void s_kernel(
    const unsigned short* __restrict__ Hs, const float* __restrict__ proto,
    float* __restrict__ S)
{
    const int tid = threadIdx.x;
    const int lane = tid & 63;
    const int gw = blockIdx.x * 4 + (tid >> 6);
    const int sub = lane >> 5, kk = lane & 31;
    const size_t nid = (size_t)gw * 2 + sub;
    const unsigned short* h = Hs + nid * D_;
    const float* p = proto + (size_t)kk * D_;
    float l = 0.f;
    #pragma unroll
    for (int d = 0; d < D_; d++) l += bf2f(h[d]) * p[d];
    float m = l;
    for (int off = 16; off; off >>= 1) m = fmaxf(m, __shfl_xor(m, off));
    float e = expf(l - m);
    float s = e;
    for (int off = 16; off; off >>= 1) s += __shfl_xor(s, off);
    S[nid * K_ + kk] = e / s;
}

// ---------------------------------------------------------------------------
// Kernel 3: corr -> AS -> Ac -> normalize -> An (bf16 out)
// ---------------------------------------------------------------------------
__global__ __launch_bounds__(256) void corr_kernel(
    const float* __restrict__ x, const float* __restrict__ S,
    unsigned short* __restrict__ An)
{
    __shared__ float xs[WIN_ * N_];
    __shared__ float sinv[N_];
    __shared__ float Ss[N_ * K_];
    __shared__ float ASs[N_ * K_];
    __shared__ float Arow[4][N_];
    __shared__ float Acs[K_][K_ + 1];
    __shared__ float dinv[K_];
    const int tid = threadIdx.x;
    const int win = blockIdx.x;
    const int b = win / WN_, w = win - b * WN_;
    const float* xb = x + ((size_t)b * T_ + (size_t)w * WIN_) * N_;
    for (int i = tid; i < WIN_ * N_; i += 256) xs[i] = xb[i];
    for (int i = tid; i < N_ * K_; i += 256) Ss[i] = S[(size_t)win * N_ * K_ + i];
    __syncthreads();
    if (tid < N_) {
        int n = tid;
        float mean = 0.f;
        for (int l = 0; l < WIN_; l++) mean += xs[l * N_ + n];
        mean *= (1.f / WIN_);
        float var = 0.f;
        for (int l = 0; l < WIN_; l++) {
            float v = xs[l * N_ + n] - mean;
            xs[l * N_ + n] = v;
            var += v * v;
        }
        var *= (1.f / (WIN_ - 1 + 1e-8f));
        sinv[n] = rsqrtf(fmaxf(var, 1e-8f));
    }
    __syncthreads();
    const int lane = tid & 63, wid = tid >> 6;
    const int l32 = lane & 31, hf = lane >> 5;
    for (int n = wid; n < N_; n += 4) {
        float sn = sinv[n];
        #pragma unroll
        for (int mm = 0; mm < 2; mm++) {
            int m = lane + 64 * mm;
            float cov = 0.f;
            for (int l = 0; l < WIN_; l++) cov += xs[l * N_ + n] * xs[l * N_ + m];
            float a = cov * (1.f / (WIN_ - 1 + 1e-8f)) * sn * sinv[m];
            Arow[wid][m] = (m == n) ? 1.f : a;
        }
        __builtin_amdgcn_wave_barrier();
        float p = 0.f;
        for (int m = hf * 64; m < hf * 64 + 64; m++)
            p += Arow[wid][m] * Ss[m * K_ + l32];
        p += __shfl_down(p, 32);
        if (hf == 0) ASs[n * K_ + l32] = p;
        __builtin_amdgcn_wave_barrier();
    }
    __syncthreads();
    {
        int l = tid & 31, kb = tid >> 5;
        for (int r = 0; r < 4; r++) {
            int k = kb + 8 * r;
            float acc = 0.f;
            for (int n = 0; n < N_; n++) acc += Ss[n * K_ + k] * ASs[n * K_ + l];
            Acs[k][l] = acc;
        }
    }
    __syncthreads();
    float symv[4];
    {
        int l = tid & 31, kb = tid >> 5;
        for (int r = 0; r < 4; r++) {
            int k = kb + 8 * r;
            symv[r] = 0.5f * (Acs[k][l] + Acs[l][k]) + ((k == l) ? 1.f : 0.f);
        }
    }
    __syncthreads();
    {
        int l = tid & 31, kb = tid >> 5;
        for (int r = 0; r < 4; r++) Acs[kb + 8 * r][l] = symv[r];
    }
    __syncthreads();
    if (tid < K_) {
        float s = 0.f;
        for (int l = 0; l < K_; l++) s += Acs[tid][l];
        dinv[tid] = rsqrtf(fmaxf(s, 1e-8f));
    }
    __syncthreads();
    unsigned short* Anw = An + (size_t)win * K_ * K_;
    for (int i = tid; i < K_ * K_; i += 256) {
        int k = i >> 5, l = i & 31;
        Anw[i] = f2bf(dinv[k] * Acs[k][l] * dinv[l]);
    }
}

// ---------------------------------------------------------------------------
// Kernel 4: Xc[k][d] = sum_n S[n][k] * Hs[n][d], per window (fp32 out).
// ---------------------------------------------------------------------------
__global__ __launch_bounds__(256) void xc_kernel(
    const float* __restrict__ S, const unsigned short* __restrict__ Hs,
    float* __restrict__ Xc)
{
    __shared__ float Ss[N_ * K_];
    __shared__ float Hss[N_ * D_];
    const int tid = threadIdx.x;
    const int win = blockIdx.x;
    for (int i = tid; i < N_ * K_; i += 256) Ss[i] = S[(size_t)win * N_ * K_ + i];
    for (int i = tid; i < N_ * D_; i += 256) Hss[i] = bf2f(Hs[(size_t)win * N_ * D_ + i]);
    __syncthreads();
    const int dd = tid & 63, kb = tid >> 6;
    for (int r = 0; r < 8; r++) {
        int k = r * 4 + kb;
        float acc = 0.f;
        for (int n = 0; n < N_; n++) acc += Ss[n * K_ + k] * Hss[n * D_ + dd];
        Xc[((size_t)win * K_ + k) * D_ + dd] = acc;
    }
}

// ---------------------------------------------------------------------------
// Kernel 5: Hs mean over nodes -> Hsm[b,w,d] (fp32)
// ---------------------------------------------------------------------------
__global__ __launch_bounds__(64) void hsmean_kernel(
    const unsigned short* __restrict__ Hs, float* __restrict__ Hsm)
{
    const int win = blockIdx.x, dd = threadIdx.x;
    float acc = 0.f;
    for (int n = 0; n < N_; n++) acc += bf2f(Hs[((size_t)win * N_ + n) * D_ + dd]);
    Hsm[(size_t)win * D_ + dd] = acc * (1.f / N_);
}

// ---------------------------------------------------------------------------
// Kernel 6: Wh -> permuted transposed split-bf16  WhT[jj][h], jj = hcol*4+gate
// ---------------------------------------------------------------------------
__global__ __launch_bounds__(256) void whprep_kernel(
    const float* __restrict__ Wh, unsigned short* __restrict__ WhT_hi,
    unsigned short* __restrict__ WhT_lo)
{
    int i = blockIdx.x * 256 + threadIdx.x;   // 65536
    int jj = i >> 7, h = i & 127;
    int jg = (jj & 3) * HID_ + (jj >> 2);
    float v = Wh[h * G4_ + jg];
    unsigned short hi = f2bf(v);
    WhT_hi[i] = hi;
    WhT_lo[i] = f2bf(v - bf2f(hi));
}

// ---------------------------------------------------------------------------
// Kernel 7: XWx[b,t,c,jj] = (Xc @ Wx + bx + bh)[jg(jj)], bf16.  1 blk/window.
// ---------------------------------------------------------------------------
__global__ __launch_bounds__(256) void xwx_kernel(
    const float* __restrict__ Xc, const float* __restrict__ Wx,
    const float* __restrict__ bx, const float* __restrict__ bh,
    unsigned short* __restrict__ XWx)
{
    __shared__ __align__(16) float Xs[32 * 68];
    __shared__ __align__(16) float Wxs[64 * 132];
    __shared__ float bs[128];
    const int tid = threadIdx.x;
    const int win = blockIdx.x;
    for (int i = tid; i < 2048; i += 256) {
        int c = i >> 6, d = i & 63;
        Xs[c * 68 + d] = Xc[(size_t)win * 2048 + i];
    }
    const int c = tid >> 3, jq = tid & 7;
    for (int chunk = 0; chunk < 4; chunk++) {
        __syncthreads();
        for (int i = tid; i < 8192; i += 256) {
            int d = i >> 7, jl = i & 127;
            int jjg = chunk * 128 + jl;
            int jg = (jjg & 3) * HID_ + (jjg >> 2);
            Wxs[d * 132 + jl] = Wx[d * G4_ + jg];
        }
        if (tid < 128) {
            int jjg = chunk * 128 + tid;
            int jg = (jjg & 3) * HID_ + (jjg >> 2);
            bs[tid] = bx[jg] + bh[jg];
        }
        __syncthreads();
        float acc[16];
        #pragma unroll
        for (int j = 0; j < 16; j++) acc[j] = bs[jq * 16 + j];
        for (int d = 0; d < 64; d++) {
            float xv = Xs[c * 68 + d];
            const float4* wp = (const float4*)&Wxs[d * 132 + jq * 16];
            #pragma unroll
            for (int j4 = 0; j4 < 4; j4++) {
                float4 w4 = wp[j4];
                acc[j4 * 4 + 0] += xv * w4.x; acc[j4 * 4 + 1] += xv * w4.y;
                acc[j4 * 4 + 2] += xv * w4.z; acc[j4 * 4 + 3] += xv * w4.w;
            }
        }
        size_t base = ((size_t)win * 32 + c) * 512 + chunk * 128 + jq * 16;
        #pragma unroll
        for (int j = 0; j < 16; j++) XWx[base + j] = f2bf(acc[j]);
    }
}

// ---------------------------------------------------------------------------
// Kernel 8: fused 100-step GCLSTM scan.  One block per b, 1024 threads.
// ---------------------------------------------------------------------------
__global__ __launch_bounds__(1024) void scan_kernel(
    const unsigned short* __restrict__ An_bf,
    const unsigned short* __restrict__ XWx,
    const unsigned short* __restrict__ WhT_hi,
    const unsigned short* __restrict__ WhT_lo,
    float* __restrict__ Hsqm)
{
    __shared__ __align__(16) unsigned short HpHi[32 * 136];
    __shared__ __align__(16) unsigned short HpLo[32 * 136];
    __shared__ __align__(16) unsigned short AnS[32 * 40];
    __shared__ __align__(16) float Gs[32 * 260];     // aliases TmpT [256][40] bf16
    __shared__ float Red[16 * 128];
    unsigned short* TmpT = (unsigned short*)Gs;

    const int tid = threadIdx.x;
    const int lane = tid & 63;
    const int wv = tid >> 6;
    const int b = blockIdx.x;
    const int sc = tid >> 5, sh = tid & 31;
    const int l15 = lane & 15, quad = lane >> 4;
    const int r0a = quad << 2;
    const int koff = quad << 3;

    float Cst[4]  = {0.f, 0.f, 0.f, 0.f};
    float Hst[4]  = {0.f, 0.f, 0.f, 0.f};
    float H2st[4] = {0.f, 0.f, 0.f, 0.f};

    #pragma unroll 1
    for (int t = 0; t < WN_; t++) {
        const float coef  = (t == 0) ? 1.f : 2.f;
        const float dninv = (t == 0) ? 1.f : ((t == 1) ? 0.5f : (1.f / 3.f));
        #pragma unroll
        for (int q = 0; q < 4; q++) {
            int h = (q >> 1) * 64 + sh * 2 + (q & 1);
            float v = (coef * Hst[q] + H2st[q]) * dninv;
            unsigned short hi = f2bf(v);
            HpHi[sc * 136 + h] = hi;
            HpLo[sc * 136 + h] = f2bf(v - bf2f(hi));
        }
        AnS[sc * 40 + (tid & 31)] = An_bf[(size_t)(b * WN_ + t) * 1024 + tid];
        __syncthreads();

        for (int half = 0; half < 2; half++) {
            const int nt = wv;
            const int ccol = nt * 16 + l15;
            const int jjg = half * 256 + ccol;
            const size_t xbase = (size_t)(b * WN_ + t) * 16384;
            floatx4 acc0, acc1;
            #pragma unroll
            for (int r = 0; r < 4; r++) {
                acc0[r] = bf2f(XWx[xbase + (size_t)(r0a + r) * 512 + jjg]);
                acc1[r] = bf2f(XWx[xbase + (size_t)(16 + r0a + r) * 512 + jjg]);
            }
            #pragma unroll
            for (int kb = 0; kb < 4; kb++) {
                int k0 = kb * 32 + koff;
                short8 a0h = *(const short8*)&HpHi[l15 * 136 + k0];
                short8 a0l = *(const short8*)&HpLo[l15 * 136 + k0];
                short8 a1h = *(const short8*)&HpHi[(16 + l15) * 136 + k0];
                short8 a1l = *(const short8*)&HpLo[(16 + l15) * 136 + k0];
                size_t wb = (size_t)jjg * 128 + k0;
                short8 bh8 = *(const short8*)&WhT_hi[wb];
                short8 bl8 = *(const short8*)&WhT_lo[wb];
                acc0 = __builtin_amdgcn_mfma_f32_16x16x32_bf16(a0h, bh8, acc0, 0, 0, 0);
                acc0 = __builtin_amdgcn_mfma_f32_16x16x32_bf16(a0h, bl8, acc0, 0, 0, 0);
                acc0 = __builtin_amdgcn_mfma_f32_16x16x32_bf16(a0l, bh8, acc0, 0, 0, 0);
                acc1 = __builtin_amdgcn_mfma_f32_16x16x32_bf16(a1h, bh8, acc1, 0, 0, 0);
                acc1 = __builtin_amdgcn_mfma_f32_16x16x32_bf16(a1h, bl8, acc1, 0, 0, 0);
                acc1 = __builtin_amdgcn_mfma_f32_16x16x32_bf16(a1l, bh8, acc1, 0, 0, 0);
            }
            #pragma unroll
            for (int r = 0; r < 4; r++) {
                TmpT[ccol * 40 + r0a + r]      = f2bf(acc0[r]);
                TmpT[ccol * 40 + 16 + r0a + r] = f2bf(acc1[r]);
            }
            __syncthreads();
            short8 a20 = *(const short8*)&AnS[l15 * 40 + koff];
            short8 a21 = *(const short8*)&AnS[(16 + l15) * 40 + koff];
            short8 b2f = *(const short8*)&TmpT[ccol * 40 + koff];
            __syncthreads();
            floatx4 g0 = {0.f, 0.f, 0.f, 0.f};
            floatx4 g1 = {0.f, 0.f, 0.f, 0.f};
            g0 = __builtin_amdgcn_mfma_f32_16x16x32_bf16(a20, b2f, g0, 0, 0, 0);
            g1 = __builtin_amdgcn_mfma_f32_16x16x32_bf16(a21, b2f, g1, 0, 0, 0);
            #pragma unroll
            for (int r = 0; r < 4; r++) {
                Gs[(r0a + r) * 260 + ccol]      = g0[r];
                Gs[(16 + r0a + r) * 260 + ccol] = g1[r];
            }
            __syncthreads();
            float hnp[2];
            #pragma unroll
            for (int e = 0; e < 2; e++) {
                int hl = sh * 2 + e;
                int q = half * 2 + e;
                float4 g4 = *(const float4*)&Gs[sc * 260 + hl * 4];
                float cn = sigf(g4.y) * Cst[q] + sigf(g4.x) * tanhfast(g4.w);
                float hn = sigf(g4.z) * tanhfast(cn);
                Cst[q] = cn;
                H2st[q] = Hst[q];
                Hst[q] = hn;
                hnp[e] = hn;
            }
            float sr0 = hnp[0] + __shfl_xor(hnp[0], 32);
            float sr1 = hnp[1] + __shfl_xor(hnp[1], 32);
            if (lane < 32) {
                Red[wv * 128 + half * 64 + sh * 2]     = sr0;
                Red[wv * 128 + half * 64 + sh * 2 + 1] = sr1;
            }
            __syncthreads();
        }
        if (tid < 128) {
            float s = 0.f;
            #pragma unroll
            for (int w2 = 0; w2 < 16; w2++) s += Red[w2 * 128 + tid];
            Hsqm[(size_t)(b * WN_ + t) * 128 + tid] = s * (1.f / 32.f);
        }
        __syncthreads();
    }
}

// ---------------------------------------------------------------------------
// Kernel 9: temporal attention pooling + classifier.  One block per b.
// ---------------------------------------------------------------------------
__global__ __launch_bounds__(128) void final_kernel(
    const float* __restrict__ Hsqm, const float* __restrict__ Hsm,
    const float* __restrict__ q_t, const float* __restrict__ q_s,
    const float* __restrict__ cls_w, const float* __restrict__ cls_b,
    float* __restrict__ out)
{
    __shared__ float red[128];
    __shared__ float sc[WN_];
    __shared__ float wt[WN_];
    __shared__ float smv;
    const int b = blockIdx.x, tid = threadIdx.x;
    float v = q_t[tid];
    red[tid] = v * v;
    __syncthreads();
    for (int off = 64; off; off >>= 1) {
        if (tid < off) red[tid] += red[tid + off];
        __syncthreads();
    }
    const float qtn = sqrtf(red[0]) + 1e-8f;
    __syncthreads();
    float v2 = (tid < D_) ? q_s[tid] : 0.f;
    red[tid] = v2 * v2;
    __syncthreads();
    for (int off = 64; off; off >>= 1) {
        if (tid < off) red[tid] += red[tid + off];
        __syncthreads();
    }
    const float qsn = sqrtf(red[0]) + 1e-8f;
    __syncthreads();
    if (tid < WN_) {
        float s = 0.f;
        const float* zr = Hsqm + ((size_t)b * WN_ + tid) * HID_;
        for (int h = 0; h < HID_; h++) s += zr[h] * q_t[h];
        sc[tid] = s / qtn;
    }
    __syncthreads();
    if (tid == 0) {
        float m = sc[0];
        for (int i = 1; i < WN_; i++) m = fmaxf(m, sc[i]);
        float s = 0.f;
        for (int i = 0; i < WN_; i++) { wt[i] = expf(sc[i] - m); s += wt[i]; }
        smv = 1.f / s;
    }
    __syncthreads();
    float part = 0.f;
    {
        float z = 0.f;
        for (int w = 0; w < WN_; w++)
            z += wt[w] * Hsqm[((size_t)b * WN_ + w) * HID_ + tid];
        part += z * smv * cls_w[tid];
    }
    __syncthreads();
    if (tid < WN_) {
        float s = 0.f;
        const float* zr = Hsm + ((size_t)b * WN_ + tid) * D_;
        for (int dd = 0; dd < D_; dd++) s += zr[dd] * q_s[dd];
        sc[tid] = s / qsn;
    }
    __syncthreads();
    if (tid == 0) {
        float m = sc[0];
        for (int i = 1; i < WN_; i++) m = fmaxf(m, sc[i]);
        float s = 0.f;
        for (int i = 0; i < WN_; i++) { wt[i] = expf(sc[i] - m); s += wt[i]; }
        smv = 1.f / s;
    }
    __syncthreads();
    if (tid < D_) {
        float z = 0.f;
        for (int w = 0; w < WN_; w++)
            z += wt[w] * Hsm[((size_t)b * WN_ + w) * D_ + tid];
        part += z * smv * cls_w[HID_ + tid];
    }
    red[tid] = part;
    __syncthreads();
    for (int off = 64; off; off >>= 1) {
        if (tid < off) red[tid] += red[tid + off];
        __syncthreads();
    }
    if (tid == 0) out[b] = 1.f / (1.f + expf(-(red[0] + cls_b[0])));
}

// ---------------------------------------------------------------------------
extern "C" void kernel_launch(void* const* d_in, const int* in_sizes, int n_in,
                              void* d_out, int out_size, void* d_ws, size_t ws_size,
                              hipStream_t stream)
{
    (void)in_sizes; (void)n_in; (void)out_size; (void)ws_size;
    const float* x     = (const float*)d_in[0];
    const float* w1    = (const float*)d_in[1];
    const float* b1    = (const float*)d_in[2];
    const float* w2    = (const float*)d_in[3];
    const float* b2    = (const float*)d_in[4];
    const float* pw    = (const float*)d_in[5];
    const float* pb    = (const float*)d_in[6];
    const float* proto = (const float*)d_in[7];
    const float* Wx    = (const float*)d_in[8];
    const float* bx    = (const float*)d_in[9];
    const float* Wh    = (const float*)d_in[10];
    const float* bh    = (const float*)d_in[11];
    const float* q_t   = (const float*)d_in[12];
    const float* q_s   = (const float*)d_in[13];
    const float* clw   = (const float*)d_in[14];
    const float* clb   = (const float*)d_in[15];

    float* ws = (float*)d_ws;
    unsigned short* Hs_bf  = (unsigned short*)d_ws;
    float*          S      = ws + 6553600;
    float*          Xc     = ws + 13107200;
    unsigned short* An_bf  = (unsigned short*)(ws + 16384000);
    float*          Hsm    = ws + 17203200;
    float*          Hsqm   = ws + 17305600;
    unsigned short* WhT_hi = (unsigned short*)(ws + 17510400);
    unsigned short* WhT_lo = (unsigned short*)(ws + 17543168);
    unsigned short* XWx    = (unsigned short*)d_ws;   // overlays Hs+S

    conv_kernel<<<B_ * WN_, 256, 0, stream>>>(x, w1, b1, w2, b2, pw, pb, Hs_bf);
    s_kernel<<<(B_ * WN_ * N_) / 8, 256, 0, stream>>>(Hs_bf, proto, S);
    corr_kernel<<<B_ * WN_, 256, 0, stream>>>(x, S, An_bf);
    xc_kernel<<<B_ * WN_, 256, 0, stream>>>(S, Hs_bf, Xc);
    hsmean_kernel<<<B_ * WN_, 64, 0, stream>>>(Hs_bf, Hsm);
    whprep_kernel<<<256, 256, 0, stream>>>(Wh, WhT_hi, WhT_lo);
    xwx_kernel<<<B_ * WN_, 256, 0, stream>>>(Xc, Wx, bx, bh, XWx);
    scan_kernel<<<B_, 1024, 0, stream>>>(An_bf, XWx, WhT_hi, WhT_lo, Hsqm);
    final_kernel<<<B_, 128, 0, stream>>>(Hsqm, Hsm, q_t, q_s, clw, clb,
                                         (float*)d_out);
}

// Round 4
// 1503.860 us; speedup vs baseline: 2.1225x; 1.2857x over previous
//
#include <hip/hip_runtime.h>

#define B_   16
#define T_   3000
#define N_   128
#define WIN_ 30
#define WN_  100
#define D_   64
#define HID_ 128
#define K_   32
#define G4_  512   // 4*HID_

typedef __attribute__((ext_vector_type(8))) short short8;
typedef __attribute__((ext_vector_type(4))) float floatx4;

__device__ __forceinline__ unsigned short f2bf(float f) {
    unsigned u = __float_as_uint(f);
    u += 0x7fffu + ((u >> 16) & 1u);
    return (unsigned short)(u >> 16);
}
__device__ __forceinline__ float bf2f(unsigned short h) {
    return __uint_as_float(((unsigned)h) << 16);
}
__device__ __forceinline__ float sigf(float x) { return 1.f / (1.f + __expf(-x)); }
__device__ __forceinline__ float tanhfast(float x) { return 2.f / (1.f + __expf(-2.f * x)) - 1.f; }

// ---------------------------------------------------------------------------
// Kernel 1: SignalRep — conv1 (fp32 VALU), conv2 (bf16 MFMA, 5 shifted-dk
// passes, w2 hi/lo split), mean, proj.  One block per window; 16 groups of
// 8 sequences.  h1 in LDS as B-operand layout [seq][t'][ci], stride 40.
// ---------------------------------------------------------------------------
__global__ __launch_bounds__(256) void conv_kernel(
    const float* __restrict__ x, const float* __restrict__ w1,
    const float* __restrict__ b1, const float* __restrict__ w2,
    const float* __restrict__ b2, const float* __restrict__ pw,
    const float* __restrict__ pb, unsigned short* __restrict__ Hs)
{
    __shared__ __align__(16) unsigned short h1s[8 * 36 * 40];
    __shared__ __align__(16) unsigned short Cs[256 * 36];
    __shared__ float xs[8 * 32];
    __shared__ float pws[32 * 64];
    __shared__ float means[8 * 33];
    const int tid = threadIdx.x;
    const int win = blockIdx.x;
    const int b = win / WN_, w = win - b * WN_;
    const float* xb = x + ((size_t)b * T_ + (size_t)w * WIN_) * N_;

    const int lane = tid & 63, wv = tid >> 6;
    const int l15 = lane & 15, quad = lane >> 4;
    const int mt = wv >> 1;
    const int ntp = wv & 1;

    for (int i = tid; i < 2048; i += 256) pws[i] = pw[i];
    for (int i = tid; i < 1920; i += 256) {
        int s = i / 240, r = i % 240;
        int ti = r / 40, c = r % 40;
        int tp = (ti < 2) ? ti : (30 + ti);
        h1s[(s * 36 + tp) * 40 + c] = 0;
    }
    short8 ahf[5], alf[5];
    #pragma unroll
    for (int dk = 0; dk < 5; dk++) {
        #pragma unroll
        for (int j = 0; j < 8; j++) {
            float v = w2[(mt * 16 + l15) * 160 + (quad * 8 + j) * 5 + dk];
            unsigned short hi = f2bf(v);
            ahf[dk][j] = (short)hi;
            alf[dk][j] = (short)f2bf(v - bf2f(hi));
        }
    }
    float b2v[4];
    #pragma unroll
    for (int r = 0; r < 4; r++) b2v[r] = b2[mt * 16 + quad * 4 + r];
    const int s1 = tid >> 5, ci1 = tid & 31;
    float w1r[5];
    #pragma unroll
    for (int k = 0; k < 5; k++) w1r[k] = w1[ci1 * 5 + k];
    const float b1v = b1[ci1];
    const int d2 = tid & 31;
    const float pbv0 = pb[2 * d2], pbv1 = pb[2 * d2 + 1];

    for (int g = 0; g < 16; g++) {
        const int n0 = g * 8;
        if (tid < 240) {
            int t = tid >> 3, s = tid & 7;
            xs[s * 32 + t] = xb[t * N_ + n0 + s];
        }
        __syncthreads();
        {
            float xr[30];
            #pragma unroll
            for (int t = 0; t < 30; t++) xr[t] = xs[s1 * 32 + t];
            #pragma unroll
            for (int t = 0; t < 30; t++) {
                float acc = b1v;
                #pragma unroll
                for (int k = 0; k < 5; k++) {
                    int p = t + k - 2;
                    if (p >= 0 && p < 30) acc += xr[p] * w1r[k];
                }
                h1s[(s1 * 36 + 2 + t) * 40 + ci1] = f2bf(fmaxf(acc, 0.f));
            }
        }
        __syncthreads();
        #pragma unroll 1
        for (int i = 0; i < 8; i++) {
            const int nt = ntp + 2 * i;
            const int c = nt * 16 + l15;
            const int s = c >> 5, tq = c & 31;
            floatx4 acc;
            #pragma unroll
            for (int r = 0; r < 4; r++) acc[r] = b2v[r];
            #pragma unroll
            for (int dk = 0; dk < 5; dk++) {
                short8 bfrag = *(const short8*)&h1s[(s * 36 + tq + dk) * 40 + quad * 8];
                acc = __builtin_amdgcn_mfma_f32_16x16x32_bf16(ahf[dk], bfrag, acc, 0, 0, 0);
                acc = __builtin_amdgcn_mfma_f32_16x16x32_bf16(alf[dk], bfrag, acc, 0, 0, 0);
            }
            if (tq < 30) {
                unsigned p0 = (unsigned)f2bf(fmaxf(acc[0], 0.f))
                            | ((unsigned)f2bf(fmaxf(acc[1], 0.f)) << 16);
                unsigned p1 = (unsigned)f2bf(fmaxf(acc[2], 0.f))
                            | ((unsigned)f2bf(fmaxf(acc[3], 0.f)) << 16);
                unsigned* cp = (unsigned*)&Cs[c * 36 + mt * 16 + quad * 4];
                cp[0] = p0; cp[1] = p1;
            }
        }
        __syncthreads();
        {
            float acc = 0.f;
            #pragma unroll
            for (int t = 0; t < 30; t++)
                acc += bf2f(Cs[(s1 * 32 + t) * 36 + ci1]);
            means[s1 * 33 + ci1] = acc * (1.f / 30.f);
        }
        __syncthreads();
        {
            float o0 = pbv0, o1 = pbv1;
            #pragma unroll 8
            for (int co = 0; co < 32; co++) {
                float m = means[s1 * 33 + co];
                o0 += m * pws[co * 64 + 2 * d2];
                o1 += m * pws[co * 64 + 2 * d2 + 1];
            }
            unsigned pk = (unsigned)f2bf(o0) | ((unsigned)f2bf(o1) << 16);
            unsigned* hp = (unsigned*)(Hs + (size_t)win * (N_ * D_) + (size_t)(n0 + s1) * D_);
            hp[d2] = pk;
        }
        __syncthreads();
    }
}

// ---------------------------------------------------------------------------
// Kernel 2: S = softmax_k(Hs @ proto^T). One 32-lane group per (b,w,n).
// ---------------------------------------------------------------------------
__global__ __launch_bounds__(256) void s_kernel(
    const unsigned short* __restrict__ Hs, const float* __restrict__ proto,
    float* __restrict__ S)
{
    const int tid = threadIdx.x;
    const int lane = tid & 63;
    const int gw = blockIdx.x * 4 + (tid >> 6);
    const int sub = lane >> 5, kk = lane & 31;
    const size_t nid = (size_t)gw * 2 + sub;
    const unsigned short* h = Hs + nid * D_;
    const float* p = proto + (size_t)kk * D_;
    float l = 0.f;
    #pragma unroll
    for (int d = 0; d < D_; d++) l += bf2f(h[d]) * p[d];
    float m = l;
    for (int off = 16; off; off >>= 1) m = fmaxf(m, __shfl_xor(m, off));
    float e = expf(l - m);
    float s = e;
    for (int off = 16; off; off >>= 1) s += __shfl_xor(s, off);
    S[nid * K_ + kk] = e / s;
}

// ---------------------------------------------------------------------------
// Kernel 3: corr -> AS -> Ac -> normalize -> An (bf16 out)
// ---------------------------------------------------------------------------
__global__ __launch_bounds__(256) void corr_kernel(
    const float* __restrict__ x, const float* __restrict__ S,
    unsigned short* __restrict__ An)
{
    __shared__ float xs[WIN_ * N_];
    __shared__ float sinv[N_];
    __shared__ float Ss[N_ * K_];
    __shared__ float ASs[N_ * K_];
    __shared__ float Arow[4][N_];
    __shared__ float Acs[K_][K_ + 1];
    __shared__ float dinv[K_];
    const int tid = threadIdx.x;
    const int win = blockIdx.x;
    const int b = win / WN_, w = win - b * WN_;
    const float* xb = x + ((size_t)b * T_ + (size_t)w * WIN_) * N_;
    for (int i = tid; i < WIN_ * N_; i += 256) xs[i] = xb[i];
    for (int i = tid; i < N_ * K_; i += 256) Ss[i] = S[(size_t)win * N_ * K_ + i];
    __syncthreads();
    if (tid < N_) {
        int n = tid;
        float mean = 0.f;
        for (int l = 0; l < WIN_; l++) mean += xs[l * N_ + n];
        mean *= (1.f / WIN_);
        float var = 0.f;
        for (int l = 0; l < WIN_; l++) {
            float v = xs[l * N_ + n] - mean;
            xs[l * N_ + n] = v;
            var += v * v;
        }
        var *= (1.f / (WIN_ - 1 + 1e-8f));
        sinv[n] = rsqrtf(fmaxf(var, 1e-8f));
    }
    __syncthreads();
    const int lane = tid & 63, wid = tid >> 6;
    const int l32 = lane & 31, hf = lane >> 5;
    for (int n = wid; n < N_; n += 4) {
        float sn = sinv[n];
        #pragma unroll
        for (int mm = 0; mm < 2; mm++) {
            int m = lane + 64 * mm;
            float cov = 0.f;
            for (int l = 0; l < WIN_; l++) cov += xs[l * N_ + n] * xs[l * N_ + m];
            float a = cov * (1.f / (WIN_ - 1 + 1e-8f)) * sn * sinv[m];
            Arow[wid][m] = (m == n) ? 1.f : a;
        }
        __builtin_amdgcn_wave_barrier();
        float p = 0.f;
        for (int m = hf * 64; m < hf * 64 + 64; m++)
            p += Arow[wid][m] * Ss[m * K_ + l32];
        p += __shfl_down(p, 32);
        if (hf == 0) ASs[n * K_ + l32] = p;
        __builtin_amdgcn_wave_barrier();
    }
    __syncthreads();
    {
        int l = tid & 31, kb = tid >> 5;
        for (int r = 0; r < 4; r++) {
            int k = kb + 8 * r;
            float acc = 0.f;
            for (int n = 0; n < N_; n++) acc += Ss[n * K_ + k] * ASs[n * K_ + l];
            Acs[k][l] = acc;
        }
    }
    __syncthreads();
    float symv[4];
    {
        int l = tid & 31, kb = tid >> 5;
        for (int r = 0; r < 4; r++) {
            int k = kb + 8 * r;
            symv[r] = 0.5f * (Acs[k][l] + Acs[l][k]) + ((k == l) ? 1.f : 0.f);
        }
    }
    __syncthreads();
    {
        int l = tid & 31, kb = tid >> 5;
        for (int r = 0; r < 4; r++) Acs[kb + 8 * r][l] = symv[r];
    }
    __syncthreads();
    if (tid < K_) {
        float s = 0.f;
        for (int l = 0; l < K_; l++) s += Acs[tid][l];
        dinv[tid] = rsqrtf(fmaxf(s, 1e-8f));
    }
    __syncthreads();
    unsigned short* Anw = An + (size_t)win * K_ * K_;
    for (int i = tid; i < K_ * K_; i += 256) {
        int k = i >> 5, l = i & 31;
        Anw[i] = f2bf(dinv[k] * Acs[k][l] * dinv[l]);
    }
}

// ---------------------------------------------------------------------------
// Kernel 4: Xc[k][d] = sum_n S[n][k] * Hs[n][d], per window (fp32 out).
// ---------------------------------------------------------------------------
__global__ __launch_bounds__(256) void xc_kernel(
    const float* __restrict__ S, const unsigned short* __restrict__ Hs,
    float* __restrict__ Xc)
{
    __shared__ float Ss[N_ * K_];
    __shared__ float Hss[N_ * D_];
    const int tid = threadIdx.x;
    const int win = blockIdx.x;
    for (int i = tid; i < N_ * K_; i += 256) Ss[i] = S[(size_t)win * N_ * K_ + i];
    for (int i = tid; i < N_ * D_; i += 256) Hss[i] = bf2f(Hs[(size_t)win * N_ * D_ + i]);
    __syncthreads();
    const int dd = tid & 63, kb = tid >> 6;
    for (int r = 0; r < 8; r++) {
        int k = r * 4 + kb;
        float acc = 0.f;
        for (int n = 0; n < N_; n++) acc += Ss[n * K_ + k] * Hss[n * D_ + dd];
        Xc[((size_t)win * K_ + k) * D_ + dd] = acc;
    }
}

// ---------------------------------------------------------------------------
// Kernel 5: Hs mean over nodes -> Hsm[b,w,d] (fp32)
// ---------------------------------------------------------------------------
__global__ __launch_bounds__(64) void hsmean_kernel(
    const unsigned short* __restrict__ Hs, float* __restrict__ Hsm)
{
    const int win = blockIdx.x, dd = threadIdx.x;
    float acc = 0.f;
    for (int n = 0; n < N_; n++) acc += bf2f(Hs[((size_t)win * N_ + n) * D_ + dd]);
    Hsm[(size_t)win * D_ + dd] = acc * (1.f / N_);
}

// ---------------------------------------------------------------------------
// Kernel 6: Wh -> permuted transposed split-bf16  WhT[jj][h], jj = hcol*4+gate
// ---------------------------------------------------------------------------
__global__ __launch_bounds__(256) void whprep_kernel(
    const float* __restrict__ Wh, unsigned short* __restrict__ WhT_hi,
    unsigned short* __restrict__ WhT_lo)
{
    int i = blockIdx.x * 256 + threadIdx.x;   // 65536
    int jj = i >> 7, h = i & 127;
    int jg = (jj & 3) * HID_ + (jj >> 2);
    float v = Wh[h * G4_ + jg];
    unsigned short hi = f2bf(v);
    WhT_hi[i] = hi;
    WhT_lo[i] = f2bf(v - bf2f(hi));
}

// ---------------------------------------------------------------------------
// Kernel 7: XWx = (Xc @ Wx + bx + bh), bf16, stored in MFMA-C-fragment
// swizzled layout: XWx[((bt*64 + mt*32+nt)*64 + lane)*4 + r] where the
// value is row (mt*16+quad*4+r), col jj (nt*16+l15), lane = quad*16+l15.
// ---------------------------------------------------------------------------
__global__ __launch_bounds__(256) void xwx_kernel(
    const float* __restrict__ Xc, const float* __restrict__ Wx,
    const float* __restrict__ bx, const float* __restrict__ bh,
    unsigned short* __restrict__ XWx)
{
    __shared__ __align__(16) float Xs[32 * 68];
    __shared__ __align__(16) float Wxs[64 * 132];
    __shared__ float bs[128];
    const int tid = threadIdx.x;
    const int win = blockIdx.x;
    for (int i = tid; i < 2048; i += 256) {
        int c = i >> 6, d = i & 63;
        Xs[c * 68 + d] = Xc[(size_t)win * 2048 + i];
    }
    const int c = tid >> 3, jq = tid & 7;
    const int mt = c >> 4, quad = (c >> 2) & 3, r = c & 3;
    for (int chunk = 0; chunk < 4; chunk++) {
        __syncthreads();
        for (int i = tid; i < 8192; i += 256) {
            int d = i >> 7, jl = i & 127;
            int jjg = chunk * 128 + jl;
            int jg = (jjg & 3) * HID_ + (jjg >> 2);
            Wxs[d * 132 + jl] = Wx[d * G4_ + jg];
        }
        if (tid < 128) {
            int jjg = chunk * 128 + tid;
            int jg = (jjg & 3) * HID_ + (jjg >> 2);
            bs[tid] = bx[jg] + bh[jg];
        }
        __syncthreads();
        float acc[16];
        #pragma unroll
        for (int j = 0; j < 16; j++) acc[j] = bs[jq * 16 + j];
        for (int d = 0; d < 64; d++) {
            float xv = Xs[c * 68 + d];
            const float4* wp = (const float4*)&Wxs[d * 132 + jq * 16];
            #pragma unroll
            for (int j4 = 0; j4 < 4; j4++) {
                float4 w4 = wp[j4];
                acc[j4 * 4 + 0] += xv * w4.x; acc[j4 * 4 + 1] += xv * w4.y;
                acc[j4 * 4 + 2] += xv * w4.z; acc[j4 * 4 + 3] += xv * w4.w;
            }
        }
        const int nt = chunk * 8 + jq;
        #pragma unroll
        for (int j = 0; j < 16; j++) {
            size_t idx = (((size_t)win * 64 + mt * 32 + nt) * 64 + quad * 16 + j) * 4 + r;
            XWx[idx] = f2bf(acc[j]);
        }
    }
}

// ---------------------------------------------------------------------------
// Kernel 8: fused 100-step GCLSTM scan.  16 blocks x 512 threads (8 waves).
// One block barrier per step.  WhT fragments in registers; XWx/An prefetched
// one step ahead; gates directly in MFMA C-layout via g^T = tmp^T @ An^T;
// LSTM state in registers; Hsqm via shfl_xor reduce.
// ---------------------------------------------------------------------------
__global__ __launch_bounds__(512, 2) void scan_kernel(
    const unsigned short* __restrict__ An_bf,   // [bt][k][m]
    const unsigned short* __restrict__ XWxS,    // swizzled (see xwx_kernel)
    const unsigned short* __restrict__ WhT_hi,  // [jj][h]
    const unsigned short* __restrict__ WhT_lo,
    float* __restrict__ Hsqm)
{
    __shared__ __align__(16) unsigned short HpHi[2][32 * 136];
    __shared__ __align__(16) unsigned short HpLo[2][32 * 136];
    __shared__ __align__(16) unsigned short TmpT[512 * 40];   // [col jj][row k]

    const int tid  = threadIdx.x;
    const int lane = tid & 63;
    const int wv   = tid >> 6;          // 0..7
    const int b    = blockIdx.x;
    const int l15  = lane & 15, quad = lane >> 4;

    // ---- preload Wh fragments for this wave's 4 ntiles ----
    short8 Bhi[4][4], Blo[4][4];
    #pragma unroll
    for (int i = 0; i < 4; i++) {
        const int nt = wv + 8 * i;
        #pragma unroll
        for (int kb = 0; kb < 4; kb++) {
            size_t off = (size_t)(nt * 16 + l15) * 128 + kb * 32 + quad * 8;
            Bhi[i][kb] = *(const short8*)&WhT_hi[off];
            Blo[i][kb] = *(const short8*)&WhT_lo[off];
        }
    }
    // ---- state: (k = kt*16+l15, h = (wv+8i)*4+quad) ----
    float Cs_[2][4], Hs_[2][4], H2_[2][4];
    #pragma unroll
    for (int kt = 0; kt < 2; kt++)
        #pragma unroll
        for (int i = 0; i < 4; i++) { Cs_[kt][i] = 0.f; Hs_[kt][i] = 0.f; H2_[kt][i] = 0.f; }

    // ---- zero initial Hp buffer 0 ----
    for (int i = tid; i < 32 * 136; i += 512) { HpHi[0][i] = 0; HpLo[0][i] = 0; }

    // ---- prefetch t=0 ----
    uint2 xw[2][4];
    short8 anf[2];
    {
        const size_t bt = (size_t)b * WN_;
        const uint2* xp = (const uint2*)XWxS;
        #pragma unroll
        for (int mtp = 0; mtp < 2; mtp++)
            #pragma unroll
            for (int i = 0; i < 4; i++)
                xw[mtp][i] = xp[(bt * 64 + mtp * 32 + wv + 8 * i) * 64 + lane];
        #pragma unroll
        for (int kt = 0; kt < 2; kt++)
            anf[kt] = *(const short8*)&An_bf[bt * 1024 + (kt * 16 + l15) * 32 + quad * 8];
    }

    #pragma unroll 1
    for (int t = 0; t < WN_; t++) {
        const int buf = t & 1;
        __syncthreads();
        // ---- GEMM1: tmp[k_node][jj] = XWx + Hp @ Wh' (3-pass hi/lo) ----
        floatx4 acc[2][4];
        #pragma unroll
        for (int mtp = 0; mtp < 2; mtp++)
            #pragma unroll
            for (int i = 0; i < 4; i++) {
                acc[mtp][i][0] = bf2f((unsigned short)(xw[mtp][i].x & 0xffff));
                acc[mtp][i][1] = bf2f((unsigned short)(xw[mtp][i].x >> 16));
                acc[mtp][i][2] = bf2f((unsigned short)(xw[mtp][i].y & 0xffff));
                acc[mtp][i][3] = bf2f((unsigned short)(xw[mtp][i].y >> 16));
            }
        #pragma unroll
        for (int kb = 0; kb < 4; kb++) {
            const int ko = kb * 32 + quad * 8;
            short8 a0h = *(const short8*)&HpHi[buf][l15 * 136 + ko];
            short8 a0l = *(const short8*)&HpLo[buf][l15 * 136 + ko];
            short8 a1h = *(const short8*)&HpHi[buf][(16 + l15) * 136 + ko];
            short8 a1l = *(const short8*)&HpLo[buf][(16 + l15) * 136 + ko];
            #pragma unroll
            for (int i = 0; i < 4; i++) {
                acc[0][i] = __builtin_amdgcn_mfma_f32_16x16x32_bf16(a0h, Bhi[i][kb], acc[0][i], 0, 0, 0);
                acc[0][i] = __builtin_amdgcn_mfma_f32_16x16x32_bf16(a0h, Blo[i][kb], acc[0][i], 0, 0, 0);
                acc[0][i] = __builtin_amdgcn_mfma_f32_16x16x32_bf16(a0l, Bhi[i][kb], acc[0][i], 0, 0, 0);
                acc[1][i] = __builtin_amdgcn_mfma_f32_16x16x32_bf16(a1h, Bhi[i][kb], acc[1][i], 0, 0, 0);
                acc[1][i] = __builtin_amdgcn_mfma_f32_16x16x32_bf16(a1h, Blo[i][kb], acc[1][i], 0, 0, 0);
                acc[1][i] = __builtin_amdgcn_mfma_f32_16x16x32_bf16(a1l, Bhi[i][kb], acc[1][i], 0, 0, 0);
            }
        }
        // ---- write tmp^T to LDS (wave-private columns) ----
        #pragma unroll
        for (int i = 0; i < 4; i++) {
            const int col = (wv + 8 * i) * 16 + l15;
            #pragma unroll
            for (int mtp = 0; mtp < 2; mtp++) {
                uint2 pk;
                pk.x = (unsigned)f2bf(acc[mtp][i][0]) | ((unsigned)f2bf(acc[mtp][i][1]) << 16);
                pk.y = (unsigned)f2bf(acc[mtp][i][2]) | ((unsigned)f2bf(acc[mtp][i][3]) << 16);
                *(uint2*)&TmpT[col * 40 + mtp * 16 + quad * 4] = pk;
            }
        }
        __builtin_amdgcn_wave_barrier();
        // ---- GEMM2: g^T[jj][k] = tmp^T @ An^T (intra-wave LDS RAW) ----
        floatx4 g[2][4];
        #pragma unroll
        for (int i = 0; i < 4; i++) {
            const int jt = wv + 8 * i;
            short8 aT = *(const short8*)&TmpT[(jt * 16 + l15) * 40 + quad * 8];
            floatx4 z = {0.f, 0.f, 0.f, 0.f};
            g[0][i] = __builtin_amdgcn_mfma_f32_16x16x32_bf16(aT, anf[0], z, 0, 0, 0);
            g[1][i] = __builtin_amdgcn_mfma_f32_16x16x32_bf16(aT, anf[1], z, 0, 0, 0);
        }
        // ---- prefetch t+1 (clamped) ----
        {
            const int tn = (t + 1 < WN_) ? (t + 1) : (WN_ - 1);
            const size_t bt1 = (size_t)b * WN_ + tn;
            const uint2* xp = (const uint2*)XWxS;
            #pragma unroll
            for (int mtp = 0; mtp < 2; mtp++)
                #pragma unroll
                for (int i = 0; i < 4; i++)
                    xw[mtp][i] = xp[(bt1 * 64 + mtp * 32 + wv + 8 * i) * 64 + lane];
            #pragma unroll
            for (int kt = 0; kt < 2; kt++)
                anf[kt] = *(const short8*)&An_bf[bt1 * 1024 + (kt * 16 + l15) * 32 + quad * 8];
        }
        // ---- gates + state update (registers only) ----
        #pragma unroll
        for (int kt = 0; kt < 2; kt++)
            #pragma unroll
            for (int i = 0; i < 4; i++) {
                float gi = g[kt][i][0], gf = g[kt][i][1];
                float go = g[kt][i][2], gc = g[kt][i][3];
                float cn = sigf(gf) * Cs_[kt][i] + sigf(gi) * tanhfast(gc);
                float hn = sigf(go) * tanhfast(cn);
                Cs_[kt][i] = cn;
                H2_[kt][i] = Hs_[kt][i];
                Hs_[kt][i] = hn;
            }
        // ---- Hsqm: mean over k ----
        #pragma unroll
        for (int i = 0; i < 4; i++) {
            float s = Hs_[0][i] + Hs_[1][i];
            s += __shfl_xor(s, 1); s += __shfl_xor(s, 2);
            s += __shfl_xor(s, 4); s += __shfl_xor(s, 8);
            if (l15 == 0)
                Hsqm[((size_t)b * WN_ + t) * HID_ + (wv + 8 * i) * 4 + quad] = s * (1.f / 32.f);
        }
        // ---- write Hp(t+1) to buf^1 ----
        if (t + 1 < WN_) {
            const float dninv = (t + 1 == 1) ? 0.5f : (1.f / 3.f);
            #pragma unroll
            for (int kt = 0; kt < 2; kt++)
                #pragma unroll
                for (int i = 0; i < 4; i++) {
                    float v = (2.f * Hs_[kt][i] + H2_[kt][i]) * dninv;
                    unsigned short hi = f2bf(v);
                    const int addr = (kt * 16 + l15) * 136 + (wv + 8 * i) * 4 + quad;
                    HpHi[buf ^ 1][addr] = hi;
                    HpLo[buf ^ 1][addr] = f2bf(v - bf2f(hi));
                }
        }
    }
}

// ---------------------------------------------------------------------------
// Kernel 9: temporal attention pooling + classifier.  One block per b.
// ---------------------------------------------------------------------------
__global__ __launch_bounds__(128) void final_kernel(
    const float* __restrict__ Hsqm, const float* __restrict__ Hsm,
    const float* __restrict__ q_t, const float* __restrict__ q_s,
    const float* __restrict__ cls_w, const float* __restrict__ cls_b,
    float* __restrict__ out)
{
    __shared__ float red[128];
    __shared__ float sc[WN_];
    __shared__ float wt[WN_];
    __shared__ float smv;
    const int b = blockIdx.x, tid = threadIdx.x;
    float v = q_t[tid];
    red[tid] = v * v;
    __syncthreads();
    for (int off = 64; off; off >>= 1) {
        if (tid < off) red[tid] += red[tid + off];
        __syncthreads();
    }
    const float qtn = sqrtf(red[0]) + 1e-8f;
    __syncthreads();
    float v2 = (tid < D_) ? q_s[tid] : 0.f;
    red[tid] = v2 * v2;
    __syncthreads();
    for (int off = 64; off; off >>= 1) {
        if (tid < off) red[tid] += red[tid + off];
        __syncthreads();
    }
    const float qsn = sqrtf(red[0]) + 1e-8f;
    __syncthreads();
    if (tid < WN_) {
        float s = 0.f;
        const float* zr = Hsqm + ((size_t)b * WN_ + tid) * HID_;
        for (int h = 0; h < HID_; h++) s += zr[h] * q_t[h];
        sc[tid] = s / qtn;
    }
    __syncthreads();
    if (tid == 0) {
        float m = sc[0];
        for (int i = 1; i < WN_; i++) m = fmaxf(m, sc[i]);
        float s = 0.f;
        for (int i = 0; i < WN_; i++) { wt[i] = expf(sc[i] - m); s += wt[i]; }
        smv = 1.f / s;
    }
    __syncthreads();
    float part = 0.f;
    {
        float z = 0.f;
        for (int w = 0; w < WN_; w++)
            z += wt[w] * Hsqm[((size_t)b * WN_ + w) * HID_ + tid];
        part += z * smv * cls_w[tid];
    }
    __syncthreads();
    if (tid < WN_) {
        float s = 0.f;
        const float* zr = Hsm + ((size_t)b * WN_ + tid) * D_;
        for (int dd = 0; dd < D_; dd++) s += zr[dd] * q_s[dd];
        sc[tid] = s / qsn;
    }
    __syncthreads();
    if (tid == 0) {
        float m = sc[0];
        for (int i = 1; i < WN_; i++) m = fmaxf(m, sc[i]);
        float s = 0.f;
        for (int i = 0; i < WN_; i++) { wt[i] = expf(sc[i] - m); s += wt[i]; }
        smv = 1.f / s;
    }
    __syncthreads();
    if (tid < D_) {
        float z = 0.f;
        for (int w = 0; w < WN_; w++)
            z += wt[w] * Hsm[((size_t)b * WN_ + w) * D_ + tid];
        part += z * smv * cls_w[HID_ + tid];
    }
    red[tid] = part;
    __syncthreads();
    for (int off = 64; off; off >>= 1) {
        if (tid < off) red[tid] += red[tid + off];
        __syncthreads();
    }
    if (tid == 0) out[b] = 1.f / (1.f + expf(-(red[0] + cls_b[0])));
}

// ---------------------------------------------------------------------------
extern "C" void kernel_launch(void* const* d_in, const int* in_sizes, int n_in,
                              void* d_out, int out_size, void* d_ws, size_t ws_size,
                              hipStream_t stream)
{
    (void)in_sizes; (void)n_in; (void)out_size; (void)ws_size;
    const float* x     = (const float*)d_in[0];
    const float* w1    = (const float*)d_in[1];
    const float* b1    = (const float*)d_in[2];
    const float* w2    = (const float*)d_in[3];
    const float* b2    = (const float*)d_in[4];
    const float* pw    = (const float*)d_in[5];
    const float* pb    = (const float*)d_in[6];
    const float* proto = (const float*)d_in[7];
    const float* Wx    = (const float*)d_in[8];
    const float* bx    = (const float*)d_in[9];
    const float* Wh    = (const float*)d_in[10];
    const float* bh    = (const float*)d_in[11];
    const float* q_t   = (const float*)d_in[12];
    const float* q_s   = (const float*)d_in[13];
    const float* clw   = (const float*)d_in[14];
    const float* clb   = (const float*)d_in[15];

    float* ws = (float*)d_ws;
    unsigned short* Hs_bf  = (unsigned short*)d_ws;
    float*          S      = ws + 6553600;
    float*          Xc     = ws + 13107200;
    unsigned short* An_bf  = (unsigned short*)(ws + 16384000);
    float*          Hsm    = ws + 17203200;
    float*          Hsqm   = ws + 17305600;
    unsigned short* WhT_hi = (unsigned short*)(ws + 17510400);
    unsigned short* WhT_lo = (unsigned short*)(ws + 17543168);
    unsigned short* XWx    = (unsigned short*)d_ws;   // overlays Hs+S

    conv_kernel<<<B_ * WN_, 256, 0, stream>>>(x, w1, b1, w2, b2, pw, pb, Hs_bf);
    s_kernel<<<(B_ * WN_ * N_) / 8, 256, 0, stream>>>(Hs_bf, proto, S);
    corr_kernel<<<B_ * WN_, 256, 0, stream>>>(x, S, An_bf);
    xc_kernel<<<B_ * WN_, 256, 0, stream>>>(S, Hs_bf, Xc);
    hsmean_kernel<<<B_ * WN_, 64, 0, stream>>>(Hs_bf, Hsm);
    whprep_kernel<<<256, 256, 0, stream>>>(Wh, WhT_hi, WhT_lo);
    xwx_kernel<<<B_ * WN_, 256, 0, stream>>>(Xc, Wx, bx, bh, XWx);
    scan_kernel<<<B_, 512, 0, stream>>>(An_bf, XWx, WhT_hi, WhT_lo, Hsqm);
    final_kernel<<<B_, 128, 0, stream>>>(Hsqm, Hsm, q_t, q_s, clw, clb,
                                         (float*)d_out);
}

// Round 5
// 1369.088 us; speedup vs baseline: 2.3314x; 1.0984x over previous
//
#include <hip/hip_runtime.h>

#define B_   16
#define T_   3000
#define N_   128
#define WIN_ 30
#define WN_  100
#define D_   64
#define HID_ 128
#define K_   32
#define G4_  512   // 4*HID_

typedef __attribute__((ext_vector_type(8))) short short8;
typedef __attribute__((ext_vector_type(4))) float floatx4;

__device__ __forceinline__ unsigned short f2bf(float f) {
    unsigned u = __float_as_uint(f);
    u += 0x7fffu + ((u >> 16) & 1u);
    return (unsigned short)(u >> 16);
}
__device__ __forceinline__ float bf2f(unsigned short h) {
    return __uint_as_float(((unsigned)h) << 16);
}
__device__ __forceinline__ float sigf(float x) { return 1.f / (1.f + __expf(-x)); }
__device__ __forceinline__ float tanhfast(float x) { return 2.f / (1.f + __expf(-2.f * x)) - 1.f; }

// ---------------------------------------------------------------------------
// Kernel 1: SignalRep — conv1 (fp32 VALU), conv2 (bf16 MFMA, 5 shifted-dk
// passes, w2 hi/lo split), mean, proj.  One block per window; 16 groups of
// 8 sequences.  h1 in LDS as B-operand layout [seq][t'][ci], stride 40.
// ---------------------------------------------------------------------------
__global__ __launch_bounds__(256) void conv_kernel(
    const float* __restrict__ x, const float* __restrict__ w1,
    const float* __restrict__ b1, const float* __restrict__ w2,
    const float* __restrict__ b2, const float* __restrict__ pw,
    const float* __restrict__ pb, unsigned short* __restrict__ Hs)
{
    __shared__ __align__(16) unsigned short h1s[8 * 36 * 40];
    __shared__ __align__(16) unsigned short Cs[256 * 36];
    __shared__ float xs[8 * 32];
    __shared__ float pws[32 * 64];
    __shared__ float means[8 * 33];
    const int tid = threadIdx.x;
    const int win = blockIdx.x;
    const int b = win / WN_, w = win - b * WN_;
    const float* xb = x + ((size_t)b * T_ + (size_t)w * WIN_) * N_;

    const int lane = tid & 63, wv = tid >> 6;
    const int l15 = lane & 15, quad = lane >> 4;
    const int mt = wv >> 1;
    const int ntp = wv & 1;

    for (int i = tid; i < 2048; i += 256) pws[i] = pw[i];
    for (int i = tid; i < 1920; i += 256) {
        int s = i / 240, r = i % 240;
        int ti = r / 40, c = r % 40;
        int tp = (ti < 2) ? ti : (30 + ti);
        h1s[(s * 36 + tp) * 40 + c] = 0;
    }
    short8 ahf[5], alf[5];
    #pragma unroll
    for (int dk = 0; dk < 5; dk++) {
        #pragma unroll
        for (int j = 0; j < 8; j++) {
            float v = w2[(mt * 16 + l15) * 160 + (quad * 8 + j) * 5 + dk];
            unsigned short hi = f2bf(v);
            ahf[dk][j] = (short)hi;
            alf[dk][j] = (short)f2bf(v - bf2f(hi));
        }
    }
    float b2v[4];
    #pragma unroll
    for (int r = 0; r < 4; r++) b2v[r] = b2[mt * 16 + quad * 4 + r];
    const int s1 = tid >> 5, ci1 = tid & 31;
    float w1r[5];
    #pragma unroll
    for (int k = 0; k < 5; k++) w1r[k] = w1[ci1 * 5 + k];
    const float b1v = b1[ci1];
    const int d2 = tid & 31;
    const float pbv0 = pb[2 * d2], pbv1 = pb[2 * d2 + 1];

    for (int g = 0; g < 16; g++) {
        const int n0 = g * 8;
        if (tid < 240) {
            int t = tid >> 3, s = tid & 7;
            xs[s * 32 + t] = xb[t * N_ + n0 + s];
        }
        __syncthreads();
        {
            float xr[30];
            #pragma unroll
            for (int t = 0; t < 30; t++) xr[t] = xs[s1 * 32 + t];
            #pragma unroll
            for (int t = 0; t < 30; t++) {
                float acc = b1v;
                #pragma unroll
                for (int k = 0; k < 5; k++) {
                    int p = t + k - 2;
                    if (p >= 0 && p < 30) acc += xr[p] * w1r[k];
                }
                h1s[(s1 * 36 + 2 + t) * 40 + ci1] = f2bf(fmaxf(acc, 0.f));
            }
        }
        __syncthreads();
        #pragma unroll 1
        for (int i = 0; i < 8; i++) {
            const int nt = ntp + 2 * i;
            const int c = nt * 16 + l15;
            const int s = c >> 5, tq = c & 31;
            floatx4 acc;
            #pragma unroll
            for (int r = 0; r < 4; r++) acc[r] = b2v[r];
            #pragma unroll
            for (int dk = 0; dk < 5; dk++) {
                short8 bfrag = *(const short8*)&h1s[(s * 36 + tq + dk) * 40 + quad * 8];
                acc = __builtin_amdgcn_mfma_f32_16x16x32_bf16(ahf[dk], bfrag, acc, 0, 0, 0);
                acc = __builtin_amdgcn_mfma_f32_16x16x32_bf16(alf[dk], bfrag, acc, 0, 0, 0);
            }
            if (tq < 30) {
                unsigned p0 = (unsigned)f2bf(fmaxf(acc[0], 0.f))
                            | ((unsigned)f2bf(fmaxf(acc[1], 0.f)) << 16);
                unsigned p1 = (unsigned)f2bf(fmaxf(acc[2], 0.f))
                            | ((unsigned)f2bf(fmaxf(acc[3], 0.f)) << 16);
                unsigned* cp = (unsigned*)&Cs[c * 36 + mt * 16 + quad * 4];
                cp[0] = p0; cp[1] = p1;
            }
        }
        __syncthreads();
        {
            float acc = 0.f;
            #pragma unroll
            for (int t = 0; t < 30; t++)
                acc += bf2f(Cs[(s1 * 32 + t) * 36 + ci1]);
            means[s1 * 33 + ci1] = acc * (1.f / 30.f);
        }
        __syncthreads();
        {
            float o0 = pbv0, o1 = pbv1;
            #pragma unroll 8
            for (int co = 0; co < 32; co++) {
                float m = means[s1 * 33 + co];
                o0 += m * pws[co * 64 + 2 * d2];
                o1 += m * pws[co * 64 + 2 * d2 + 1];
            }
            unsigned pk = (unsigned)f2bf(o0) | ((unsigned)f2bf(o1) << 16);
            unsigned* hp = (unsigned*)(Hs + (size_t)win * (N_ * D_) + (size_t)(n0 + s1) * D_);
            hp[d2] = pk;
        }
        __syncthreads();
    }
}

// ---------------------------------------------------------------------------
// Kernel 2: S = softmax_k(Hs @ proto^T). One 32-lane group per (b,w,n).
// ---------------------------------------------------------------------------
__global__ __launch_bounds__(256) void s_kernel(
    const unsigned short* __restrict__ Hs, const float* __restrict__ proto,
    float* __restrict__ S)
{
    const int tid = threadIdx.x;
    const int lane = tid & 63;
    const int gw = blockIdx.x * 4 + (tid >> 6);
    const int sub = lane >> 5, kk = lane & 31;
    const size_t nid = (size_t)gw * 2 + sub;
    const unsigned short* h = Hs + nid * D_;
    const float* p = proto + (size_t)kk * D_;
    float l = 0.f;
    #pragma unroll
    for (int d = 0; d < D_; d++) l += bf2f(h[d]) * p[d];
    float m = l;
    for (int off = 16; off; off >>= 1) m = fmaxf(m, __shfl_xor(m, off));
    float e = expf(l - m);
    float s = e;
    for (int off = 16; off; off >>= 1) s += __shfl_xor(s, off);
    S[nid * K_ + kk] = e / s;
}

// ---------------------------------------------------------------------------
// Kernel 3: corr -> AS -> Ac -> normalize -> An (bf16 out)
// ---------------------------------------------------------------------------
__global__ __launch_bounds__(256) void corr_kernel(
    const float* __restrict__ x, const float* __restrict__ S,
    unsigned short* __restrict__ An)
{
    __shared__ float xs[WIN_ * N_];
    __shared__ float sinv[N_];
    __shared__ float Ss[N_ * K_];
    __shared__ float ASs[N_ * K_];
    __shared__ float Arow[4][N_];
    __shared__ float Acs[K_][K_ + 1];
    __shared__ float dinv[K_];
    const int tid = threadIdx.x;
    const int win = blockIdx.x;
    const int b = win / WN_, w = win - b * WN_;
    const float* xb = x + ((size_t)b * T_ + (size_t)w * WIN_) * N_;
    for (int i = tid; i < WIN_ * N_; i += 256) xs[i] = xb[i];
    for (int i = tid; i < N_ * K_; i += 256) Ss[i] = S[(size_t)win * N_ * K_ + i];
    __syncthreads();
    if (tid < N_) {
        int n = tid;
        float mean = 0.f;
        for (int l = 0; l < WIN_; l++) mean += xs[l * N_ + n];
        mean *= (1.f / WIN_);
        float var = 0.f;
        for (int l = 0; l < WIN_; l++) {
            float v = xs[l * N_ + n] - mean;
            xs[l * N_ + n] = v;
            var += v * v;
        }
        var *= (1.f / (WIN_ - 1 + 1e-8f));
        sinv[n] = rsqrtf(fmaxf(var, 1e-8f));
    }
    __syncthreads();
    const int lane = tid & 63, wid = tid >> 6;
    const int l32 = lane & 31, hf = lane >> 5;
    for (int n = wid; n < N_; n += 4) {
        float sn = sinv[n];
        #pragma unroll
        for (int mm = 0; mm < 2; mm++) {
            int m = lane + 64 * mm;
            float cov = 0.f;
            for (int l = 0; l < WIN_; l++) cov += xs[l * N_ + n] * xs[l * N_ + m];
            float a = cov * (1.f / (WIN_ - 1 + 1e-8f)) * sn * sinv[m];
            Arow[wid][m] = (m == n) ? 1.f : a;
        }
        __builtin_amdgcn_wave_barrier();
        float p = 0.f;
        for (int m = hf * 64; m < hf * 64 + 64; m++)
            p += Arow[wid][m] * Ss[m * K_ + l32];
        p += __shfl_down(p, 32);
        if (hf == 0) ASs[n * K_ + l32] = p;
        __builtin_amdgcn_wave_barrier();
    }
    __syncthreads();
    {
        int l = tid & 31, kb = tid >> 5;
        for (int r = 0; r < 4; r++) {
            int k = kb + 8 * r;
            float acc = 0.f;
            for (int n = 0; n < N_; n++) acc += Ss[n * K_ + k] * ASs[n * K_ + l];
            Acs[k][l] = acc;
        }
    }
    __syncthreads();
    float symv[4];
    {
        int l = tid & 31, kb = tid >> 5;
        for (int r = 0; r < 4; r++) {
            int k = kb + 8 * r;
            symv[r] = 0.5f * (Acs[k][l] + Acs[l][k]) + ((k == l) ? 1.f : 0.f);
        }
    }
    __syncthreads();
    {
        int l = tid & 31, kb = tid >> 5;
        for (int r = 0; r < 4; r++) Acs[kb + 8 * r][l] = symv[r];
    }
    __syncthreads();
    if (tid < K_) {
        float s = 0.f;
        for (int l = 0; l < K_; l++) s += Acs[tid][l];
        dinv[tid] = rsqrtf(fmaxf(s, 1e-8f));
    }
    __syncthreads();
    unsigned short* Anw = An + (size_t)win * K_ * K_;
    for (int i = tid; i < K_ * K_; i += 256) {
        int k = i >> 5, l = i & 31;
        Anw[i] = f2bf(dinv[k] * Acs[k][l] * dinv[l]);
    }
}

// ---------------------------------------------------------------------------
// Kernel 4: Xc[k][d] = sum_n S[n][k] * Hs[n][d], per window (fp32 out).
// ---------------------------------------------------------------------------
__global__ __launch_bounds__(256) void xc_kernel(
    const float* __restrict__ S, const unsigned short* __restrict__ Hs,
    float* __restrict__ Xc)
{
    __shared__ float Ss[N_ * K_];
    __shared__ float Hss[N_ * D_];
    const int tid = threadIdx.x;
    const int win = blockIdx.x;
    for (int i = tid; i < N_ * K_; i += 256) Ss[i] = S[(size_t)win * N_ * K_ + i];
    for (int i = tid; i < N_ * D_; i += 256) Hss[i] = bf2f(Hs[(size_t)win * N_ * D_ + i]);
    __syncthreads();
    const int dd = tid & 63, kb = tid >> 6;
    for (int r = 0; r < 8; r++) {
        int k = r * 4 + kb;
        float acc = 0.f;
        for (int n = 0; n < N_; n++) acc += Ss[n * K_ + k] * Hss[n * D_ + dd];
        Xc[((size_t)win * K_ + k) * D_ + dd] = acc;
    }
}

// ---------------------------------------------------------------------------
// Kernel 5: Hs mean over nodes -> Hsm[b,w,d] (fp32)
// ---------------------------------------------------------------------------
__global__ __launch_bounds__(64) void hsmean_kernel(
    const unsigned short* __restrict__ Hs, float* __restrict__ Hsm)
{
    const int win = blockIdx.x, dd = threadIdx.x;
    float acc = 0.f;
    for (int n = 0; n < N_; n++) acc += bf2f(Hs[((size_t)win * N_ + n) * D_ + dd]);
    Hsm[(size_t)win * D_ + dd] = acc * (1.f / N_);
}

// ---------------------------------------------------------------------------
// Kernel 6: Wh -> permuted transposed bf16  WhT[jj][h], jj = hcol*4+gate
// ---------------------------------------------------------------------------
__global__ __launch_bounds__(256) void whprep_kernel(
    const float* __restrict__ Wh, unsigned short* __restrict__ WhT_hi)
{
    int i = blockIdx.x * 256 + threadIdx.x;   // 65536
    int jj = i >> 7, h = i & 127;
    int jg = (jj & 3) * HID_ + (jj >> 2);
    WhT_hi[i] = f2bf(Wh[h * G4_ + jg]);
}

// ---------------------------------------------------------------------------
// Kernel 7: XWx = (Xc @ Wx + bx + bh), bf16, stored in MFMA-C-fragment
// swizzled layout: XWx[((bt*64 + mt*32+nt)*64 + lane)*4 + r] where the
// value is row (mt*16+quad*4+r), col jj (nt*16+l15), lane = quad*16+l15.
// ---------------------------------------------------------------------------
__global__ __launch_bounds__(256) void xwx_kernel(
    const float* __restrict__ Xc, const float* __restrict__ Wx,
    const float* __restrict__ bx, const float* __restrict__ bh,
    unsigned short* __restrict__ XWx)
{
    __shared__ __align__(16) float Xs[32 * 68];
    __shared__ __align__(16) float Wxs[64 * 132];
    __shared__ float bs[128];
    const int tid = threadIdx.x;
    const int win = blockIdx.x;
    for (int i = tid; i < 2048; i += 256) {
        int c = i >> 6, d = i & 63;
        Xs[c * 68 + d] = Xc[(size_t)win * 2048 + i];
    }
    const int c = tid >> 3, jq = tid & 7;
    const int mt = c >> 4, quad = (c >> 2) & 3, r = c & 3;
    for (int chunk = 0; chunk < 4; chunk++) {
        __syncthreads();
        for (int i = tid; i < 8192; i += 256) {
            int d = i >> 7, jl = i & 127;
            int jjg = chunk * 128 + jl;
            int jg = (jjg & 3) * HID_ + (jjg >> 2);
            Wxs[d * 132 + jl] = Wx[d * G4_ + jg];
        }
        if (tid < 128) {
            int jjg = chunk * 128 + tid;
            int jg = (jjg & 3) * HID_ + (jjg >> 2);
            bs[tid] = bx[jg] + bh[jg];
        }
        __syncthreads();
        float acc[16];
        #pragma unroll
        for (int j = 0; j < 16; j++) acc[j] = bs[jq * 16 + j];
        for (int d = 0; d < 64; d++) {
            float xv = Xs[c * 68 + d];
            const float4* wp = (const float4*)&Wxs[d * 132 + jq * 16];
            #pragma unroll
            for (int j4 = 0; j4 < 4; j4++) {
                float4 w4 = wp[j4];
                acc[j4 * 4 + 0] += xv * w4.x; acc[j4 * 4 + 1] += xv * w4.y;
                acc[j4 * 4 + 2] += xv * w4.z; acc[j4 * 4 + 3] += xv * w4.w;
            }
        }
        const int nt = chunk * 8 + jq;
        #pragma unroll
        for (int j = 0; j < 16; j++) {
            size_t idx = (((size_t)win * 64 + mt * 32 + nt) * 64 + quad * 16 + j) * 4 + r;
            XWx[idx] = f2bf(acc[j]);
        }
    }
}

// ---------------------------------------------------------------------------
// Kernel 8: fused 100-step GCLSTM scan.  16 blocks x 1024 threads (16 waves,
// 4/SIMD).  One block barrier per step.  Single-pass bf16 GEMM1 (Wh plain
// bf16); per-wave Wh fragments = 32 VGPRs (register-resident); XWx/An
// prefetched one step ahead; gates in MFMA C-layout; state in registers.
// ---------------------------------------------------------------------------
__global__ __launch_bounds__(1024) void scan_kernel(
    const unsigned short* __restrict__ An_bf,   // [bt][k][m]
    const unsigned short* __restrict__ XWxS,    // swizzled (see xwx_kernel)
    const unsigned short* __restrict__ WhT,     // [jj][h]
    float* __restrict__ Hsqm)
{
    __shared__ __align__(16) unsigned short HpHi[2][32 * 136];
    __shared__ __align__(16) unsigned short TmpT[512 * 40];   // [col jj][row k]

    const int tid  = threadIdx.x;
    const int lane = tid & 63;
    const int wv   = tid >> 6;          // 0..15
    const int b    = blockIdx.x;
    const int l15  = lane & 15, quad = lane >> 4;

    // ---- Wh fragments for this wave's 2 ntiles (8 frags = 32 VGPRs) ----
    short8 Bw[2][4];
    #pragma unroll
    for (int i = 0; i < 2; i++) {
        const int nt = wv + 16 * i;
        #pragma unroll
        for (int kb = 0; kb < 4; kb++)
            Bw[i][kb] = *(const short8*)&WhT[(size_t)(nt * 16 + l15) * 128 + kb * 32 + quad * 8];
    }
    // ---- state: (k = kt*16+l15, h = (wv+16i)*4+quad) ----
    float Cs_[2][2], Hs_[2][2], H2_[2][2];
    #pragma unroll
    for (int kt = 0; kt < 2; kt++)
        #pragma unroll
        for (int i = 0; i < 2; i++) { Cs_[kt][i] = 0.f; Hs_[kt][i] = 0.f; H2_[kt][i] = 0.f; }

    for (int i = tid; i < 32 * 136; i += 1024) HpHi[0][i] = 0;

    // ---- prefetch t=0 ----
    uint2 xw[2][2];
    short8 anf[2];
    {
        const size_t bt = (size_t)b * WN_;
        const uint2* xp = (const uint2*)XWxS;
        #pragma unroll
        for (int mtp = 0; mtp < 2; mtp++)
            #pragma unroll
            for (int i = 0; i < 2; i++)
                xw[mtp][i] = xp[(bt * 64 + mtp * 32 + wv + 16 * i) * 64 + lane];
        #pragma unroll
        for (int kt = 0; kt < 2; kt++)
            anf[kt] = *(const short8*)&An_bf[bt * 1024 + (kt * 16 + l15) * 32 + quad * 8];
    }

    #pragma unroll 1
    for (int t = 0; t < WN_; t++) {
        const int buf = t & 1;
        __syncthreads();
        // ---- GEMM1: tmp[m][jj] = XWx + Hp @ Wh' (single-pass bf16) ----
        floatx4 acc[2][2];
        #pragma unroll
        for (int mtp = 0; mtp < 2; mtp++)
            #pragma unroll
            for (int i = 0; i < 2; i++) {
                acc[mtp][i][0] = bf2f((unsigned short)(xw[mtp][i].x & 0xffff));
                acc[mtp][i][1] = bf2f((unsigned short)(xw[mtp][i].x >> 16));
                acc[mtp][i][2] = bf2f((unsigned short)(xw[mtp][i].y & 0xffff));
                acc[mtp][i][3] = bf2f((unsigned short)(xw[mtp][i].y >> 16));
            }
        #pragma unroll
        for (int kb = 0; kb < 4; kb++) {
            const int ko = kb * 32 + quad * 8;
            short8 a0 = *(const short8*)&HpHi[buf][l15 * 136 + ko];
            short8 a1 = *(const short8*)&HpHi[buf][(16 + l15) * 136 + ko];
            #pragma unroll
            for (int i = 0; i < 2; i++) {
                acc[0][i] = __builtin_amdgcn_mfma_f32_16x16x32_bf16(a0, Bw[i][kb], acc[0][i], 0, 0, 0);
                acc[1][i] = __builtin_amdgcn_mfma_f32_16x16x32_bf16(a1, Bw[i][kb], acc[1][i], 0, 0, 0);
            }
        }
        // ---- write tmp^T to LDS (wave-private columns) ----
        #pragma unroll
        for (int i = 0; i < 2; i++) {
            const int col = (wv + 16 * i) * 16 + l15;
            #pragma unroll
            for (int mtp = 0; mtp < 2; mtp++) {
                uint2 pk;
                pk.x = (unsigned)f2bf(acc[mtp][i][0]) | ((unsigned)f2bf(acc[mtp][i][1]) << 16);
                pk.y = (unsigned)f2bf(acc[mtp][i][2]) | ((unsigned)f2bf(acc[mtp][i][3]) << 16);
                *(uint2*)&TmpT[col * 40 + mtp * 16 + quad * 4] = pk;
            }
        }
        __builtin_amdgcn_wave_barrier();
        // ---- GEMM2: g^T[jj][k] = tmp^T @ An^T (intra-wave LDS RAW) ----
        floatx4 g[2][2];
        #pragma unroll
        for (int i = 0; i < 2; i++) {
            const int jt = wv + 16 * i;
            short8 aT = *(const short8*)&TmpT[(jt * 16 + l15) * 40 + quad * 8];
            floatx4 z = {0.f, 0.f, 0.f, 0.f};
            g[0][i] = __builtin_amdgcn_mfma_f32_16x16x32_bf16(aT, anf[0], z, 0, 0, 0);
            g[1][i] = __builtin_amdgcn_mfma_f32_16x16x32_bf16(aT, anf[1], z, 0, 0, 0);
        }
        // ---- prefetch t+1 (clamped) ----
        {
            const int tn = (t + 1 < WN_) ? (t + 1) : (WN_ - 1);
            const size_t bt1 = (size_t)b * WN_ + tn;
            const uint2* xp = (const uint2*)XWxS;
            #pragma unroll
            for (int mtp = 0; mtp < 2; mtp++)
                #pragma unroll
                for (int i = 0; i < 2; i++)
                    xw[mtp][i] = xp[(bt1 * 64 + mtp * 32 + wv + 16 * i) * 64 + lane];
            #pragma unroll
            for (int kt = 0; kt < 2; kt++)
                anf[kt] = *(const short8*)&An_bf[bt1 * 1024 + (kt * 16 + l15) * 32 + quad * 8];
        }
        // ---- gates + state update (registers only) ----
        #pragma unroll
        for (int kt = 0; kt < 2; kt++)
            #pragma unroll
            for (int i = 0; i < 2; i++) {
                float gi = g[kt][i][0], gf = g[kt][i][1];
                float go = g[kt][i][2], gc = g[kt][i][3];
                float cn = sigf(gf) * Cs_[kt][i] + sigf(gi) * tanhfast(gc);
                float hn = sigf(go) * tanhfast(cn);
                Cs_[kt][i] = cn;
                H2_[kt][i] = Hs_[kt][i];
                Hs_[kt][i] = hn;
            }
        // ---- Hsqm: mean over k ----
        #pragma unroll
        for (int i = 0; i < 2; i++) {
            float s = Hs_[0][i] + Hs_[1][i];
            s += __shfl_xor(s, 1); s += __shfl_xor(s, 2);
            s += __shfl_xor(s, 4); s += __shfl_xor(s, 8);
            if (l15 == 0)
                Hsqm[((size_t)b * WN_ + t) * HID_ + (wv + 16 * i) * 4 + quad] = s * (1.f / 32.f);
        }
        // ---- write Hp(t+1) to buf^1 ----
        if (t + 1 < WN_) {
            const float dninv = (t + 1 == 1) ? 0.5f : (1.f / 3.f);
            #pragma unroll
            for (int kt = 0; kt < 2; kt++)
                #pragma unroll
                for (int i = 0; i < 2; i++) {
                    float v = (2.f * Hs_[kt][i] + H2_[kt][i]) * dninv;
                    const int addr = (kt * 16 + l15) * 136 + (wv + 16 * i) * 4 + quad;
                    HpHi[buf ^ 1][addr] = f2bf(v);
                }
        }
    }
}

// ---------------------------------------------------------------------------
// Kernel 9: temporal attention pooling + classifier.  One block per b.
// ---------------------------------------------------------------------------
__global__ __launch_bounds__(128) void final_kernel(
    const float* __restrict__ Hsqm, const float* __restrict__ Hsm,
    const float* __restrict__ q_t, const float* __restrict__ q_s,
    const float* __restrict__ cls_w, const float* __restrict__ cls_b,
    float* __restrict__ out)
{
    __shared__ float red[128];
    __shared__ float sc[WN_];
    __shared__ float wt[WN_];
    __shared__ float smv;
    const int b = blockIdx.x, tid = threadIdx.x;
    float v = q_t[tid];
    red[tid] = v * v;
    __syncthreads();
    for (int off = 64; off; off >>= 1) {
        if (tid < off) red[tid] += red[tid + off];
        __syncthreads();
    }
    const float qtn = sqrtf(red[0]) + 1e-8f;
    __syncthreads();
    float v2 = (tid < D_) ? q_s[tid] : 0.f;
    red[tid] = v2 * v2;
    __syncthreads();
    for (int off = 64; off; off >>= 1) {
        if (tid < off) red[tid] += red[tid + off];
        __syncthreads();
    }
    const float qsn = sqrtf(red[0]) + 1e-8f;
    __syncthreads();
    if (tid < WN_) {
        float s = 0.f;
        const float* zr = Hsqm + ((size_t)b * WN_ + tid) * HID_;
        for (int h = 0; h < HID_; h++) s += zr[h] * q_t[h];
        sc[tid] = s / qtn;
    }
    __syncthreads();
    if (tid == 0) {
        float m = sc[0];
        for (int i = 1; i < WN_; i++) m = fmaxf(m, sc[i]);
        float s = 0.f;
        for (int i = 0; i < WN_; i++) { wt[i] = expf(sc[i] - m); s += wt[i]; }
        smv = 1.f / s;
    }
    __syncthreads();
    float part = 0.f;
    {
        float z = 0.f;
        for (int w = 0; w < WN_; w++)
            z += wt[w] * Hsqm[((size_t)b * WN_ + w) * HID_ + tid];
        part += z * smv * cls_w[tid];
    }
    __syncthreads();
    if (tid < WN_) {
        float s = 0.f;
        const float* zr = Hsm + ((size_t)b * WN_ + tid) * D_;
        for (int dd = 0; dd < D_; dd++) s += zr[dd] * q_s[dd];
        sc[tid] = s / qsn;
    }
    __syncthreads();
    if (tid == 0) {
        float m = sc[0];
        for (int i = 1; i < WN_; i++) m = fmaxf(m, sc[i]);
        float s = 0.f;
        for (int i = 0; i < WN_; i++) { wt[i] = expf(sc[i] - m); s += wt[i]; }
        smv = 1.f / s;
    }
    __syncthreads();
    if (tid < D_) {
        float z = 0.f;
        for (int w = 0; w < WN_; w++)
            z += wt[w] * Hsm[((size_t)b * WN_ + w) * D_ + tid];
        part += z * smv * cls_w[HID_ + tid];
    }
    red[tid] = part;
    __syncthreads();
    for (int off = 64; off; off >>= 1) {
        if (tid < off) red[tid] += red[tid + off];
        __syncthreads();
    }
    if (tid == 0) out[b] = 1.f / (1.f + expf(-(red[0] + cls_b[0])));
}

// ---------------------------------------------------------------------------
extern "C" void kernel_launch(void* const* d_in, const int* in_sizes, int n_in,
                              void* d_out, int out_size, void* d_ws, size_t ws_size,
                              hipStream_t stream)
{
    (void)in_sizes; (void)n_in; (void)out_size; (void)ws_size;
    const float* x     = (const float*)d_in[0];
    const float* w1    = (const float*)d_in[1];
    const float* b1    = (const float*)d_in[2];
    const float* w2    = (const float*)d_in[3];
    const float* b2    = (const float*)d_in[4];
    const float* pw    = (const float*)d_in[5];
    const float* pb    = (const float*)d_in[6];
    const float* proto = (const float*)d_in[7];
    const float* Wx    = (const float*)d_in[8];
    const float* bx    = (const float*)d_in[9];
    const float* Wh    = (const float*)d_in[10];
    const float* bh    = (const float*)d_in[11];
    const float* q_t   = (const float*)d_in[12];
    const float* q_s   = (const float*)d_in[13];
    const float* clw   = (const float*)d_in[14];
    const float* clb   = (const float*)d_in[15];

    float* ws = (float*)d_ws;
    unsigned short* Hs_bf  = (unsigned short*)d_ws;
    float*          S      = ws + 6553600;
    float*          Xc     = ws + 13107200;
    unsigned short* An_bf  = (unsigned short*)(ws + 16384000);
    float*          Hsm    = ws + 17203200;
    float*          Hsqm   = ws + 17305600;
    unsigned short* WhT    = (unsigned short*)(ws + 17510400);
    unsigned short* XWx    = (unsigned short*)d_ws;   // overlays Hs+S

    conv_kernel<<<B_ * WN_, 256, 0, stream>>>(x, w1, b1, w2, b2, pw, pb, Hs_bf);
    s_kernel<<<(B_ * WN_ * N_) / 8, 256, 0, stream>>>(Hs_bf, proto, S);
    corr_kernel<<<B_ * WN_, 256, 0, stream>>>(x, S, An_bf);
    xc_kernel<<<B_ * WN_, 256, 0, stream>>>(S, Hs_bf, Xc);
    hsmean_kernel<<<B_ * WN_, 64, 0, stream>>>(Hs_bf, Hsm);
    whprep_kernel<<<256, 256, 0, stream>>>(Wh, WhT);
    xwx_kernel<<<B_ * WN_, 256, 0, stream>>>(Xc, Wx, bx, bh, XWx);
    scan_kernel<<<B_, 1024, 0, stream>>>(An_bf, XWx, WhT, Hsqm);
    final_kernel<<<B_, 128, 0, stream>>>(Hsqm, Hsm, q_t, q_s, clw, clb,
                                         (float*)d_out);
}

// Round 6
// 875.817 us; speedup vs baseline: 3.6445x; 1.5632x over previous
//
#include <hip/hip_runtime.h>

#define B_   16
#define T_   3000
#define N_   128
#define WIN_ 30
#define WN_  100
#define D_   64
#define HID_ 128
#define K_   32
#define G4_  512   // 4*HID_

typedef unsigned short us;
typedef __attribute__((ext_vector_type(8))) short short8;
typedef __attribute__((ext_vector_type(4))) float floatx4;

__device__ __forceinline__ us f2bf(float f) {
    unsigned u = __float_as_uint(f);
    u += 0x7fffu + ((u >> 16) & 1u);
    return (us)(u >> 16);
}
__device__ __forceinline__ float bf2f(us h) {
    return __uint_as_float(((unsigned)h) << 16);
}
__device__ __forceinline__ float sigf(float x) { return 1.f / (1.f + __expf(-x)); }
__device__ __forceinline__ float tanhfast(float x) { return 2.f / (1.f + __expf(-2.f * x)) - 1.f; }
// Barrier WITHOUT vmcnt drain: LDS ordering only.  Safe here because all
// global loads/stores crossing it are wave-private (consumed by issuing wave).
__device__ __forceinline__ void ldsbar() {
    __asm__ volatile("s_waitcnt lgkmcnt(0)\n\ts_barrier" ::: "memory");
}

// ---------------------------------------------------------------------------
// Kernel 1: SignalRep conv (unchanged from round 5 — verified).
// ---------------------------------------------------------------------------
__global__ __launch_bounds__(256) void conv_kernel(
    const float* __restrict__ x, const float* __restrict__ w1,
    const float* __restrict__ b1, const float* __restrict__ w2,
    const float* __restrict__ b2, const float* __restrict__ pw,
    const float* __restrict__ pb, us* __restrict__ Hs)
{
    __shared__ __align__(16) us h1s[8 * 36 * 40];
    __shared__ __align__(16) us Cs[256 * 36];
    __shared__ float xs[8 * 32];
    __shared__ float pws[32 * 64];
    __shared__ float means[8 * 33];
    const int tid = threadIdx.x;
    const int win = blockIdx.x;
    const int b = win / WN_, w = win - b * WN_;
    const float* xb = x + ((size_t)b * T_ + (size_t)w * WIN_) * N_;

    const int lane = tid & 63, wv = tid >> 6;
    const int l15 = lane & 15, quad = lane >> 4;
    const int mt = wv >> 1;
    const int ntp = wv & 1;

    for (int i = tid; i < 2048; i += 256) pws[i] = pw[i];
    for (int i = tid; i < 1920; i += 256) {
        int s = i / 240, r = i % 240;
        int ti = r / 40, c = r % 40;
        int tp = (ti < 2) ? ti : (30 + ti);
        h1s[(s * 36 + tp) * 40 + c] = 0;
    }
    short8 ahf[5], alf[5];
    #pragma unroll
    for (int dk = 0; dk < 5; dk++) {
        #pragma unroll
        for (int j = 0; j < 8; j++) {
            float v = w2[(mt * 16 + l15) * 160 + (quad * 8 + j) * 5 + dk];
            us hi = f2bf(v);
            ahf[dk][j] = (short)hi;
            alf[dk][j] = (short)f2bf(v - bf2f(hi));
        }
    }
    float b2v[4];
    #pragma unroll
    for (int r = 0; r < 4; r++) b2v[r] = b2[mt * 16 + quad * 4 + r];
    const int s1 = tid >> 5, ci1 = tid & 31;
    float w1r[5];
    #pragma unroll
    for (int k = 0; k < 5; k++) w1r[k] = w1[ci1 * 5 + k];
    const float b1v = b1[ci1];
    const int d2 = tid & 31;
    const float pbv0 = pb[2 * d2], pbv1 = pb[2 * d2 + 1];

    for (int g = 0; g < 16; g++) {
        const int n0 = g * 8;
        if (tid < 240) {
            int t = tid >> 3, s = tid & 7;
            xs[s * 32 + t] = xb[t * N_ + n0 + s];
        }
        __syncthreads();
        {
            float xr[30];
            #pragma unroll
            for (int t = 0; t < 30; t++) xr[t] = xs[s1 * 32 + t];
            #pragma unroll
            for (int t = 0; t < 30; t++) {
                float acc = b1v;
                #pragma unroll
                for (int k = 0; k < 5; k++) {
                    int p = t + k - 2;
                    if (p >= 0 && p < 30) acc += xr[p] * w1r[k];
                }
                h1s[(s1 * 36 + 2 + t) * 40 + ci1] = f2bf(fmaxf(acc, 0.f));
            }
        }
        __syncthreads();
        #pragma unroll 1
        for (int i = 0; i < 8; i++) {
            const int nt = ntp + 2 * i;
            const int c = nt * 16 + l15;
            const int s = c >> 5, tq = c & 31;
            floatx4 acc;
            #pragma unroll
            for (int r = 0; r < 4; r++) acc[r] = b2v[r];
            #pragma unroll
            for (int dk = 0; dk < 5; dk++) {
                short8 bfrag = *(const short8*)&h1s[(s * 36 + tq + dk) * 40 + quad * 8];
                acc = __builtin_amdgcn_mfma_f32_16x16x32_bf16(ahf[dk], bfrag, acc, 0, 0, 0);
                acc = __builtin_amdgcn_mfma_f32_16x16x32_bf16(alf[dk], bfrag, acc, 0, 0, 0);
            }
            if (tq < 30) {
                unsigned p0 = (unsigned)f2bf(fmaxf(acc[0], 0.f))
                            | ((unsigned)f2bf(fmaxf(acc[1], 0.f)) << 16);
                unsigned p1 = (unsigned)f2bf(fmaxf(acc[2], 0.f))
                            | ((unsigned)f2bf(fmaxf(acc[3], 0.f)) << 16);
                unsigned* cp = (unsigned*)&Cs[c * 36 + mt * 16 + quad * 4];
                cp[0] = p0; cp[1] = p1;
            }
        }
        __syncthreads();
        {
            float acc = 0.f;
            #pragma unroll
            for (int t = 0; t < 30; t++)
                acc += bf2f(Cs[(s1 * 32 + t) * 36 + ci1]);
            means[s1 * 33 + ci1] = acc * (1.f / 30.f);
        }
        __syncthreads();
        {
            float o0 = pbv0, o1 = pbv1;
            #pragma unroll 8
            for (int co = 0; co < 32; co++) {
                float m = means[s1 * 33 + co];
                o0 += m * pws[co * 64 + 2 * d2];
                o1 += m * pws[co * 64 + 2 * d2 + 1];
            }
            unsigned pk = (unsigned)f2bf(o0) | ((unsigned)f2bf(o1) << 16);
            unsigned* hp = (unsigned*)(Hs + (size_t)win * (N_ * D_) + (size_t)(n0 + s1) * D_);
            hp[d2] = pk;
        }
        __syncthreads();
    }
}

// ---------------------------------------------------------------------------
// Kernel 2: prep — WhT[jj][h] bf16, WxT_hi/lo[jj][d] bf16, bs2[jj]=bx+bh.
// jj = hcol*4+gate permutation: jg = (jj&3)*HID + (jj>>2).
// ---------------------------------------------------------------------------
__global__ __launch_bounds__(256) void prep_kernel(
    const float* __restrict__ Wh, const float* __restrict__ Wx,
    const float* __restrict__ bx, const float* __restrict__ bh,
    us* __restrict__ WhT, us* __restrict__ WxT_hi, us* __restrict__ WxT_lo,
    float* __restrict__ bs2)
{
    int i = blockIdx.x * 256 + threadIdx.x;
    if (i < 65536) {
        int jj = i >> 7, h = i & 127;
        int jg = (jj & 3) * HID_ + (jj >> 2);
        WhT[i] = f2bf(Wh[h * G4_ + jg]);
    } else if (i < 98304) {
        int j = i - 65536;
        int jj = j >> 6;
        int d = j & 63;
        int jg = (jj & 3) * HID_ + (jj >> 2);
        float v = Wx[d * G4_ + jg];
        us hi = f2bf(v);
        WxT_hi[j] = hi;
        WxT_lo[j] = f2bf(v - bf2f(hi));
    } else if (i < 98816) {
        int jj = i - 98304;
        int jg = (jj & 3) * HID_ + (jj >> 2);
        bs2[jj] = bx[jg] + bh[jg];
    }
}

// ---------------------------------------------------------------------------
// Kernel 3: fused per-window kernel — logits+softmax (S), Hsm (node-mean),
// Xc = S^T@Hs, XWx = Xc@Wx + bias (swizzled C-frag layout for scan).
// All GEMMs via MFMA with hi/lo splits where inputs aren't already bf16.
// One block (256 thr / 4 waves) per window.
// ---------------------------------------------------------------------------
__global__ __launch_bounds__(256) void xcwx_kernel(
    const us* __restrict__ Hs, const float* __restrict__ proto,
    const us* __restrict__ WxT_hi, const us* __restrict__ WxT_lo,
    const float* __restrict__ bs2, us* __restrict__ S_out,
    us* __restrict__ XWx, float* __restrict__ Hsm)
{
    __shared__ __align__(16) us Hnd[128 * 72];      // Hs [n][d]
    __shared__ __align__(16) us HsT[64 * 136];      // Hs^T [d][n]
    __shared__ __align__(16) us PT_hi[32 * 72];     // proto [k][d]
    __shared__ __align__(16) us PT_lo[32 * 72];
    __shared__ __align__(16) us SsT_hi[32 * 136];   // S^T [k][n]
    __shared__ __align__(16) us SsT_lo[32 * 136];
    __shared__ __align__(16) us XcA_hi[32 * 72];    // Xc [k][d]
    __shared__ __align__(16) us XcA_lo[32 * 72];
    __shared__ float bias[512];
    const int tid = threadIdx.x;
    const int win = blockIdx.x;
    const int lane = tid & 63, wv = tid >> 6;
    const int l15 = lane & 15, quad = lane >> 4;

    // ---- stage ----
    {
        const uint2* hp = (const uint2*)(Hs + (size_t)win * 8192);
        #pragma unroll
        for (int it = 0; it < 8; it++) {
            int idx4 = tid + 256 * it;              // 2048 uint2
            int n = idx4 >> 4, dpos = (idx4 & 15) * 4;
            uint2 v = hp[idx4];
            *(uint2*)&Hnd[n * 72 + dpos] = v;
            us s0 = (us)(v.x & 0xffff), s1 = (us)(v.x >> 16);
            us s2 = (us)(v.y & 0xffff), s3 = (us)(v.y >> 16);
            HsT[(dpos + 0) * 136 + n] = s0;
            HsT[(dpos + 1) * 136 + n] = s1;
            HsT[(dpos + 2) * 136 + n] = s2;
            HsT[(dpos + 3) * 136 + n] = s3;
        }
        for (int i = tid; i < 2048; i += 256) {
            int k = i >> 6, d = i & 63;
            float v = proto[i];
            us hi = f2bf(v);
            PT_hi[k * 72 + d] = hi;
            PT_lo[k * 72 + d] = f2bf(v - bf2f(hi));
        }
        for (int i = tid; i < 512; i += 256) bias[i] = bs2[i];
    }
    __syncthreads();
    // ---- logits + softmax ----
    floatx4 lg[2][2];
    #pragma unroll
    for (int p = 0; p < 2; p++) {
        const int mt = wv * 2 + p;
        #pragma unroll
        for (int kt = 0; kt < 2; kt++) {
            floatx4 a = {0.f, 0.f, 0.f, 0.f};
            #pragma unroll
            for (int kb = 0; kb < 2; kb++) {
                short8 af  = *(const short8*)&Hnd[(mt * 16 + l15) * 72 + kb * 32 + quad * 8];
                short8 bhf = *(const short8*)&PT_hi[(kt * 16 + l15) * 72 + kb * 32 + quad * 8];
                short8 blf = *(const short8*)&PT_lo[(kt * 16 + l15) * 72 + kb * 32 + quad * 8];
                a = __builtin_amdgcn_mfma_f32_16x16x32_bf16(af, bhf, a, 0, 0, 0);
                a = __builtin_amdgcn_mfma_f32_16x16x32_bf16(af, blf, a, 0, 0, 0);
            }
            lg[p][kt] = a;
        }
    }
    #pragma unroll
    for (int p = 0; p < 2; p++) {
        #pragma unroll
        for (int r = 0; r < 4; r++) {
            float v0 = lg[p][0][r], v1 = lg[p][1][r];
            float m = fmaxf(v0, v1);
            #pragma unroll
            for (int off = 8; off; off >>= 1) m = fmaxf(m, __shfl_xor(m, off));
            float e0 = expf(v0 - m), e1 = expf(v1 - m);
            float s = e0 + e1;
            #pragma unroll
            for (int off = 8; off; off >>= 1) s += __shfl_xor(s, off);
            float inv = 1.f / s;
            e0 *= inv; e1 *= inv;
            const int n = (wv * 2 + p) * 16 + quad * 4 + r;
            us h0 = f2bf(e0), h1 = f2bf(e1);
            SsT_hi[l15 * 136 + n]        = h0;
            SsT_hi[(16 + l15) * 136 + n] = h1;
            SsT_lo[l15 * 136 + n]        = f2bf(e0 - bf2f(h0));
            SsT_lo[(16 + l15) * 136 + n] = f2bf(e1 - bf2f(h1));
            S_out[(size_t)win * 4096 + n * 32 + l15]      = h0;
            S_out[(size_t)win * 4096 + n * 32 + 16 + l15] = h1;
        }
    }
    __syncthreads();
    // ---- Hsm: mean over nodes (from HsT) ----
    {
        const int d = tid >> 2, seg = tid & 3;
        float acc = 0.f;
        const unsigned* hp = (const unsigned*)&HsT[d * 136 + seg * 32];
        #pragma unroll
        for (int q = 0; q < 16; q++) {
            unsigned v = hp[q];
            acc += bf2f((us)(v & 0xffff)) + bf2f((us)(v >> 16));
        }
        acc += __shfl_xor(acc, 1);
        acc += __shfl_xor(acc, 2);
        if (seg == 0) Hsm[(size_t)win * 64 + d] = acc * (1.f / 128.f);
    }
    // ---- GEMM_a: Xc[k][d] = S^T @ Hs ----
    #pragma unroll
    for (int p = 0; p < 2; p++) {
        const int id = wv * 2 + p, mt = id >> 2, nt = id & 3;
        floatx4 a = {0.f, 0.f, 0.f, 0.f};
        #pragma unroll
        for (int kb = 0; kb < 4; kb++) {
            short8 ah = *(const short8*)&SsT_hi[(mt * 16 + l15) * 136 + kb * 32 + quad * 8];
            short8 al = *(const short8*)&SsT_lo[(mt * 16 + l15) * 136 + kb * 32 + quad * 8];
            short8 bf_ = *(const short8*)&HsT[(nt * 16 + l15) * 136 + kb * 32 + quad * 8];
            a = __builtin_amdgcn_mfma_f32_16x16x32_bf16(ah, bf_, a, 0, 0, 0);
            a = __builtin_amdgcn_mfma_f32_16x16x32_bf16(al, bf_, a, 0, 0, 0);
        }
        #pragma unroll
        for (int r = 0; r < 4; r++) {
            const int k = mt * 16 + quad * 4 + r, d = nt * 16 + l15;
            float v = a[r];
            us hi = f2bf(v);
            XcA_hi[k * 72 + d] = hi;
            XcA_lo[k * 72 + d] = f2bf(v - bf2f(hi));
        }
    }
    __syncthreads();
    // ---- GEMM_b: XWx = Xc @ Wx + bias (3-pass hi/lo) ----
    short8 Ah[2][2], Al[2][2];
    #pragma unroll
    for (int mt = 0; mt < 2; mt++)
        #pragma unroll
        for (int kb = 0; kb < 2; kb++) {
            Ah[mt][kb] = *(const short8*)&XcA_hi[(mt * 16 + l15) * 72 + kb * 32 + quad * 8];
            Al[mt][kb] = *(const short8*)&XcA_lo[(mt * 16 + l15) * 72 + kb * 32 + quad * 8];
        }
    #pragma unroll 1
    for (int i = 0; i < 8; i++) {
        const int nt = wv + 4 * i;
        const float bv = bias[nt * 16 + l15];
        floatx4 acc[2];
        acc[0] = (floatx4){bv, bv, bv, bv};
        acc[1] = (floatx4){bv, bv, bv, bv};
        #pragma unroll
        for (int kb = 0; kb < 2; kb++) {
            short8 wh8 = *(const short8*)&WxT_hi[(size_t)(nt * 16 + l15) * 64 + kb * 32 + quad * 8];
            short8 wl8 = *(const short8*)&WxT_lo[(size_t)(nt * 16 + l15) * 64 + kb * 32 + quad * 8];
            #pragma unroll
            for (int mt = 0; mt < 2; mt++) {
                acc[mt] = __builtin_amdgcn_mfma_f32_16x16x32_bf16(Ah[mt][kb], wh8, acc[mt], 0, 0, 0);
                acc[mt] = __builtin_amdgcn_mfma_f32_16x16x32_bf16(Ah[mt][kb], wl8, acc[mt], 0, 0, 0);
                acc[mt] = __builtin_amdgcn_mfma_f32_16x16x32_bf16(Al[mt][kb], wh8, acc[mt], 0, 0, 0);
            }
        }
        #pragma unroll
        for (int mt = 0; mt < 2; mt++) {
            uint2 pk;
            pk.x = (unsigned)f2bf(acc[mt][0]) | ((unsigned)f2bf(acc[mt][1]) << 16);
            pk.y = (unsigned)f2bf(acc[mt][2]) | ((unsigned)f2bf(acc[mt][3]) << 16);
            ((uint2*)XWx)[((size_t)win * 64 + mt * 32 + nt) * 64 + lane] = pk;
        }
    }
}

// ---------------------------------------------------------------------------
// Kernel 4: corr -> AS -> Ac -> normalize -> An, as a 3-GEMM MFMA chain.
// cov = xm^T @ xm uses the same LDS array for A and B fragments.
// ---------------------------------------------------------------------------
__global__ __launch_bounds__(256) void corr_kernel(
    const float* __restrict__ x, const us* __restrict__ S_bf,
    us* __restrict__ An)
{
    __shared__ __align__(16) float xs[30 * 128];    // [l][n]
    __shared__ __align__(16) us XA[128 * 40];       // xm^T [n][l], cols 30/31 = 0
    __shared__ __align__(16) us SsT[32 * 136];      // S^T [k][n]
    __shared__ __align__(16) us CB[128 * 136];      // corr [n][m] bf16
    __shared__ __align__(16) us AST[32 * 136];      // AS^T [l][n] bf16
    __shared__ float Acs[32 * 33];
    __shared__ float sinv[128];
    __shared__ float dinv[32];
    const int tid = threadIdx.x;
    const int win = blockIdx.x;
    const int b = win / WN_, w = win - b * WN_;
    const float* xb = x + ((size_t)b * T_ + (size_t)w * WIN_) * N_;
    const int lane = tid & 63, wv = tid >> 6;
    const int l15 = lane & 15, quad = lane >> 4;
    const float inv29 = 1.f / (WIN_ - 1 + 1e-8f);

    for (int i = tid; i < 3840; i += 256) xs[i] = xb[i];
    for (int i = tid; i < 4096; i += 256) {
        int n = i >> 5, k = i & 31;
        SsT[k * 136 + n] = S_bf[(size_t)win * 4096 + i];
    }
    __syncthreads();
    if (tid < 128) {
        const int n = tid;
        float mean = 0.f;
        #pragma unroll
        for (int l = 0; l < 30; l++) mean += xs[l * 128 + n];
        mean *= (1.f / 30.f);
        float var = 0.f;
        #pragma unroll
        for (int l = 0; l < 30; l++) {
            float v = xs[l * 128 + n] - mean;
            var += v * v;
            XA[n * 40 + l] = f2bf(v);
        }
        XA[n * 40 + 30] = 0; XA[n * 40 + 31] = 0;
        var *= inv29;
        sinv[n] = rsqrtf(fmaxf(var, 1e-8f));
    }
    __syncthreads();
    // ---- cov -> corr (64 tiles, K=32, A and B from the same array) ----
    #pragma unroll 1
    for (int q = 0; q < 16; q++) {
        const int id = wv * 16 + q, mt = id >> 3, nt = id & 7;
        short8 a = *(const short8*)&XA[(mt * 16 + l15) * 40 + quad * 8];
        short8 bb = *(const short8*)&XA[(nt * 16 + l15) * 40 + quad * 8];
        floatx4 d = {0.f, 0.f, 0.f, 0.f};
        d = __builtin_amdgcn_mfma_f32_16x16x32_bf16(a, bb, d, 0, 0, 0);
        const int m = nt * 16 + l15;
        const float sm = sinv[m];
        #pragma unroll
        for (int r = 0; r < 4; r++) {
            const int n = mt * 16 + quad * 4 + r;
            float v = d[r] * inv29 * sinv[n] * sm;
            if (n == m) v = 1.f;
            CB[n * 136 + m] = f2bf(v);
        }
    }
    __syncthreads();
    // ---- AS = corr @ S (16 tiles, K=128) ----
    #pragma unroll 1
    for (int q = 0; q < 4; q++) {
        const int id = wv * 4 + q, mt = id >> 1, lt = id & 1;
        floatx4 d = {0.f, 0.f, 0.f, 0.f};
        #pragma unroll
        for (int kb = 0; kb < 4; kb++) {
            short8 a = *(const short8*)&CB[(mt * 16 + l15) * 136 + kb * 32 + quad * 8];
            short8 bb = *(const short8*)&SsT[(lt * 16 + l15) * 136 + kb * 32 + quad * 8];
            d = __builtin_amdgcn_mfma_f32_16x16x32_bf16(a, bb, d, 0, 0, 0);
        }
        const int l = lt * 16 + l15;
        #pragma unroll
        for (int r = 0; r < 4; r++)
            AST[l * 136 + mt * 16 + quad * 4 + r] = f2bf(d[r]);
    }
    __syncthreads();
    // ---- Ac = S^T @ AS (4 tiles, K=128) ----
    {
        const int kt = wv >> 1, lt = wv & 1;
        floatx4 d = {0.f, 0.f, 0.f, 0.f};
        #pragma unroll
        for (int kb = 0; kb < 4; kb++) {
            short8 a = *(const short8*)&SsT[(kt * 16 + l15) * 136 + kb * 32 + quad * 8];
            short8 bb = *(const short8*)&AST[(lt * 16 + l15) * 136 + kb * 32 + quad * 8];
            d = __builtin_amdgcn_mfma_f32_16x16x32_bf16(a, bb, d, 0, 0, 0);
        }
        #pragma unroll
        for (int r = 0; r < 4; r++)
            Acs[(kt * 16 + quad * 4 + r) * 33 + lt * 16 + l15] = d[r];
    }
    __syncthreads();
    // ---- symmetrize + I, rowsum, D^-1/2 normalize, store bf16 ----
    float symv[4];
    {
        int l = tid & 31, kb = tid >> 5;
        for (int r = 0; r < 4; r++) {
            int k = kb + 8 * r;
            symv[r] = 0.5f * (Acs[k * 33 + l] + Acs[l * 33 + k]) + ((k == l) ? 1.f : 0.f);
        }
    }
    __syncthreads();
    {
        int l = tid & 31, kb = tid >> 5;
        for (int r = 0; r < 4; r++) Acs[(kb + 8 * r) * 33 + l] = symv[r];
    }
    __syncthreads();
    if (tid < K_) {
        float s = 0.f;
        for (int l = 0; l < K_; l++) s += Acs[tid * 33 + l];
        dinv[tid] = rsqrtf(fmaxf(s, 1e-8f));
    }
    __syncthreads();
    us* Anw = An + (size_t)win * K_ * K_;
    for (int i = tid; i < K_ * K_; i += 256) {
        int k = i >> 5, l = i & 31;
        Anw[i] = f2bf(dinv[k] * Acs[k * 33 + l] * dinv[l]);
    }
}

// ---------------------------------------------------------------------------
// Kernel 5: fused 100-step GCLSTM scan.  16 blocks x 512 threads (8 waves).
// Raw lgkm-only barrier (no vmcnt drain); prefetch at top of step; Wh in
// 64 VGPRs; gates in MFMA C-layout; LSTM state in registers.
// ---------------------------------------------------------------------------
__global__ __launch_bounds__(512) void scan_kernel(
    const us* __restrict__ An_bf,   // [bt][k][m]
    const us* __restrict__ XWxS,    // swizzled C-frag layout
    const us* __restrict__ WhT,     // [jj][h]
    float* __restrict__ Hsqm)
{
    __shared__ __align__(16) us HpHi[2][32 * 136];
    __shared__ __align__(16) us TmpT[512 * 40];     // [col jj][row m]

    const int tid  = threadIdx.x;
    const int lane = tid & 63;
    const int wv   = tid >> 6;          // 0..7
    const int b    = blockIdx.x;
    const int l15  = lane & 15, quad = lane >> 4;

    // Wh B-fragments for this wave's 4 ntiles: 16 short8 = 64 VGPRs.
    short8 Bw[4][4];
    #pragma unroll
    for (int i = 0; i < 4; i++) {
        const int nt = wv + 8 * i;
        #pragma unroll
        for (int kb = 0; kb < 4; kb++)
            Bw[i][kb] = *(const short8*)&WhT[(size_t)(nt * 16 + l15) * 128 + kb * 32 + quad * 8];
    }
    // state: (k = kt*16+l15, h = (wv+8i)*4+quad)
    float Cst[2][4], Hst[2][4], H2t[2][4];
    #pragma unroll
    for (int kt = 0; kt < 2; kt++)
        #pragma unroll
        for (int i = 0; i < 4; i++) { Cst[kt][i] = 0.f; Hst[kt][i] = 0.f; H2t[kt][i] = 0.f; }

    for (int i = tid; i < 32 * 136; i += 512) HpHi[0][i] = 0;

    const size_t bt0 = (size_t)b * WN_;
    const uint2* xp = (const uint2*)XWxS;
    uint2 xw[2][4];
    short8 anf[2];
    #pragma unroll
    for (int mtp = 0; mtp < 2; mtp++)
        #pragma unroll
        for (int i = 0; i < 4; i++)
            xw[mtp][i] = xp[(bt0 * 64 + mtp * 32 + wv + 8 * i) * 64 + lane];
    #pragma unroll
    for (int kt = 0; kt < 2; kt++)
        anf[kt] = *(const short8*)&An_bf[bt0 * 1024 + (kt * 16 + l15) * 32 + quad * 8];

    #pragma unroll 1
    for (int t = 0; t < WN_; t++) {
        const int buf = t & 1;
        ldsbar();
        // acc init from XWx C-frags
        floatx4 acc[2][4];
        #pragma unroll
        for (int mtp = 0; mtp < 2; mtp++)
            #pragma unroll
            for (int i = 0; i < 4; i++) {
                acc[mtp][i][0] = bf2f((us)(xw[mtp][i].x & 0xffff));
                acc[mtp][i][1] = bf2f((us)(xw[mtp][i].x >> 16));
                acc[mtp][i][2] = bf2f((us)(xw[mtp][i].y & 0xffff));
                acc[mtp][i][3] = bf2f((us)(xw[mtp][i].y >> 16));
            }
        // prefetch XWx for t+1 immediately (full step to land; no barrier drain)
        {
            const int tn = (t + 1 < WN_) ? (t + 1) : (WN_ - 1);
            const size_t base = (bt0 + tn) * 64;
            #pragma unroll
            for (int mtp = 0; mtp < 2; mtp++)
                #pragma unroll
                for (int i = 0; i < 4; i++)
                    xw[mtp][i] = xp[(base + mtp * 32 + wv + 8 * i) * 64 + lane];
        }
        // GEMM1: tmp[m][jj] = XWx + Hp @ Wh'
        #pragma unroll
        for (int kb = 0; kb < 4; kb++) {
            const int ko = kb * 32 + quad * 8;
            short8 a0 = *(const short8*)&HpHi[buf][l15 * 136 + ko];
            short8 a1 = *(const short8*)&HpHi[buf][(16 + l15) * 136 + ko];
            #pragma unroll
            for (int i = 0; i < 4; i++) {
                acc[0][i] = __builtin_amdgcn_mfma_f32_16x16x32_bf16(a0, Bw[i][kb], acc[0][i], 0, 0, 0);
                acc[1][i] = __builtin_amdgcn_mfma_f32_16x16x32_bf16(a1, Bw[i][kb], acc[1][i], 0, 0, 0);
            }
        }
        // tmp^T to LDS (wave-private columns)
        #pragma unroll
        for (int i = 0; i < 4; i++) {
            const int col = (wv + 8 * i) * 16 + l15;
            #pragma unroll
            for (int mtp = 0; mtp < 2; mtp++) {
                uint2 pk;
                pk.x = (unsigned)f2bf(acc[mtp][i][0]) | ((unsigned)f2bf(acc[mtp][i][1]) << 16);
                pk.y = (unsigned)f2bf(acc[mtp][i][2]) | ((unsigned)f2bf(acc[mtp][i][3]) << 16);
                *(uint2*)&TmpT[col * 40 + mtp * 16 + quad * 4] = pk;
            }
        }
        __builtin_amdgcn_wave_barrier();
        // GEMM2: g^T[jj][k] = tmp^T @ An^T
        floatx4 g[2][4];
        #pragma unroll
        for (int i = 0; i < 4; i++) {
            short8 aT = *(const short8*)&TmpT[((wv + 8 * i) * 16 + l15) * 40 + quad * 8];
            floatx4 z = {0.f, 0.f, 0.f, 0.f};
            g[0][i] = __builtin_amdgcn_mfma_f32_16x16x32_bf16(aT, anf[0], z, 0, 0, 0);
            g[1][i] = __builtin_amdgcn_mfma_f32_16x16x32_bf16(aT, anf[1], z, 0, 0, 0);
        }
        // prefetch An for t+1
        {
            const int tn = (t + 1 < WN_) ? (t + 1) : (WN_ - 1);
            #pragma unroll
            for (int kt = 0; kt < 2; kt++)
                anf[kt] = *(const short8*)&An_bf[(bt0 + tn) * 1024 + (kt * 16 + l15) * 32 + quad * 8];
        }
        // gates + state
        #pragma unroll
        for (int kt = 0; kt < 2; kt++)
            #pragma unroll
            for (int i = 0; i < 4; i++) {
                float gi = g[kt][i][0], gf = g[kt][i][1];
                float go = g[kt][i][2], gc = g[kt][i][3];
                float cn = sigf(gf) * Cst[kt][i] + sigf(gi) * tanhfast(gc);
                float hn = sigf(go) * tanhfast(cn);
                Cst[kt][i] = cn;
                H2t[kt][i] = Hst[kt][i];
                Hst[kt][i] = hn;
            }
        // Hsqm: mean over k
        #pragma unroll
        for (int i = 0; i < 4; i++) {
            float s = Hst[0][i] + Hst[1][i];
            s += __shfl_xor(s, 1); s += __shfl_xor(s, 2);
            s += __shfl_xor(s, 4); s += __shfl_xor(s, 8);
            if (l15 == 0)
                Hsqm[(bt0 + t) * HID_ + (wv + 8 * i) * 4 + quad] = s * (1.f / 32.f);
        }
        // Hp(t+1)
        if (t + 1 < WN_) {
            const float dninv = (t + 1 == 1) ? 0.5f : (1.f / 3.f);
            #pragma unroll
            for (int kt = 0; kt < 2; kt++)
                #pragma unroll
                for (int i = 0; i < 4; i++) {
                    float v = (2.f * Hst[kt][i] + H2t[kt][i]) * dninv;
                    HpHi[buf ^ 1][(kt * 16 + l15) * 136 + (wv + 8 * i) * 4 + quad] = f2bf(v);
                }
        }
    }
}

// ---------------------------------------------------------------------------
// Kernel 6: temporal attention pooling + classifier (unchanged).
// ---------------------------------------------------------------------------
__global__ __launch_bounds__(128) void final_kernel(
    const float* __restrict__ Hsqm, const float* __restrict__ Hsm,
    const float* __restrict__ q_t, const float* __restrict__ q_s,
    const float* __restrict__ cls_w, const float* __restrict__ cls_b,
    float* __restrict__ out)
{
    __shared__ float red[128];
    __shared__ float sc[WN_];
    __shared__ float wt[WN_];
    __shared__ float smv;
    const int b = blockIdx.x, tid = threadIdx.x;
    float v = q_t[tid];
    red[tid] = v * v;
    __syncthreads();
    for (int off = 64; off; off >>= 1) {
        if (tid < off) red[tid] += red[tid + off];
        __syncthreads();
    }
    const float qtn = sqrtf(red[0]) + 1e-8f;
    __syncthreads();
    float v2 = (tid < D_) ? q_s[tid] : 0.f;
    red[tid] = v2 * v2;
    __syncthreads();
    for (int off = 64; off; off >>= 1) {
        if (tid < off) red[tid] += red[tid + off];
        __syncthreads();
    }
    const float qsn = sqrtf(red[0]) + 1e-8f;
    __syncthreads();
    if (tid < WN_) {
        float s = 0.f;
        const float* zr = Hsqm + ((size_t)b * WN_ + tid) * HID_;
        for (int h = 0; h < HID_; h++) s += zr[h] * q_t[h];
        sc[tid] = s / qtn;
    }
    __syncthreads();
    if (tid == 0) {
        float m = sc[0];
        for (int i = 1; i < WN_; i++) m = fmaxf(m, sc[i]);
        float s = 0.f;
        for (int i = 0; i < WN_; i++) { wt[i] = expf(sc[i] - m); s += wt[i]; }
        smv = 1.f / s;
    }
    __syncthreads();
    float part = 0.f;
    {
        float z = 0.f;
        for (int w = 0; w < WN_; w++)
            z += wt[w] * Hsqm[((size_t)b * WN_ + w) * HID_ + tid];
        part += z * smv * cls_w[tid];
    }
    __syncthreads();
    if (tid < WN_) {
        float s = 0.f;
        const float* zr = Hsm + ((size_t)b * WN_ + tid) * D_;
        for (int dd = 0; dd < D_; dd++) s += zr[dd] * q_s[dd];
        sc[tid] = s / qsn;
    }
    __syncthreads();
    if (tid == 0) {
        float m = sc[0];
        for (int i = 1; i < WN_; i++) m = fmaxf(m, sc[i]);
        float s = 0.f;
        for (int i = 0; i < WN_; i++) { wt[i] = expf(sc[i] - m); s += wt[i]; }
        smv = 1.f / s;
    }
    __syncthreads();
    if (tid < D_) {
        float z = 0.f;
        for (int w = 0; w < WN_; w++)
            z += wt[w] * Hsm[((size_t)b * WN_ + w) * D_ + tid];
        part += z * smv * cls_w[HID_ + tid];
    }
    red[tid] = part;
    __syncthreads();
    for (int off = 64; off; off >>= 1) {
        if (tid < off) red[tid] += red[tid + off];
        __syncthreads();
    }
    if (tid == 0) out[b] = 1.f / (1.f + expf(-(red[0] + cls_b[0])));
}

// ---------------------------------------------------------------------------
extern "C" void kernel_launch(void* const* d_in, const int* in_sizes, int n_in,
                              void* d_out, int out_size, void* d_ws, size_t ws_size,
                              hipStream_t stream)
{
    (void)in_sizes; (void)n_in; (void)out_size; (void)ws_size;
    const float* x     = (const float*)d_in[0];
    const float* w1    = (const float*)d_in[1];
    const float* b1    = (const float*)d_in[2];
    const float* w2    = (const float*)d_in[3];
    const float* b2    = (const float*)d_in[4];
    const float* pw    = (const float*)d_in[5];
    const float* pb    = (const float*)d_in[6];
    const float* proto = (const float*)d_in[7];
    const float* Wx    = (const float*)d_in[8];
    const float* bx    = (const float*)d_in[9];
    const float* Wh    = (const float*)d_in[10];
    const float* bh    = (const float*)d_in[11];
    const float* q_t   = (const float*)d_in[12];
    const float* q_s   = (const float*)d_in[13];
    const float* clw   = (const float*)d_in[14];
    const float* clb   = (const float*)d_in[15];

    float* ws = (float*)d_ws;
    // float-slot layout (total 24,130,048 floats ≈ 96.5 MB):
    us*    Hs_bf  = (us*)d_ws;                      // [0, 6553600)
    us*    S_bf   = (us*)(ws + 6553600);            // [6553600, 9830400)
    us*    XWx    = (us*)(ws + 9830400);            // [9830400, 22937600)
    us*    An_bf  = (us*)(ws + 22937600);           // [22937600, 23756800)
    float* Hsm    = ws + 23756800;                  // [23756800, 23859200)
    float* Hsqm   = ws + 23859200;                  // [23859200, 24064000)
    us*    WhT    = (us*)(ws + 24064000);           // [24064000, 24096768)
    us*    WxT_hi = (us*)(ws + 24096768);           // [24096768, 24113152)
    us*    WxT_lo = (us*)(ws + 24113152);           // [24113152, 24129536)
    float* bs2    = ws + 24129536;                  // [24129536, 24130048)

    prep_kernel<<<386, 256, 0, stream>>>(Wh, Wx, bx, bh, WhT, WxT_hi, WxT_lo, bs2);
    conv_kernel<<<B_ * WN_, 256, 0, stream>>>(x, w1, b1, w2, b2, pw, pb, Hs_bf);
    xcwx_kernel<<<B_ * WN_, 256, 0, stream>>>(Hs_bf, proto, WxT_hi, WxT_lo,
                                              bs2, S_bf, XWx, Hsm);
    corr_kernel<<<B_ * WN_, 256, 0, stream>>>(x, S_bf, An_bf);
    scan_kernel<<<B_, 512, 0, stream>>>(An_bf, XWx, WhT, Hsqm);
    final_kernel<<<B_, 128, 0, stream>>>(Hsqm, Hsm, q_t, q_s, clw, clb,
                                         (float*)d_out);
}

// Round 7
// 851.737 us; speedup vs baseline: 3.7475x; 1.0283x over previous
//
#include <hip/hip_runtime.h>

#define B_   16
#define T_   3000
#define N_   128
#define WIN_ 30
#define WN_  100
#define D_   64
#define HID_ 128
#define K_   32
#define G4_  512   // 4*HID_

typedef unsigned short us;
typedef __attribute__((ext_vector_type(8))) short short8;
typedef __attribute__((ext_vector_type(4))) float floatx4;

__device__ __forceinline__ us f2bf(float f) {
    unsigned u = __float_as_uint(f);
    u += 0x7fffu + ((u >> 16) & 1u);
    return (us)(u >> 16);
}
__device__ __forceinline__ float bf2f(us h) {
    return __uint_as_float(((unsigned)h) << 16);
}
__device__ __forceinline__ float sigf(float x) { return 1.f / (1.f + __expf(-x)); }
__device__ __forceinline__ float tanhfast(float x) { return 2.f / (1.f + __expf(-2.f * x)) - 1.f; }
// Barrier WITHOUT vmcnt drain: LDS ordering only.  Safe when all global
// loads/stores crossing it are wave-private (consumed by issuing wave).
__device__ __forceinline__ void ldsbar() {
    __asm__ volatile("s_waitcnt lgkmcnt(0)\n\ts_barrier" ::: "memory");
}

// ---------------------------------------------------------------------------
// Kernel 1: SignalRep conv — zero per-group block barriers.  Wave owns 2
// complete sequences: conv1 (fp32 VALU, lane=(sloc,ci)) writes wave-private
// h1; conv2 (bf16 MFMA, w2 hi/lo in regs) reads it after wave_barrier only.
// Mean over t via shfl_xor on C-frags -> Ms fp32 LDS.  Proj 32->64 done once
// at the end as 3-pass hi/lo MFMA GEMM.
// ---------------------------------------------------------------------------
__global__ __launch_bounds__(256) void conv_kernel(
    const float* __restrict__ x, const float* __restrict__ w1,
    const float* __restrict__ b1, const float* __restrict__ w2,
    const float* __restrict__ b2, const float* __restrict__ pw,
    const float* __restrict__ pb, us* __restrict__ Hs)
{
    __shared__ __align__(16) float xs_all[30 * 128];   // [t][n]
    __shared__ __align__(16) us h1s[8 * 36 * 40];      // [s][t'][ci], wave-private rows
    __shared__ __align__(16) float Ms[128 * 40];       // [n][co] means (already /30)
    __shared__ __align__(16) us PwT_hi[64 * 40];       // [d][co]
    __shared__ __align__(16) us PwT_lo[64 * 40];
    const int tid = threadIdx.x;
    const int win = blockIdx.x;
    const int b = win / WN_, w = win - b * WN_;
    const float* xb = x + ((size_t)b * T_ + (size_t)w * WIN_) * N_;
    const int lane = tid & 63, wv = tid >> 6;
    const int l15 = lane & 15, quad = lane >> 4;
    const int sloc = lane >> 5, ci = lane & 31;

    // ---- stage (once) ----
    {
        const float4* xb4 = (const float4*)xb;
        float4* xs4 = (float4*)xs_all;
        for (int i = tid; i < 960; i += 256) xs4[i] = xb4[i];
    }
    for (int i = tid; i < 2048; i += 256) {
        int co = i >> 6, d = i & 63;
        float v = pw[i];
        us hi = f2bf(v);
        PwT_hi[d * 40 + co] = hi;
        PwT_lo[d * 40 + co] = f2bf(v - bf2f(hi));
    }
    for (int i = tid; i < 1920; i += 256) {            // zero h1 pad rows
        int s = i / 240, r = i % 240;
        int ti = r / 40, c = r % 40;
        int tp = (ti < 2) ? ti : (30 + ti);
        h1s[(s * 36 + tp) * 40 + c] = 0;
    }
    // w2 A-fragments, hi/lo (exact weights), both co-tiles: 80 VGPR
    short8 ahf[2][5], alf[2][5];
    #pragma unroll
    for (int cot = 0; cot < 2; cot++)
        #pragma unroll
        for (int dk = 0; dk < 5; dk++)
            #pragma unroll
            for (int j = 0; j < 8; j++) {
                float v = w2[(cot * 16 + l15) * 160 + (quad * 8 + j) * 5 + dk];
                us hi = f2bf(v);
                ahf[cot][dk][j] = (short)hi;
                alf[cot][dk][j] = (short)f2bf(v - bf2f(hi));
            }
    float b2v[2][4];
    #pragma unroll
    for (int cot = 0; cot < 2; cot++)
        #pragma unroll
        for (int r = 0; r < 4; r++) b2v[cot][r] = b2[cot * 16 + quad * 4 + r];
    float w1r[5];
    #pragma unroll
    for (int k = 0; k < 5; k++) w1r[k] = w1[ci * 5 + k];
    const float b1v = b1[ci];
    float pbv[4];
    #pragma unroll
    for (int nt = 0; nt < 4; nt++) pbv[nt] = pb[nt * 16 + l15];
    ldsbar();

    // ---- 16 groups of 8 sequences, no block barriers ----
    for (int g = 0; g < 16; g++) {
        const int n1 = g * 8 + wv * 2 + sloc;
        // conv1: lane (sloc, ci) computes all 30 t for its seq
        {
            float xr[30];
            #pragma unroll
            for (int p = 0; p < 30; p++) xr[p] = xs_all[p * 128 + n1];
            #pragma unroll
            for (int t = 0; t < 30; t++) {
                float acc = b1v;
                #pragma unroll
                for (int k = 0; k < 5; k++) {
                    int p = t + k - 2;
                    if (p >= 0 && p < 30) acc += xr[p] * w1r[k];
                }
                h1s[((wv * 2 + sloc) * 36 + 2 + t) * 40 + ci] = f2bf(fmaxf(acc, 0.f));
            }
        }
        __builtin_amdgcn_wave_barrier();
        // conv2 + relu + mean: wave's 2 seqs x 2 co-tiles
        #pragma unroll
        for (int s2 = 0; s2 < 2; s2++) {
            const int sl = wv * 2 + s2;
            const int nn = g * 8 + sl;
            #pragma unroll
            for (int cot = 0; cot < 2; cot++) {
                floatx4 a0, a1;
                #pragma unroll
                for (int r = 0; r < 4; r++) { a0[r] = b2v[cot][r]; a1[r] = b2v[cot][r]; }
                #pragma unroll
                for (int dk = 0; dk < 5; dk++) {
                    short8 bf0 = *(const short8*)&h1s[(sl * 36 + l15 + dk) * 40 + quad * 8];
                    short8 bf1 = *(const short8*)&h1s[(sl * 36 + 16 + l15 + dk) * 40 + quad * 8];
                    a0 = __builtin_amdgcn_mfma_f32_16x16x32_bf16(ahf[cot][dk], bf0, a0, 0, 0, 0);
                    a0 = __builtin_amdgcn_mfma_f32_16x16x32_bf16(alf[cot][dk], bf0, a0, 0, 0, 0);
                    a1 = __builtin_amdgcn_mfma_f32_16x16x32_bf16(ahf[cot][dk], bf1, a1, 0, 0, 0);
                    a1 = __builtin_amdgcn_mfma_f32_16x16x32_bf16(alf[cot][dk], bf1, a1, 0, 0, 0);
                }
                floatx4 sr;
                #pragma unroll
                for (int r = 0; r < 4; r++)
                    sr[r] = fmaxf(a0[r], 0.f) + ((l15 < 14) ? fmaxf(a1[r], 0.f) : 0.f);
                #pragma unroll
                for (int off = 1; off < 16; off <<= 1) {
                    #pragma unroll
                    for (int r = 0; r < 4; r++) sr[r] += __shfl_xor(sr[r], off);
                }
                if (l15 == 0) {
                    float4 v;
                    v.x = sr[0] * (1.f / 30.f); v.y = sr[1] * (1.f / 30.f);
                    v.z = sr[2] * (1.f / 30.f); v.w = sr[3] * (1.f / 30.f);
                    *(float4*)&Ms[nn * 40 + cot * 16 + quad * 4] = v;
                }
            }
        }
        __builtin_amdgcn_wave_barrier();
    }
    ldsbar();
    // ---- proj GEMM: Hs[n][d] = Ms @ pw + pb (3-pass hi/lo) ----
    short8 Ah[2], Al[2];
    #pragma unroll
    for (int i = 0; i < 2; i++) {
        const int mt = wv * 2 + i;
        float4 v0 = *(const float4*)&Ms[(mt * 16 + l15) * 40 + quad * 8];
        float4 v1 = *(const float4*)&Ms[(mt * 16 + l15) * 40 + quad * 8 + 4];
        float vv[8] = {v0.x, v0.y, v0.z, v0.w, v1.x, v1.y, v1.z, v1.w};
        #pragma unroll
        for (int j = 0; j < 8; j++) {
            us hi = f2bf(vv[j]);
            Ah[i][j] = (short)hi;
            Al[i][j] = (short)f2bf(vv[j] - bf2f(hi));
        }
    }
    us* hp = Hs + (size_t)win * 8192;
    #pragma unroll
    for (int id = 0; id < 8; id++) {
        const int i = id >> 2, nt = id & 3;
        short8 Bh = *(const short8*)&PwT_hi[(nt * 16 + l15) * 40 + quad * 8];
        short8 Bl = *(const short8*)&PwT_lo[(nt * 16 + l15) * 40 + quad * 8];
        floatx4 a = {pbv[nt], pbv[nt], pbv[nt], pbv[nt]};
        a = __builtin_amdgcn_mfma_f32_16x16x32_bf16(Ah[i], Bh, a, 0, 0, 0);
        a = __builtin_amdgcn_mfma_f32_16x16x32_bf16(Al[i], Bh, a, 0, 0, 0);
        a = __builtin_amdgcn_mfma_f32_16x16x32_bf16(Ah[i], Bl, a, 0, 0, 0);
        const int mt = wv * 2 + i;
        #pragma unroll
        for (int r = 0; r < 4; r++)
            hp[(mt * 16 + quad * 4 + r) * 64 + nt * 16 + l15] = f2bf(a[r]);
    }
}

// ---------------------------------------------------------------------------
// Kernel 2: prep — WhT[jj][h] bf16, WxT_hi/lo[jj][d] bf16, bs2[jj]=bx+bh.
// ---------------------------------------------------------------------------
__global__ __launch_bounds__(256) void prep_kernel(
    const float* __restrict__ Wh, const float* __restrict__ Wx,
    const float* __restrict__ bx, const float* __restrict__ bh,
    us* __restrict__ WhT, us* __restrict__ WxT_hi, us* __restrict__ WxT_lo,
    float* __restrict__ bs2)
{
    int i = blockIdx.x * 256 + threadIdx.x;
    if (i < 65536) {
        int jj = i >> 7, h = i & 127;
        int jg = (jj & 3) * HID_ + (jj >> 2);
        WhT[i] = f2bf(Wh[h * G4_ + jg]);
    } else if (i < 98304) {
        int j = i - 65536;
        int jj = j >> 6;
        int d = j & 63;
        int jg = (jj & 3) * HID_ + (jj >> 2);
        float v = Wx[d * G4_ + jg];
        us hi = f2bf(v);
        WxT_hi[j] = hi;
        WxT_lo[j] = f2bf(v - bf2f(hi));
    } else if (i < 98816) {
        int jj = i - 98304;
        int jg = (jj & 3) * HID_ + (jj >> 2);
        bs2[jj] = bx[jg] + bh[jg];
    }
}

// ---------------------------------------------------------------------------
// Kernel 3: fused per-window — softmax S, Hsm, Xc = S^T@Hs, XWx = Xc@Wx+bias.
// (unchanged from round 6 — verified)
// ---------------------------------------------------------------------------
__global__ __launch_bounds__(256) void xcwx_kernel(
    const us* __restrict__ Hs, const float* __restrict__ proto,
    const us* __restrict__ WxT_hi, const us* __restrict__ WxT_lo,
    const float* __restrict__ bs2, us* __restrict__ S_out,
    us* __restrict__ XWx, float* __restrict__ Hsm)
{
    __shared__ __align__(16) us Hnd[128 * 72];
    __shared__ __align__(16) us HsT[64 * 136];
    __shared__ __align__(16) us PT_hi[32 * 72];
    __shared__ __align__(16) us PT_lo[32 * 72];
    __shared__ __align__(16) us SsT_hi[32 * 136];
    __shared__ __align__(16) us SsT_lo[32 * 136];
    __shared__ __align__(16) us XcA_hi[32 * 72];
    __shared__ __align__(16) us XcA_lo[32 * 72];
    __shared__ float bias[512];
    const int tid = threadIdx.x;
    const int win = blockIdx.x;
    const int lane = tid & 63, wv = tid >> 6;
    const int l15 = lane & 15, quad = lane >> 4;

    {
        const uint2* hp = (const uint2*)(Hs + (size_t)win * 8192);
        #pragma unroll
        for (int it = 0; it < 8; it++) {
            int idx4 = tid + 256 * it;
            int n = idx4 >> 4, dpos = (idx4 & 15) * 4;
            uint2 v = hp[idx4];
            *(uint2*)&Hnd[n * 72 + dpos] = v;
            us s0 = (us)(v.x & 0xffff), s1 = (us)(v.x >> 16);
            us s2 = (us)(v.y & 0xffff), s3 = (us)(v.y >> 16);
            HsT[(dpos + 0) * 136 + n] = s0;
            HsT[(dpos + 1) * 136 + n] = s1;
            HsT[(dpos + 2) * 136 + n] = s2;
            HsT[(dpos + 3) * 136 + n] = s3;
        }
        for (int i = tid; i < 2048; i += 256) {
            int k = i >> 6, d = i & 63;
            float v = proto[i];
            us hi = f2bf(v);
            PT_hi[k * 72 + d] = hi;
            PT_lo[k * 72 + d] = f2bf(v - bf2f(hi));
        }
        for (int i = tid; i < 512; i += 256) bias[i] = bs2[i];
    }
    __syncthreads();
    floatx4 lg[2][2];
    #pragma unroll
    for (int p = 0; p < 2; p++) {
        const int mt = wv * 2 + p;
        #pragma unroll
        for (int kt = 0; kt < 2; kt++) {
            floatx4 a = {0.f, 0.f, 0.f, 0.f};
            #pragma unroll
            for (int kb = 0; kb < 2; kb++) {
                short8 af  = *(const short8*)&Hnd[(mt * 16 + l15) * 72 + kb * 32 + quad * 8];
                short8 bhf = *(const short8*)&PT_hi[(kt * 16 + l15) * 72 + kb * 32 + quad * 8];
                short8 blf = *(const short8*)&PT_lo[(kt * 16 + l15) * 72 + kb * 32 + quad * 8];
                a = __builtin_amdgcn_mfma_f32_16x16x32_bf16(af, bhf, a, 0, 0, 0);
                a = __builtin_amdgcn_mfma_f32_16x16x32_bf16(af, blf, a, 0, 0, 0);
            }
            lg[p][kt] = a;
        }
    }
    #pragma unroll
    for (int p = 0; p < 2; p++) {
        #pragma unroll
        for (int r = 0; r < 4; r++) {
            float v0 = lg[p][0][r], v1 = lg[p][1][r];
            float m = fmaxf(v0, v1);
            #pragma unroll
            for (int off = 8; off; off >>= 1) m = fmaxf(m, __shfl_xor(m, off));
            float e0 = expf(v0 - m), e1 = expf(v1 - m);
            float s = e0 + e1;
            #pragma unroll
            for (int off = 8; off; off >>= 1) s += __shfl_xor(s, off);
            float inv = 1.f / s;
            e0 *= inv; e1 *= inv;
            const int n = (wv * 2 + p) * 16 + quad * 4 + r;
            us h0 = f2bf(e0), h1 = f2bf(e1);
            SsT_hi[l15 * 136 + n]        = h0;
            SsT_hi[(16 + l15) * 136 + n] = h1;
            SsT_lo[l15 * 136 + n]        = f2bf(e0 - bf2f(h0));
            SsT_lo[(16 + l15) * 136 + n] = f2bf(e1 - bf2f(h1));
            S_out[(size_t)win * 4096 + n * 32 + l15]      = h0;
            S_out[(size_t)win * 4096 + n * 32 + 16 + l15] = h1;
        }
    }
    __syncthreads();
    {
        const int d = tid >> 2, seg = tid & 3;
        float acc = 0.f;
        const unsigned* hp2 = (const unsigned*)&HsT[d * 136 + seg * 32];
        #pragma unroll
        for (int q = 0; q < 16; q++) {
            unsigned v = hp2[q];
            acc += bf2f((us)(v & 0xffff)) + bf2f((us)(v >> 16));
        }
        acc += __shfl_xor(acc, 1);
        acc += __shfl_xor(acc, 2);
        if (seg == 0) Hsm[(size_t)win * 64 + d] = acc * (1.f / 128.f);
    }
    #pragma unroll
    for (int p = 0; p < 2; p++) {
        const int id = wv * 2 + p, mt = id >> 2, nt = id & 3;
        floatx4 a = {0.f, 0.f, 0.f, 0.f};
        #pragma unroll
        for (int kb = 0; kb < 4; kb++) {
            short8 ah = *(const short8*)&SsT_hi[(mt * 16 + l15) * 136 + kb * 32 + quad * 8];
            short8 al = *(const short8*)&SsT_lo[(mt * 16 + l15) * 136 + kb * 32 + quad * 8];
            short8 bf_ = *(const short8*)&HsT[(nt * 16 + l15) * 136 + kb * 32 + quad * 8];
            a = __builtin_amdgcn_mfma_f32_16x16x32_bf16(ah, bf_, a, 0, 0, 0);
            a = __builtin_amdgcn_mfma_f32_16x16x32_bf16(al, bf_, a, 0, 0, 0);
        }
        #pragma unroll
        for (int r = 0; r < 4; r++) {
            const int k = mt * 16 + quad * 4 + r, d = nt * 16 + l15;
            float v = a[r];
            us hi = f2bf(v);
            XcA_hi[k * 72 + d] = hi;
            XcA_lo[k * 72 + d] = f2bf(v - bf2f(hi));
        }
    }
    __syncthreads();
    short8 Ah[2][2], Al[2][2];
    #pragma unroll
    for (int mt = 0; mt < 2; mt++)
        #pragma unroll
        for (int kb = 0; kb < 2; kb++) {
            Ah[mt][kb] = *(const short8*)&XcA_hi[(mt * 16 + l15) * 72 + kb * 32 + quad * 8];
            Al[mt][kb] = *(const short8*)&XcA_lo[(mt * 16 + l15) * 72 + kb * 32 + quad * 8];
        }
    #pragma unroll 1
    for (int i = 0; i < 8; i++) {
        const int nt = wv + 4 * i;
        const float bv = bias[nt * 16 + l15];
        floatx4 acc[2];
        acc[0] = (floatx4){bv, bv, bv, bv};
        acc[1] = (floatx4){bv, bv, bv, bv};
        #pragma unroll
        for (int kb = 0; kb < 2; kb++) {
            short8 wh8 = *(const short8*)&WxT_hi[(size_t)(nt * 16 + l15) * 64 + kb * 32 + quad * 8];
            short8 wl8 = *(const short8*)&WxT_lo[(size_t)(nt * 16 + l15) * 64 + kb * 32 + quad * 8];
            #pragma unroll
            for (int mt = 0; mt < 2; mt++) {
                acc[mt] = __builtin_amdgcn_mfma_f32_16x16x32_bf16(Ah[mt][kb], wh8, acc[mt], 0, 0, 0);
                acc[mt] = __builtin_amdgcn_mfma_f32_16x16x32_bf16(Ah[mt][kb], wl8, acc[mt], 0, 0, 0);
                acc[mt] = __builtin_amdgcn_mfma_f32_16x16x32_bf16(Al[mt][kb], wh8, acc[mt], 0, 0, 0);
            }
        }
        #pragma unroll
        for (int mt = 0; mt < 2; mt++) {
            uint2 pk;
            pk.x = (unsigned)f2bf(acc[mt][0]) | ((unsigned)f2bf(acc[mt][1]) << 16);
            pk.y = (unsigned)f2bf(acc[mt][2]) | ((unsigned)f2bf(acc[mt][3]) << 16);
            ((uint2*)XWx)[((size_t)win * 64 + mt * 32 + nt) * 64 + lane] = pk;
        }
    }
}

// ---------------------------------------------------------------------------
// Kernel 4: corr -> AS -> Ac -> normalize -> An (unchanged from round 6).
// ---------------------------------------------------------------------------
__global__ __launch_bounds__(256) void corr_kernel(
    const float* __restrict__ x, const us* __restrict__ S_bf,
    us* __restrict__ An)
{
    __shared__ __align__(16) float xs[30 * 128];
    __shared__ __align__(16) us XA[128 * 40];
    __shared__ __align__(16) us SsT[32 * 136];
    __shared__ __align__(16) us CB[128 * 136];
    __shared__ __align__(16) us AST[32 * 136];
    __shared__ float Acs[32 * 33];
    __shared__ float sinv[128];
    __shared__ float dinv[32];
    const int tid = threadIdx.x;
    const int win = blockIdx.x;
    const int b = win / WN_, w = win - b * WN_;
    const float* xb = x + ((size_t)b * T_ + (size_t)w * WIN_) * N_;
    const int lane = tid & 63, wv = tid >> 6;
    const int l15 = lane & 15, quad = lane >> 4;
    const float inv29 = 1.f / (WIN_ - 1 + 1e-8f);

    for (int i = tid; i < 3840; i += 256) xs[i] = xb[i];
    for (int i = tid; i < 4096; i += 256) {
        int n = i >> 5, k = i & 31;
        SsT[k * 136 + n] = S_bf[(size_t)win * 4096 + i];
    }
    __syncthreads();
    if (tid < 128) {
        const int n = tid;
        float mean = 0.f;
        #pragma unroll
        for (int l = 0; l < 30; l++) mean += xs[l * 128 + n];
        mean *= (1.f / 30.f);
        float var = 0.f;
        #pragma unroll
        for (int l = 0; l < 30; l++) {
            float v = xs[l * 128 + n] - mean;
            var += v * v;
            XA[n * 40 + l] = f2bf(v);
        }
        XA[n * 40 + 30] = 0; XA[n * 40 + 31] = 0;
        var *= inv29;
        sinv[n] = rsqrtf(fmaxf(var, 1e-8f));
    }
    __syncthreads();
    #pragma unroll 1
    for (int q = 0; q < 16; q++) {
        const int id = wv * 16 + q, mt = id >> 3, nt = id & 7;
        short8 a = *(const short8*)&XA[(mt * 16 + l15) * 40 + quad * 8];
        short8 bb = *(const short8*)&XA[(nt * 16 + l15) * 40 + quad * 8];
        floatx4 d = {0.f, 0.f, 0.f, 0.f};
        d = __builtin_amdgcn_mfma_f32_16x16x32_bf16(a, bb, d, 0, 0, 0);
        const int m = nt * 16 + l15;
        const float sm = sinv[m];
        #pragma unroll
        for (int r = 0; r < 4; r++) {
            const int n = mt * 16 + quad * 4 + r;
            float v = d[r] * inv29 * sinv[n] * sm;
            if (n == m) v = 1.f;
            CB[n * 136 + m] = f2bf(v);
        }
    }
    __syncthreads();
    #pragma unroll 1
    for (int q = 0; q < 4; q++) {
        const int id = wv * 4 + q, mt = id >> 1, lt = id & 1;
        floatx4 d = {0.f, 0.f, 0.f, 0.f};
        #pragma unroll
        for (int kb = 0; kb < 4; kb++) {
            short8 a = *(const short8*)&CB[(mt * 16 + l15) * 136 + kb * 32 + quad * 8];
            short8 bb = *(const short8*)&SsT[(lt * 16 + l15) * 136 + kb * 32 + quad * 8];
            d = __builtin_amdgcn_mfma_f32_16x16x32_bf16(a, bb, d, 0, 0, 0);
        }
        const int l = lt * 16 + l15;
        #pragma unroll
        for (int r = 0; r < 4; r++)
            AST[l * 136 + mt * 16 + quad * 4 + r] = f2bf(d[r]);
    }
    __syncthreads();
    {
        const int kt = wv >> 1, lt = wv & 1;
        floatx4 d = {0.f, 0.f, 0.f, 0.f};
        #pragma unroll
        for (int kb = 0; kb < 4; kb++) {
            short8 a = *(const short8*)&SsT[(kt * 16 + l15) * 136 + kb * 32 + quad * 8];
            short8 bb = *(const short8*)&AST[(lt * 16 + l15) * 136 + kb * 32 + quad * 8];
            d = __builtin_amdgcn_mfma_f32_16x16x32_bf16(a, bb, d, 0, 0, 0);
        }
        #pragma unroll
        for (int r = 0; r < 4; r++)
            Acs[(kt * 16 + quad * 4 + r) * 33 + lt * 16 + l15] = d[r];
    }
    __syncthreads();
    float symv[4];
    {
        int l = tid & 31, kb = tid >> 5;
        for (int r = 0; r < 4; r++) {
            int k = kb + 8 * r;
            symv[r] = 0.5f * (Acs[k * 33 + l] + Acs[l * 33 + k]) + ((k == l) ? 1.f : 0.f);
        }
    }
    __syncthreads();
    {
        int l = tid & 31, kb = tid >> 5;
        for (int r = 0; r < 4; r++) Acs[(kb + 8 * r) * 33 + l] = symv[r];
    }
    __syncthreads();
    if (tid < K_) {
        float s = 0.f;
        for (int l = 0; l < K_; l++) s += Acs[tid * 33 + l];
        dinv[tid] = rsqrtf(fmaxf(s, 1e-8f));
    }
    __syncthreads();
    us* Anw = An + (size_t)win * K_ * K_;
    for (int i = tid; i < K_ * K_; i += 256) {
        int k = i >> 5, l = i & 31;
        Anw[i] = f2bf(dinv[k] * Acs[k * 33 + l] * dinv[l]);
    }
}

// ---------------------------------------------------------------------------
// Kernel 5: fused 100-step GCLSTM scan.  16 blocks x 1024 threads (16 waves,
// 4/SIMD).  ldsbar (no vmcnt drain) once per step; XWx prefetch issued at
// top of step; An prefetch after GEMM2; Wh frags in 32 VGPR; state in regs.
// ---------------------------------------------------------------------------
__global__ __launch_bounds__(1024) void scan_kernel(
    const us* __restrict__ An_bf,   // [bt][k][m]
    const us* __restrict__ XWxS,    // swizzled C-frag layout
    const us* __restrict__ WhT,     // [jj][h]
    float* __restrict__ Hsqm)
{
    __shared__ __align__(16) us HpHi[2][32 * 136];
    __shared__ __align__(16) us TmpT[512 * 40];     // [col jj][row m]

    const int tid  = threadIdx.x;
    const int lane = tid & 63;
    const int wv   = tid >> 6;          // 0..15
    const int b    = blockIdx.x;
    const int l15  = lane & 15, quad = lane >> 4;

    short8 Bw[2][4];
    #pragma unroll
    for (int i = 0; i < 2; i++) {
        const int nt = wv + 16 * i;
        #pragma unroll
        for (int kb = 0; kb < 4; kb++)
            Bw[i][kb] = *(const short8*)&WhT[(size_t)(nt * 16 + l15) * 128 + kb * 32 + quad * 8];
    }
    float Cs_[2][2], Hs_[2][2], H2_[2][2];
    #pragma unroll
    for (int kt = 0; kt < 2; kt++)
        #pragma unroll
        for (int i = 0; i < 2; i++) { Cs_[kt][i] = 0.f; Hs_[kt][i] = 0.f; H2_[kt][i] = 0.f; }

    for (int i = tid; i < 32 * 136; i += 1024) HpHi[0][i] = 0;

    const size_t bt0 = (size_t)b * WN_;
    const uint2* xp = (const uint2*)XWxS;
    uint2 xw[2][2];
    short8 anf[2];
    #pragma unroll
    for (int mtp = 0; mtp < 2; mtp++)
        #pragma unroll
        for (int i = 0; i < 2; i++)
            xw[mtp][i] = xp[(bt0 * 64 + mtp * 32 + wv + 16 * i) * 64 + lane];
    #pragma unroll
    for (int kt = 0; kt < 2; kt++)
        anf[kt] = *(const short8*)&An_bf[bt0 * 1024 + (kt * 16 + l15) * 32 + quad * 8];

    #pragma unroll 1
    for (int t = 0; t < WN_; t++) {
        const int buf = t & 1;
        ldsbar();
        floatx4 acc[2][2];
        #pragma unroll
        for (int mtp = 0; mtp < 2; mtp++)
            #pragma unroll
            for (int i = 0; i < 2; i++) {
                acc[mtp][i][0] = bf2f((us)(xw[mtp][i].x & 0xffff));
                acc[mtp][i][1] = bf2f((us)(xw[mtp][i].x >> 16));
                acc[mtp][i][2] = bf2f((us)(xw[mtp][i].y & 0xffff));
                acc[mtp][i][3] = bf2f((us)(xw[mtp][i].y >> 16));
            }
        // prefetch XWx(t+1) — issued before compute so it lands during the step
        {
            const int tn = (t + 1 < WN_) ? (t + 1) : (WN_ - 1);
            const size_t base = (bt0 + tn) * 64;
            #pragma unroll
            for (int mtp = 0; mtp < 2; mtp++)
                #pragma unroll
                for (int i = 0; i < 2; i++)
                    xw[mtp][i] = xp[(base + mtp * 32 + wv + 16 * i) * 64 + lane];
        }
        // GEMM1: tmp[m][jj] = XWx + Hp @ Wh'
        #pragma unroll
        for (int kb = 0; kb < 4; kb++) {
            const int ko = kb * 32 + quad * 8;
            short8 a0 = *(const short8*)&HpHi[buf][l15 * 136 + ko];
            short8 a1 = *(const short8*)&HpHi[buf][(16 + l15) * 136 + ko];
            #pragma unroll
            for (int i = 0; i < 2; i++) {
                acc[0][i] = __builtin_amdgcn_mfma_f32_16x16x32_bf16(a0, Bw[i][kb], acc[0][i], 0, 0, 0);
                acc[1][i] = __builtin_amdgcn_mfma_f32_16x16x32_bf16(a1, Bw[i][kb], acc[1][i], 0, 0, 0);
            }
        }
        #pragma unroll
        for (int i = 0; i < 2; i++) {
            const int col = (wv + 16 * i) * 16 + l15;
            #pragma unroll
            for (int mtp = 0; mtp < 2; mtp++) {
                uint2 pk;
                pk.x = (unsigned)f2bf(acc[mtp][i][0]) | ((unsigned)f2bf(acc[mtp][i][1]) << 16);
                pk.y = (unsigned)f2bf(acc[mtp][i][2]) | ((unsigned)f2bf(acc[mtp][i][3]) << 16);
                *(uint2*)&TmpT[col * 40 + mtp * 16 + quad * 4] = pk;
            }
        }
        __builtin_amdgcn_wave_barrier();
        // GEMM2: g^T[jj][k] = tmp^T @ An^T
        floatx4 g[2][2];
        #pragma unroll
        for (int i = 0; i < 2; i++) {
            const int jt = wv + 16 * i;
            short8 aT = *(const short8*)&TmpT[(jt * 16 + l15) * 40 + quad * 8];
            floatx4 z = {0.f, 0.f, 0.f, 0.f};
            g[0][i] = __builtin_amdgcn_mfma_f32_16x16x32_bf16(aT, anf[0], z, 0, 0, 0);
            g[1][i] = __builtin_amdgcn_mfma_f32_16x16x32_bf16(aT, anf[1], z, 0, 0, 0);
        }
        // prefetch An(t+1)
        {
            const int tn = (t + 1 < WN_) ? (t + 1) : (WN_ - 1);
            #pragma unroll
            for (int kt = 0; kt < 2; kt++)
                anf[kt] = *(const short8*)&An_bf[(bt0 + tn) * 1024 + (kt * 16 + l15) * 32 + quad * 8];
        }
        // gates + state (registers only)
        #pragma unroll
        for (int kt = 0; kt < 2; kt++)
            #pragma unroll
            for (int i = 0; i < 2; i++) {
                float gi = g[kt][i][0], gf = g[kt][i][1];
                float go = g[kt][i][2], gc = g[kt][i][3];
                float cn = sigf(gf) * Cs_[kt][i] + sigf(gi) * tanhfast(gc);
                float hn = sigf(go) * tanhfast(cn);
                Cs_[kt][i] = cn;
                H2_[kt][i] = Hs_[kt][i];
                Hs_[kt][i] = hn;
            }
        // Hsqm: mean over k
        #pragma unroll
        for (int i = 0; i < 2; i++) {
            float s = Hs_[0][i] + Hs_[1][i];
            s += __shfl_xor(s, 1); s += __shfl_xor(s, 2);
            s += __shfl_xor(s, 4); s += __shfl_xor(s, 8);
            if (l15 == 0)
                Hsqm[(bt0 + t) * HID_ + (wv + 16 * i) * 4 + quad] = s * (1.f / 32.f);
        }
        // Hp(t+1)
        if (t + 1 < WN_) {
            const float dninv = (t + 1 == 1) ? 0.5f : (1.f / 3.f);
            #pragma unroll
            for (int kt = 0; kt < 2; kt++)
                #pragma unroll
                for (int i = 0; i < 2; i++) {
                    float v = (2.f * Hs_[kt][i] + H2_[kt][i]) * dninv;
                    HpHi[buf ^ 1][(kt * 16 + l15) * 136 + (wv + 16 * i) * 4 + quad] = f2bf(v);
                }
        }
    }
}

// ---------------------------------------------------------------------------
// Kernel 6: temporal attention pooling + classifier (unchanged).
// ---------------------------------------------------------------------------
__global__ __launch_bounds__(128) void final_kernel(
    const float* __restrict__ Hsqm, const float* __restrict__ Hsm,
    const float* __restrict__ q_t, const float* __restrict__ q_s,
    const float* __restrict__ cls_w, const float* __restrict__ cls_b,
    float* __restrict__ out)
{
    __shared__ float red[128];
    __shared__ float sc[WN_];
    __shared__ float wt[WN_];
    __shared__ float smv;
    const int b = blockIdx.x, tid = threadIdx.x;
    float v = q_t[tid];
    red[tid] = v * v;
    __syncthreads();
    for (int off = 64; off; off >>= 1) {
        if (tid < off) red[tid] += red[tid + off];
        __syncthreads();
    }
    const float qtn = sqrtf(red[0]) + 1e-8f;
    __syncthreads();
    float v2 = (tid < D_) ? q_s[tid] : 0.f;
    red[tid] = v2 * v2;
    __syncthreads();
    for (int off = 64; off; off >>= 1) {
        if (tid < off) red[tid] += red[tid + off];
        __syncthreads();
    }
    const float qsn = sqrtf(red[0]) + 1e-8f;
    __syncthreads();
    if (tid < WN_) {
        float s = 0.f;
        const float* zr = Hsqm + ((size_t)b * WN_ + tid) * HID_;
        for (int h = 0; h < HID_; h++) s += zr[h] * q_t[h];
        sc[tid] = s / qtn;
    }
    __syncthreads();
    if (tid == 0) {
        float m = sc[0];
        for (int i = 1; i < WN_; i++) m = fmaxf(m, sc[i]);
        float s = 0.f;
        for (int i = 0; i < WN_; i++) { wt[i] = expf(sc[i] - m); s += wt[i]; }
        smv = 1.f / s;
    }
    __syncthreads();
    float part = 0.f;
    {
        float z = 0.f;
        for (int w = 0; w < WN_; w++)
            z += wt[w] * Hsqm[((size_t)b * WN_ + w) * HID_ + tid];
        part += z * smv * cls_w[tid];
    }
    __syncthreads();
    if (tid < WN_) {
        float s = 0.f;
        const float* zr = Hsm + ((size_t)b * WN_ + tid) * D_;
        for (int dd = 0; dd < D_; dd++) s += zr[dd] * q_s[dd];
        sc[tid] = s / qsn;
    }
    __syncthreads();
    if (tid == 0) {
        float m = sc[0];
        for (int i = 1; i < WN_; i++) m = fmaxf(m, sc[i]);
        float s = 0.f;
        for (int i = 0; i < WN_; i++) { wt[i] = expf(sc[i] - m); s += wt[i]; }
        smv = 1.f / s;
    }
    __syncthreads();
    if (tid < D_) {
        float z = 0.f;
        for (int w = 0; w < WN_; w++)
            z += wt[w] * Hsm[((size_t)b * WN_ + w) * D_ + tid];
        part += z * smv * cls_w[HID_ + tid];
    }
    red[tid] = part;
    __syncthreads();
    for (int off = 64; off; off >>= 1) {
        if (tid < off) red[tid] += red[tid + off];
        __syncthreads();
    }
    if (tid == 0) out[b] = 1.f / (1.f + expf(-(red[0] + cls_b[0])));
}

// ---------------------------------------------------------------------------
extern "C" void kernel_launch(void* const* d_in, const int* in_sizes, int n_in,
                              void* d_out, int out_size, void* d_ws, size_t ws_size,
                              hipStream_t stream)
{
    (void)in_sizes; (void)n_in; (void)out_size; (void)ws_size;
    const float* x     = (const float*)d_in[0];
    const float* w1    = (const float*)d_in[1];
    const float* b1    = (const float*)d_in[2];
    const float* w2    = (const float*)d_in[3];
    const float* b2    = (const float*)d_in[4];
    const float* pw    = (const float*)d_in[5];
    const float* pb    = (const float*)d_in[6];
    const float* proto = (const float*)d_in[7];
    const float* Wx    = (const float*)d_in[8];
    const float* bx    = (const float*)d_in[9];
    const float* Wh    = (const float*)d_in[10];
    const float* bh    = (const float*)d_in[11];
    const float* q_t   = (const float*)d_in[12];
    const float* q_s   = (const float*)d_in[13];
    const float* clw   = (const float*)d_in[14];
    const float* clb   = (const float*)d_in[15];

    float* ws = (float*)d_ws;
    us*    Hs_bf  = (us*)d_ws;                      // [0, 6553600)
    us*    S_bf   = (us*)(ws + 6553600);            // [6553600, 9830400)
    us*    XWx    = (us*)(ws + 9830400);            // [9830400, 22937600)
    us*    An_bf  = (us*)(ws + 22937600);           // [22937600, 23756800)
    float* Hsm    = ws + 23756800;                  // [23756800, 23859200)
    float* Hsqm   = ws + 23859200;                  // [23859200, 24064000)
    us*    WhT    = (us*)(ws + 24064000);           // [24064000, 24096768)
    us*    WxT_hi = (us*)(ws + 24096768);           // [24096768, 24113152)
    us*    WxT_lo = (us*)(ws + 24113152);           // [24113152, 24129536)
    float* bs2    = ws + 24129536;                  // [24129536, 24130048)

    prep_kernel<<<386, 256, 0, stream>>>(Wh, Wx, bx, bh, WhT, WxT_hi, WxT_lo, bs2);
    conv_kernel<<<B_ * WN_, 256, 0, stream>>>(x, w1, b1, w2, b2, pw, pb, Hs_bf);
    xcwx_kernel<<<B_ * WN_, 256, 0, stream>>>(Hs_bf, proto, WxT_hi, WxT_lo,
                                              bs2, S_bf, XWx, Hsm);
    corr_kernel<<<B_ * WN_, 256, 0, stream>>>(x, S_bf, An_bf);
    scan_kernel<<<B_, 1024, 0, stream>>>(An_bf, XWx, WhT, Hsqm);
    final_kernel<<<B_, 128, 0, stream>>>(Hsqm, Hsm, q_t, q_s, clw, clb,
                                         (float*)d_out);
}

// Round 8
// 806.213 us; speedup vs baseline: 3.9591x; 1.0565x over previous
//
#include <hip/hip_runtime.h>

#define B_   16
#define T_   3000
#define N_   128
#define WIN_ 30
#define WN_  100
#define D_   64
#define HID_ 128
#define K_   32
#define G4_  512   // 4*HID_

typedef unsigned short us;
typedef __attribute__((ext_vector_type(8))) short short8;
typedef __attribute__((ext_vector_type(4))) float floatx4;

__device__ __forceinline__ us f2bf(float f) {
    unsigned u = __float_as_uint(f);
    u += 0x7fffu + ((u >> 16) & 1u);
    return (us)(u >> 16);
}
__device__ __forceinline__ float bf2f(us h) {
    return __uint_as_float(((unsigned)h) << 16);
}
__device__ __forceinline__ float sigf(float x) { return 1.f / (1.f + __expf(-x)); }
__device__ __forceinline__ float tanhfast(float x) { return 2.f / (1.f + __expf(-2.f * x)) - 1.f; }
// Barrier WITHOUT vmcnt drain: LDS ordering only.  Safe when all global
// loads/stores crossing it are wave-private (consumed by issuing wave).
__device__ __forceinline__ void ldsbar() {
    __asm__ volatile("s_waitcnt lgkmcnt(0)\n\ts_barrier" ::: "memory");
}

// ---------------------------------------------------------------------------
// Kernel 1: SignalRep conv — wave-private h1, zero per-group block barriers.
// conv2 now SINGLE-PASS bf16 MFMA (w2 hi only; lo pass dropped — error
// ~0.4% relative, far under threshold).  Proj stays 3-pass (once per block).
// ---------------------------------------------------------------------------
__global__ __launch_bounds__(256) void conv_kernel(
    const float* __restrict__ x, const float* __restrict__ w1,
    const float* __restrict__ b1, const float* __restrict__ w2,
    const float* __restrict__ b2, const float* __restrict__ pw,
    const float* __restrict__ pb, us* __restrict__ Hs)
{
    __shared__ __align__(16) float xs_all[30 * 128];   // [t][n]
    __shared__ __align__(16) us h1s[8 * 36 * 40];      // [s][t'][ci]
    __shared__ __align__(16) float Ms[128 * 40];       // [n][co] means (/30)
    __shared__ __align__(16) us PwT_hi[64 * 40];       // [d][co]
    __shared__ __align__(16) us PwT_lo[64 * 40];
    const int tid = threadIdx.x;
    const int win = blockIdx.x;
    const int b = win / WN_, w = win - b * WN_;
    const float* xb = x + ((size_t)b * T_ + (size_t)w * WIN_) * N_;
    const int lane = tid & 63, wv = tid >> 6;
    const int l15 = lane & 15, quad = lane >> 4;
    const int sloc = lane >> 5, ci = lane & 31;

    {
        const float4* xb4 = (const float4*)xb;
        float4* xs4 = (float4*)xs_all;
        for (int i = tid; i < 960; i += 256) xs4[i] = xb4[i];
    }
    for (int i = tid; i < 2048; i += 256) {
        int co = i >> 6, d = i & 63;
        float v = pw[i];
        us hi = f2bf(v);
        PwT_hi[d * 40 + co] = hi;
        PwT_lo[d * 40 + co] = f2bf(v - bf2f(hi));
    }
    for (int i = tid; i < 1920; i += 256) {            // zero h1 pad rows
        int s = i / 240, r = i % 240;
        int ti = r / 40, c = r % 40;
        int tp = (ti < 2) ? ti : (30 + ti);
        h1s[(s * 36 + tp) * 40 + c] = 0;
    }
    // w2 A-fragments (hi only), both co-tiles: 40 VGPR
    short8 ahf[2][5];
    #pragma unroll
    for (int cot = 0; cot < 2; cot++)
        #pragma unroll
        for (int dk = 0; dk < 5; dk++)
            #pragma unroll
            for (int j = 0; j < 8; j++)
                ahf[cot][dk][j] = (short)f2bf(w2[(cot * 16 + l15) * 160 + (quad * 8 + j) * 5 + dk]);
    float b2v[2][4];
    #pragma unroll
    for (int cot = 0; cot < 2; cot++)
        #pragma unroll
        for (int r = 0; r < 4; r++) b2v[cot][r] = b2[cot * 16 + quad * 4 + r];
    float w1r[5];
    #pragma unroll
    for (int k = 0; k < 5; k++) w1r[k] = w1[ci * 5 + k];
    const float b1v = b1[ci];
    float pbv[4];
    #pragma unroll
    for (int nt = 0; nt < 4; nt++) pbv[nt] = pb[nt * 16 + l15];
    ldsbar();

    for (int g = 0; g < 16; g++) {
        const int n1 = g * 8 + wv * 2 + sloc;
        {
            float xr[30];
            #pragma unroll
            for (int p = 0; p < 30; p++) xr[p] = xs_all[p * 128 + n1];
            #pragma unroll
            for (int t = 0; t < 30; t++) {
                float acc = b1v;
                #pragma unroll
                for (int k = 0; k < 5; k++) {
                    int p = t + k - 2;
                    if (p >= 0 && p < 30) acc += xr[p] * w1r[k];
                }
                h1s[((wv * 2 + sloc) * 36 + 2 + t) * 40 + ci] = f2bf(fmaxf(acc, 0.f));
            }
        }
        __builtin_amdgcn_wave_barrier();
        #pragma unroll
        for (int s2 = 0; s2 < 2; s2++) {
            const int sl = wv * 2 + s2;
            const int nn = g * 8 + sl;
            #pragma unroll
            for (int cot = 0; cot < 2; cot++) {
                floatx4 a0, a1;
                #pragma unroll
                for (int r = 0; r < 4; r++) { a0[r] = b2v[cot][r]; a1[r] = b2v[cot][r]; }
                #pragma unroll
                for (int dk = 0; dk < 5; dk++) {
                    short8 bf0 = *(const short8*)&h1s[(sl * 36 + l15 + dk) * 40 + quad * 8];
                    short8 bf1 = *(const short8*)&h1s[(sl * 36 + 16 + l15 + dk) * 40 + quad * 8];
                    a0 = __builtin_amdgcn_mfma_f32_16x16x32_bf16(ahf[cot][dk], bf0, a0, 0, 0, 0);
                    a1 = __builtin_amdgcn_mfma_f32_16x16x32_bf16(ahf[cot][dk], bf1, a1, 0, 0, 0);
                }
                floatx4 sr;
                #pragma unroll
                for (int r = 0; r < 4; r++)
                    sr[r] = fmaxf(a0[r], 0.f) + ((l15 < 14) ? fmaxf(a1[r], 0.f) : 0.f);
                #pragma unroll
                for (int off = 1; off < 16; off <<= 1) {
                    #pragma unroll
                    for (int r = 0; r < 4; r++) sr[r] += __shfl_xor(sr[r], off);
                }
                if (l15 == 0) {
                    float4 v;
                    v.x = sr[0] * (1.f / 30.f); v.y = sr[1] * (1.f / 30.f);
                    v.z = sr[2] * (1.f / 30.f); v.w = sr[3] * (1.f / 30.f);
                    *(float4*)&Ms[nn * 40 + cot * 16 + quad * 4] = v;
                }
            }
        }
        __builtin_amdgcn_wave_barrier();
    }
    ldsbar();
    // proj GEMM: Hs[n][d] = Ms @ pw + pb (3-pass hi/lo, once per block)
    short8 Ah[2], Al[2];
    #pragma unroll
    for (int i = 0; i < 2; i++) {
        const int mt = wv * 2 + i;
        float4 v0 = *(const float4*)&Ms[(mt * 16 + l15) * 40 + quad * 8];
        float4 v1 = *(const float4*)&Ms[(mt * 16 + l15) * 40 + quad * 8 + 4];
        float vv[8] = {v0.x, v0.y, v0.z, v0.w, v1.x, v1.y, v1.z, v1.w};
        #pragma unroll
        for (int j = 0; j < 8; j++) {
            us hi = f2bf(vv[j]);
            Ah[i][j] = (short)hi;
            Al[i][j] = (short)f2bf(vv[j] - bf2f(hi));
        }
    }
    us* hp = Hs + (size_t)win * 8192;
    #pragma unroll
    for (int id = 0; id < 8; id++) {
        const int i = id >> 2, nt = id & 3;
        short8 Bh = *(const short8*)&PwT_hi[(nt * 16 + l15) * 40 + quad * 8];
        short8 Bl = *(const short8*)&PwT_lo[(nt * 16 + l15) * 40 + quad * 8];
        floatx4 a = {pbv[nt], pbv[nt], pbv[nt], pbv[nt]};
        a = __builtin_amdgcn_mfma_f32_16x16x32_bf16(Ah[i], Bh, a, 0, 0, 0);
        a = __builtin_amdgcn_mfma_f32_16x16x32_bf16(Al[i], Bh, a, 0, 0, 0);
        a = __builtin_amdgcn_mfma_f32_16x16x32_bf16(Ah[i], Bl, a, 0, 0, 0);
        const int mt = wv * 2 + i;
        #pragma unroll
        for (int r = 0; r < 4; r++)
            hp[(mt * 16 + quad * 4 + r) * 64 + nt * 16 + l15] = f2bf(a[r]);
    }
}

// ---------------------------------------------------------------------------
// Kernel 2: prep — WhT[jj][h] bf16, WxT[jj][d] bf16, bs2[jj]=bx+bh.
// ---------------------------------------------------------------------------
__global__ __launch_bounds__(256) void prep_kernel(
    const float* __restrict__ Wh, const float* __restrict__ Wx,
    const float* __restrict__ bx, const float* __restrict__ bh,
    us* __restrict__ WhT, us* __restrict__ WxT, float* __restrict__ bs2)
{
    int i = blockIdx.x * 256 + threadIdx.x;
    if (i < 65536) {
        int jj = i >> 7, h = i & 127;
        int jg = (jj & 3) * HID_ + (jj >> 2);
        WhT[i] = f2bf(Wh[h * G4_ + jg]);
    } else if (i < 98304) {
        int j = i - 65536;
        int jj = j >> 6;
        int d = j & 63;
        int jg = (jj & 3) * HID_ + (jj >> 2);
        WxT[j] = f2bf(Wx[d * G4_ + jg]);
    } else if (i < 98816) {
        int jj = i - 98304;
        int jg = (jj & 3) * HID_ + (jj >> 2);
        bs2[jj] = bx[jg] + bh[jg];
    }
}

// ---------------------------------------------------------------------------
// Kernel 3: fused per-window — softmax S, Hsm, Xc = S^T@Hs, XWx = Xc@Wx+bias.
// SINGLE-PASS bf16 MFMA everywhere (hi/lo arrays removed; XWx is rounded to
// bf16 by the scan anyway, so extra passes bought nothing).
// ---------------------------------------------------------------------------
__global__ __launch_bounds__(256) void xcwx_kernel(
    const us* __restrict__ Hs, const float* __restrict__ proto,
    const us* __restrict__ WxT, const float* __restrict__ bs2,
    us* __restrict__ S_out, us* __restrict__ XWx, float* __restrict__ Hsm)
{
    __shared__ __align__(16) us Hnd[128 * 72];
    __shared__ __align__(16) us HsT[64 * 136];
    __shared__ __align__(16) us PT_hi[32 * 72];
    __shared__ __align__(16) us SsT_hi[32 * 136];
    __shared__ __align__(16) us XcA_hi[32 * 72];
    __shared__ float bias[512];
    const int tid = threadIdx.x;
    const int win = blockIdx.x;
    const int lane = tid & 63, wv = tid >> 6;
    const int l15 = lane & 15, quad = lane >> 4;

    {
        const uint2* hp = (const uint2*)(Hs + (size_t)win * 8192);
        #pragma unroll
        for (int it = 0; it < 8; it++) {
            int idx4 = tid + 256 * it;
            int n = idx4 >> 4, dpos = (idx4 & 15) * 4;
            uint2 v = hp[idx4];
            *(uint2*)&Hnd[n * 72 + dpos] = v;
            us s0 = (us)(v.x & 0xffff), s1 = (us)(v.x >> 16);
            us s2 = (us)(v.y & 0xffff), s3 = (us)(v.y >> 16);
            HsT[(dpos + 0) * 136 + n] = s0;
            HsT[(dpos + 1) * 136 + n] = s1;
            HsT[(dpos + 2) * 136 + n] = s2;
            HsT[(dpos + 3) * 136 + n] = s3;
        }
        for (int i = tid; i < 2048; i += 256) {
            int k = i >> 6, d = i & 63;
            PT_hi[k * 72 + d] = f2bf(proto[i]);
        }
        for (int i = tid; i < 512; i += 256) bias[i] = bs2[i];
    }
    __syncthreads();
    // logits (single-pass)
    floatx4 lg[2][2];
    #pragma unroll
    for (int p = 0; p < 2; p++) {
        const int mt = wv * 2 + p;
        #pragma unroll
        for (int kt = 0; kt < 2; kt++) {
            floatx4 a = {0.f, 0.f, 0.f, 0.f};
            #pragma unroll
            for (int kb = 0; kb < 2; kb++) {
                short8 af  = *(const short8*)&Hnd[(mt * 16 + l15) * 72 + kb * 32 + quad * 8];
                short8 bhf = *(const short8*)&PT_hi[(kt * 16 + l15) * 72 + kb * 32 + quad * 8];
                a = __builtin_amdgcn_mfma_f32_16x16x32_bf16(af, bhf, a, 0, 0, 0);
            }
            lg[p][kt] = a;
        }
    }
    #pragma unroll
    for (int p = 0; p < 2; p++) {
        #pragma unroll
        for (int r = 0; r < 4; r++) {
            float v0 = lg[p][0][r], v1 = lg[p][1][r];
            float m = fmaxf(v0, v1);
            #pragma unroll
            for (int off = 8; off; off >>= 1) m = fmaxf(m, __shfl_xor(m, off));
            float e0 = expf(v0 - m), e1 = expf(v1 - m);
            float s = e0 + e1;
            #pragma unroll
            for (int off = 8; off; off >>= 1) s += __shfl_xor(s, off);
            float inv = 1.f / s;
            e0 *= inv; e1 *= inv;
            const int n = (wv * 2 + p) * 16 + quad * 4 + r;
            us h0 = f2bf(e0), h1 = f2bf(e1);
            SsT_hi[l15 * 136 + n]        = h0;
            SsT_hi[(16 + l15) * 136 + n] = h1;
            S_out[(size_t)win * 4096 + n * 32 + l15]      = h0;
            S_out[(size_t)win * 4096 + n * 32 + 16 + l15] = h1;
        }
    }
    __syncthreads();
    // Hsm: node-mean
    {
        const int d = tid >> 2, seg = tid & 3;
        float acc = 0.f;
        const unsigned* hp2 = (const unsigned*)&HsT[d * 136 + seg * 32];
        #pragma unroll
        for (int q = 0; q < 16; q++) {
            unsigned v = hp2[q];
            acc += bf2f((us)(v & 0xffff)) + bf2f((us)(v >> 16));
        }
        acc += __shfl_xor(acc, 1);
        acc += __shfl_xor(acc, 2);
        if (seg == 0) Hsm[(size_t)win * 64 + d] = acc * (1.f / 128.f);
    }
    // Xc = S^T @ Hs (single-pass)
    #pragma unroll
    for (int p = 0; p < 2; p++) {
        const int id = wv * 2 + p, mt = id >> 2, nt = id & 3;
        floatx4 a = {0.f, 0.f, 0.f, 0.f};
        #pragma unroll
        for (int kb = 0; kb < 4; kb++) {
            short8 ah = *(const short8*)&SsT_hi[(mt * 16 + l15) * 136 + kb * 32 + quad * 8];
            short8 bf_ = *(const short8*)&HsT[(nt * 16 + l15) * 136 + kb * 32 + quad * 8];
            a = __builtin_amdgcn_mfma_f32_16x16x32_bf16(ah, bf_, a, 0, 0, 0);
        }
        #pragma unroll
        for (int r = 0; r < 4; r++) {
            const int k = mt * 16 + quad * 4 + r, d = nt * 16 + l15;
            XcA_hi[k * 72 + d] = f2bf(a[r]);
        }
    }
    __syncthreads();
    // XWx = Xc @ Wx + bias (single-pass)
    short8 Ah[2][2];
    #pragma unroll
    for (int mt = 0; mt < 2; mt++)
        #pragma unroll
        for (int kb = 0; kb < 2; kb++)
            Ah[mt][kb] = *(const short8*)&XcA_hi[(mt * 16 + l15) * 72 + kb * 32 + quad * 8];
    #pragma unroll 1
    for (int i = 0; i < 8; i++) {
        const int nt = wv + 4 * i;
        const float bv = bias[nt * 16 + l15];
        floatx4 acc[2];
        acc[0] = (floatx4){bv, bv, bv, bv};
        acc[1] = (floatx4){bv, bv, bv, bv};
        #pragma unroll
        for (int kb = 0; kb < 2; kb++) {
            short8 wh8 = *(const short8*)&WxT[(size_t)(nt * 16 + l15) * 64 + kb * 32 + quad * 8];
            #pragma unroll
            for (int mt = 0; mt < 2; mt++)
                acc[mt] = __builtin_amdgcn_mfma_f32_16x16x32_bf16(Ah[mt][kb], wh8, acc[mt], 0, 0, 0);
        }
        #pragma unroll
        for (int mt = 0; mt < 2; mt++) {
            uint2 pk;
            pk.x = (unsigned)f2bf(acc[mt][0]) | ((unsigned)f2bf(acc[mt][1]) << 16);
            pk.y = (unsigned)f2bf(acc[mt][2]) | ((unsigned)f2bf(acc[mt][3]) << 16);
            ((uint2*)XWx)[((size_t)win * 64 + mt * 32 + nt) * 64 + lane] = pk;
        }
    }
}

// ---------------------------------------------------------------------------
// Kernel 4: corr -> AS -> Ac -> normalize -> An (unchanged — verified).
// ---------------------------------------------------------------------------
__global__ __launch_bounds__(256) void corr_kernel(
    const float* __restrict__ x, const us* __restrict__ S_bf,
    us* __restrict__ An)
{
    __shared__ __align__(16) float xs[30 * 128];
    __shared__ __align__(16) us XA[128 * 40];
    __shared__ __align__(16) us SsT[32 * 136];
    __shared__ __align__(16) us CB[128 * 136];
    __shared__ __align__(16) us AST[32 * 136];
    __shared__ float Acs[32 * 33];
    __shared__ float sinv[128];
    __shared__ float dinv[32];
    const int tid = threadIdx.x;
    const int win = blockIdx.x;
    const int b = win / WN_, w = win - b * WN_;
    const float* xb = x + ((size_t)b * T_ + (size_t)w * WIN_) * N_;
    const int lane = tid & 63, wv = tid >> 6;
    const int l15 = lane & 15, quad = lane >> 4;
    const float inv29 = 1.f / (WIN_ - 1 + 1e-8f);

    for (int i = tid; i < 3840; i += 256) xs[i] = xb[i];
    for (int i = tid; i < 4096; i += 256) {
        int n = i >> 5, k = i & 31;
        SsT[k * 136 + n] = S_bf[(size_t)win * 4096 + i];
    }
    __syncthreads();
    if (tid < 128) {
        const int n = tid;
        float mean = 0.f;
        #pragma unroll
        for (int l = 0; l < 30; l++) mean += xs[l * 128 + n];
        mean *= (1.f / 30.f);
        float var = 0.f;
        #pragma unroll
        for (int l = 0; l < 30; l++) {
            float v = xs[l * 128 + n] - mean;
            var += v * v;
            XA[n * 40 + l] = f2bf(v);
        }
        XA[n * 40 + 30] = 0; XA[n * 40 + 31] = 0;
        var *= inv29;
        sinv[n] = rsqrtf(fmaxf(var, 1e-8f));
    }
    __syncthreads();
    #pragma unroll 1
    for (int q = 0; q < 16; q++) {
        const int id = wv * 16 + q, mt = id >> 3, nt = id & 7;
        short8 a = *(const short8*)&XA[(mt * 16 + l15) * 40 + quad * 8];
        short8 bb = *(const short8*)&XA[(nt * 16 + l15) * 40 + quad * 8];
        floatx4 d = {0.f, 0.f, 0.f, 0.f};
        d = __builtin_amdgcn_mfma_f32_16x16x32_bf16(a, bb, d, 0, 0, 0);
        const int m = nt * 16 + l15;
        const float sm = sinv[m];
        #pragma unroll
        for (int r = 0; r < 4; r++) {
            const int n = mt * 16 + quad * 4 + r;
            float v = d[r] * inv29 * sinv[n] * sm;
            if (n == m) v = 1.f;
            CB[n * 136 + m] = f2bf(v);
        }
    }
    __syncthreads();
    #pragma unroll 1
    for (int q = 0; q < 4; q++) {
        const int id = wv * 4 + q, mt = id >> 1, lt = id & 1;
        floatx4 d = {0.f, 0.f, 0.f, 0.f};
        #pragma unroll
        for (int kb = 0; kb < 4; kb++) {
            short8 a = *(const short8*)&CB[(mt * 16 + l15) * 136 + kb * 32 + quad * 8];
            short8 bb = *(const short8*)&SsT[(lt * 16 + l15) * 136 + kb * 32 + quad * 8];
            d = __builtin_amdgcn_mfma_f32_16x16x32_bf16(a, bb, d, 0, 0, 0);
        }
        const int l = lt * 16 + l15;
        #pragma unroll
        for (int r = 0; r < 4; r++)
            AST[l * 136 + mt * 16 + quad * 4 + r] = f2bf(d[r]);
    }
    __syncthreads();
    {
        const int kt = wv >> 1, lt = wv & 1;
        floatx4 d = {0.f, 0.f, 0.f, 0.f};
        #pragma unroll
        for (int kb = 0; kb < 4; kb++) {
            short8 a = *(const short8*)&SsT[(kt * 16 + l15) * 136 + kb * 32 + quad * 8];
            short8 bb = *(const short8*)&AST[(lt * 16 + l15) * 136 + kb * 32 + quad * 8];
            d = __builtin_amdgcn_mfma_f32_16x16x32_bf16(a, bb, d, 0, 0, 0);
        }
        #pragma unroll
        for (int r = 0; r < 4; r++)
            Acs[(kt * 16 + quad * 4 + r) * 33 + lt * 16 + l15] = d[r];
    }
    __syncthreads();
    float symv[4];
    {
        int l = tid & 31, kb = tid >> 5;
        for (int r = 0; r < 4; r++) {
            int k = kb + 8 * r;
            symv[r] = 0.5f * (Acs[k * 33 + l] + Acs[l * 33 + k]) + ((k == l) ? 1.f : 0.f);
        }
    }
    __syncthreads();
    {
        int l = tid & 31, kb = tid >> 5;
        for (int r = 0; r < 4; r++) Acs[(kb + 8 * r) * 33 + l] = symv[r];
    }
    __syncthreads();
    if (tid < K_) {
        float s = 0.f;
        for (int l = 0; l < K_; l++) s += Acs[tid * 33 + l];
        dinv[tid] = rsqrtf(fmaxf(s, 1e-8f));
    }
    __syncthreads();
    us* Anw = An + (size_t)win * K_ * K_;
    for (int i = tid; i < K_ * K_; i += 256) {
        int k = i >> 5, l = i & 31;
        Anw[i] = f2bf(dinv[k] * Acs[k * 33 + l] * dinv[l]);
    }
}

// ---------------------------------------------------------------------------
// Kernel 5: fused 100-step GCLSTM scan (unchanged from round 7 — best
// measured at 379 µs; r5/r6/r7 variants all land 378-427, latency floor).
// ---------------------------------------------------------------------------
__global__ __launch_bounds__(1024) void scan_kernel(
    const us* __restrict__ An_bf,   // [bt][k][m]
    const us* __restrict__ XWxS,    // swizzled C-frag layout
    const us* __restrict__ WhT,     // [jj][h]
    float* __restrict__ Hsqm)
{
    __shared__ __align__(16) us HpHi[2][32 * 136];
    __shared__ __align__(16) us TmpT[512 * 40];     // [col jj][row m]

    const int tid  = threadIdx.x;
    const int lane = tid & 63;
    const int wv   = tid >> 6;          // 0..15
    const int b    = blockIdx.x;
    const int l15  = lane & 15, quad = lane >> 4;

    short8 Bw[2][4];
    #pragma unroll
    for (int i = 0; i < 2; i++) {
        const int nt = wv + 16 * i;
        #pragma unroll
        for (int kb = 0; kb < 4; kb++)
            Bw[i][kb] = *(const short8*)&WhT[(size_t)(nt * 16 + l15) * 128 + kb * 32 + quad * 8];
    }
    float Cs_[2][2], Hs_[2][2], H2_[2][2];
    #pragma unroll
    for (int kt = 0; kt < 2; kt++)
        #pragma unroll
        for (int i = 0; i < 2; i++) { Cs_[kt][i] = 0.f; Hs_[kt][i] = 0.f; H2_[kt][i] = 0.f; }

    for (int i = tid; i < 32 * 136; i += 1024) HpHi[0][i] = 0;

    const size_t bt0 = (size_t)b * WN_;
    const uint2* xp = (const uint2*)XWxS;
    uint2 xw[2][2];
    short8 anf[2];
    #pragma unroll
    for (int mtp = 0; mtp < 2; mtp++)
        #pragma unroll
        for (int i = 0; i < 2; i++)
            xw[mtp][i] = xp[(bt0 * 64 + mtp * 32 + wv + 16 * i) * 64 + lane];
    #pragma unroll
    for (int kt = 0; kt < 2; kt++)
        anf[kt] = *(const short8*)&An_bf[bt0 * 1024 + (kt * 16 + l15) * 32 + quad * 8];

    #pragma unroll 1
    for (int t = 0; t < WN_; t++) {
        const int buf = t & 1;
        ldsbar();
        floatx4 acc[2][2];
        #pragma unroll
        for (int mtp = 0; mtp < 2; mtp++)
            #pragma unroll
            for (int i = 0; i < 2; i++) {
                acc[mtp][i][0] = bf2f((us)(xw[mtp][i].x & 0xffff));
                acc[mtp][i][1] = bf2f((us)(xw[mtp][i].x >> 16));
                acc[mtp][i][2] = bf2f((us)(xw[mtp][i].y & 0xffff));
                acc[mtp][i][3] = bf2f((us)(xw[mtp][i].y >> 16));
            }
        {
            const int tn = (t + 1 < WN_) ? (t + 1) : (WN_ - 1);
            const size_t base = (bt0 + tn) * 64;
            #pragma unroll
            for (int mtp = 0; mtp < 2; mtp++)
                #pragma unroll
                for (int i = 0; i < 2; i++)
                    xw[mtp][i] = xp[(base + mtp * 32 + wv + 16 * i) * 64 + lane];
        }
        #pragma unroll
        for (int kb = 0; kb < 4; kb++) {
            const int ko = kb * 32 + quad * 8;
            short8 a0 = *(const short8*)&HpHi[buf][l15 * 136 + ko];
            short8 a1 = *(const short8*)&HpHi[buf][(16 + l15) * 136 + ko];
            #pragma unroll
            for (int i = 0; i < 2; i++) {
                acc[0][i] = __builtin_amdgcn_mfma_f32_16x16x32_bf16(a0, Bw[i][kb], acc[0][i], 0, 0, 0);
                acc[1][i] = __builtin_amdgcn_mfma_f32_16x16x32_bf16(a1, Bw[i][kb], acc[1][i], 0, 0, 0);
            }
        }
        #pragma unroll
        for (int i = 0; i < 2; i++) {
            const int col = (wv + 16 * i) * 16 + l15;
            #pragma unroll
            for (int mtp = 0; mtp < 2; mtp++) {
                uint2 pk;
                pk.x = (unsigned)f2bf(acc[mtp][i][0]) | ((unsigned)f2bf(acc[mtp][i][1]) << 16);
                pk.y = (unsigned)f2bf(acc[mtp][i][2]) | ((unsigned)f2bf(acc[mtp][i][3]) << 16);
                *(uint2*)&TmpT[col * 40 + mtp * 16 + quad * 4] = pk;
            }
        }
        __builtin_amdgcn_wave_barrier();
        floatx4 g[2][2];
        #pragma unroll
        for (int i = 0; i < 2; i++) {
            const int jt = wv + 16 * i;
            short8 aT = *(const short8*)&TmpT[(jt * 16 + l15) * 40 + quad * 8];
            floatx4 z = {0.f, 0.f, 0.f, 0.f};
            g[0][i] = __builtin_amdgcn_mfma_f32_16x16x32_bf16(aT, anf[0], z, 0, 0, 0);
            g[1][i] = __builtin_amdgcn_mfma_f32_16x16x32_bf16(aT, anf[1], z, 0, 0, 0);
        }
        {
            const int tn = (t + 1 < WN_) ? (t + 1) : (WN_ - 1);
            #pragma unroll
            for (int kt = 0; kt < 2; kt++)
                anf[kt] = *(const short8*)&An_bf[(bt0 + tn) * 1024 + (kt * 16 + l15) * 32 + quad * 8];
        }
        #pragma unroll
        for (int kt = 0; kt < 2; kt++)
            #pragma unroll
            for (int i = 0; i < 2; i++) {
                float gi = g[kt][i][0], gf = g[kt][i][1];
                float go = g[kt][i][2], gc = g[kt][i][3];
                float cn = sigf(gf) * Cs_[kt][i] + sigf(gi) * tanhfast(gc);
                float hn = sigf(go) * tanhfast(cn);
                Cs_[kt][i] = cn;
                H2_[kt][i] = Hs_[kt][i];
                Hs_[kt][i] = hn;
            }
        #pragma unroll
        for (int i = 0; i < 2; i++) {
            float s = Hs_[0][i] + Hs_[1][i];
            s += __shfl_xor(s, 1); s += __shfl_xor(s, 2);
            s += __shfl_xor(s, 4); s += __shfl_xor(s, 8);
            if (l15 == 0)
                Hsqm[(bt0 + t) * HID_ + (wv + 16 * i) * 4 + quad] = s * (1.f / 32.f);
        }
        if (t + 1 < WN_) {
            const float dninv = (t + 1 == 1) ? 0.5f : (1.f / 3.f);
            #pragma unroll
            for (int kt = 0; kt < 2; kt++)
                #pragma unroll
                for (int i = 0; i < 2; i++) {
                    float v = (2.f * Hs_[kt][i] + H2_[kt][i]) * dninv;
                    HpHi[buf ^ 1][(kt * 16 + l15) * 136 + (wv + 16 * i) * 4 + quad] = f2bf(v);
                }
        }
    }
}

// ---------------------------------------------------------------------------
// Kernel 6: temporal attention pooling + classifier — parallel reductions.
// ---------------------------------------------------------------------------
__global__ __launch_bounds__(128) void final_kernel(
    const float* __restrict__ Hsqm, const float* __restrict__ Hsm,
    const float* __restrict__ q_t, const float* __restrict__ q_s,
    const float* __restrict__ cls_w, const float* __restrict__ cls_b,
    float* __restrict__ out)
{
    __shared__ float red[128];
    __shared__ float wt[WN_];
    const int b = blockIdx.x, tid = threadIdx.x;
    // ||q_t||
    float v = q_t[tid];
    red[tid] = v * v;
    __syncthreads();
    for (int off = 64; off; off >>= 1) {
        if (tid < off) red[tid] += red[tid + off];
        __syncthreads();
    }
    const float qtn = sqrtf(red[0]) + 1e-8f;
    __syncthreads();
    // ||q_s||
    float v2 = (tid < D_) ? q_s[tid] : 0.f;
    red[tid] = v2 * v2;
    __syncthreads();
    for (int off = 64; off; off >>= 1) {
        if (tid < off) red[tid] += red[tid + off];
        __syncthreads();
    }
    const float qsn = sqrtf(red[0]) + 1e-8f;
    __syncthreads();
    // graph branch: scores
    float sc_t = -1e30f;
    if (tid < WN_) {
        float s = 0.f;
        const float* zr = Hsqm + ((size_t)b * WN_ + tid) * HID_;
        for (int h = 0; h < HID_; h++) s += zr[h] * q_t[h];
        sc_t = s / qtn;
    }
    red[tid] = sc_t;
    __syncthreads();
    for (int off = 64; off; off >>= 1) {
        if (tid < off) red[tid] = fmaxf(red[tid], red[tid + off]);
        __syncthreads();
    }
    const float mt_ = red[0];
    __syncthreads();
    float e_t = (tid < WN_) ? expf(sc_t - mt_) : 0.f;
    red[tid] = e_t;
    __syncthreads();
    for (int off = 64; off; off >>= 1) {
        if (tid < off) red[tid] += red[tid + off];
        __syncthreads();
    }
    const float sinv_t = 1.f / red[0];
    __syncthreads();
    if (tid < WN_) wt[tid] = e_t * sinv_t;
    __syncthreads();
    float part = 0.f;
    {
        float z = 0.f;
        for (int w = 0; w < WN_; w++)
            z += wt[w] * Hsqm[((size_t)b * WN_ + w) * HID_ + tid];
        part += z * cls_w[tid];
    }
    __syncthreads();
    // signal branch
    float sc_s = -1e30f;
    if (tid < WN_) {
        float s = 0.f;
        const float* zr = Hsm + ((size_t)b * WN_ + tid) * D_;
        for (int dd = 0; dd < D_; dd++) s += zr[dd] * q_s[dd];
        sc_s = s / qsn;
    }
    red[tid] = sc_s;
    __syncthreads();
    for (int off = 64; off; off >>= 1) {
        if (tid < off) red[tid] = fmaxf(red[tid], red[tid + off]);
        __syncthreads();
    }
    const float ms_ = red[0];
    __syncthreads();
    float e_s = (tid < WN_) ? expf(sc_s - ms_) : 0.f;
    red[tid] = e_s;
    __syncthreads();
    for (int off = 64; off; off >>= 1) {
        if (tid < off) red[tid] += red[tid + off];
        __syncthreads();
    }
    const float sinv_s = 1.f / red[0];
    __syncthreads();
    if (tid < WN_) wt[tid] = e_s * sinv_s;
    __syncthreads();
    if (tid < D_) {
        float z = 0.f;
        for (int w = 0; w < WN_; w++)
            z += wt[w] * Hsm[((size_t)b * WN_ + w) * D_ + tid];
        part += z * cls_w[HID_ + tid];
    }
    red[tid] = part;
    __syncthreads();
    for (int off = 64; off; off >>= 1) {
        if (tid < off) red[tid] += red[tid + off];
        __syncthreads();
    }
    if (tid == 0) out[b] = 1.f / (1.f + expf(-(red[0] + cls_b[0])));
}

// ---------------------------------------------------------------------------
extern "C" void kernel_launch(void* const* d_in, const int* in_sizes, int n_in,
                              void* d_out, int out_size, void* d_ws, size_t ws_size,
                              hipStream_t stream)
{
    (void)in_sizes; (void)n_in; (void)out_size; (void)ws_size;
    const float* x     = (const float*)d_in[0];
    const float* w1    = (const float*)d_in[1];
    const float* b1    = (const float*)d_in[2];
    const float* w2    = (const float*)d_in[3];
    const float* b2    = (const float*)d_in[4];
    const float* pw    = (const float*)d_in[5];
    const float* pb    = (const float*)d_in[6];
    const float* proto = (const float*)d_in[7];
    const float* Wx    = (const float*)d_in[8];
    const float* bx    = (const float*)d_in[9];
    const float* Wh    = (const float*)d_in[10];
    const float* bh    = (const float*)d_in[11];
    const float* q_t   = (const float*)d_in[12];
    const float* q_s   = (const float*)d_in[13];
    const float* clw   = (const float*)d_in[14];
    const float* clb   = (const float*)d_in[15];

    float* ws = (float*)d_ws;
    us*    Hs_bf  = (us*)d_ws;                      // [0, 6553600)
    us*    S_bf   = (us*)(ws + 6553600);            // [6553600, 9830400)
    us*    XWx    = (us*)(ws + 9830400);            // [9830400, 22937600)
    us*    An_bf  = (us*)(ws + 22937600);           // [22937600, 23756800)
    float* Hsm    = ws + 23756800;                  // [23756800, 23859200)
    float* Hsqm   = ws + 23859200;                  // [23859200, 24064000)
    us*    WhT    = (us*)(ws + 24064000);           // [24064000, 24096768)
    us*    WxT    = (us*)(ws + 24096768);           // [24096768, 24113152)
    float* bs2    = ws + 24129536;                  // [24129536, 24130048)

    prep_kernel<<<386, 256, 0, stream>>>(Wh, Wx, bx, bh, WhT, WxT, bs2);
    conv_kernel<<<B_ * WN_, 256, 0, stream>>>(x, w1, b1, w2, b2, pw, pb, Hs_bf);
    xcwx_kernel<<<B_ * WN_, 256, 0, stream>>>(Hs_bf, proto, WxT, bs2,
                                              S_bf, XWx, Hsm);
    corr_kernel<<<B_ * WN_, 256, 0, stream>>>(x, S_bf, An_bf);
    scan_kernel<<<B_, 1024, 0, stream>>>(An_bf, XWx, WhT, Hsqm);
    final_kernel<<<B_, 128, 0, stream>>>(Hsqm, Hsm, q_t, q_s, clw, clb,
                                         (float*)d_out);
}

// Round 9
// 703.295 us; speedup vs baseline: 4.5385x; 1.1463x over previous
//
#include <hip/hip_runtime.h>

#define B_   16
#define T_   3000
#define N_   128
#define WIN_ 30
#define WN_  100
#define D_   64
#define HID_ 128
#define K_   32
#define G4_  512   // 4*HID_

typedef unsigned short us;
typedef __attribute__((ext_vector_type(8))) short short8;
typedef __attribute__((ext_vector_type(4))) float floatx4;

__device__ __forceinline__ us f2bf(float f) {
    unsigned u = __float_as_uint(f);
    u += 0x7fffu + ((u >> 16) & 1u);
    return (us)(u >> 16);
}
__device__ __forceinline__ float bf2f(us h) {
    return __uint_as_float(((unsigned)h) << 16);
}
__device__ __forceinline__ float sigf(float x) { return 1.f / (1.f + __expf(-x)); }
__device__ __forceinline__ float tanhfast(float x) { return 2.f / (1.f + __expf(-2.f * x)) - 1.f; }
// Barrier WITHOUT vmcnt drain: LDS ordering only.  Safe when all global
// loads/stores crossing it are wave-private (consumed by issuing wave).
__device__ __forceinline__ void ldsbar() {
    __asm__ volatile("s_waitcnt lgkmcnt(0)\n\ts_barrier" ::: "memory");
}

// ---------------------------------------------------------------------------
// Kernel 1: SignalRep conv.  Transposed conv2 C-layout (rows = t, cols = co):
// mean-over-t is now in-lane reg sums + 2 swizzles per (seq,cot) instead of
// 16; conv1 writes pair-packed b32 (15 writes vs 30 u16).  Wave-private h1,
// zero per-group block barriers.  conv2 single-pass bf16, proj 3-pass hi/lo.
// ---------------------------------------------------------------------------
__global__ __launch_bounds__(256) void conv_kernel(
    const float* __restrict__ x, const float* __restrict__ w1,
    const float* __restrict__ b1, const float* __restrict__ w2,
    const float* __restrict__ b2, const float* __restrict__ pw,
    const float* __restrict__ pb, us* __restrict__ Hs)
{
    __shared__ __align__(16) float xs_all[30 * 128];   // [t][n]
    __shared__ __align__(16) us h1s[8 * 36 * 40];      // [s][t'][ci]
    __shared__ __align__(16) float Ms[128 * 40];       // [n][co] means (/30)
    __shared__ __align__(16) us PwT_hi[64 * 40];       // [d][co]
    __shared__ __align__(16) us PwT_lo[64 * 40];
    const int tid = threadIdx.x;
    const int win = blockIdx.x;
    const int b = win / WN_, w = win - b * WN_;
    const float* xb = x + ((size_t)b * T_ + (size_t)w * WIN_) * N_;
    const int lane = tid & 63, wv = tid >> 6;
    const int l15 = lane & 15, quad = lane >> 4;

    {
        const float4* xb4 = (const float4*)xb;
        float4* xs4 = (float4*)xs_all;
        for (int i = tid; i < 960; i += 256) xs4[i] = xb4[i];
    }
    for (int i = tid; i < 2048; i += 256) {
        int co = i >> 6, d = i & 63;
        float v = pw[i];
        us hi = f2bf(v);
        PwT_hi[d * 40 + co] = hi;
        PwT_lo[d * 40 + co] = f2bf(v - bf2f(hi));
    }
    for (int i = tid; i < 1920; i += 256) {            // zero h1 pad rows
        int s = i / 240, r = i % 240;
        int ti = r / 40, c = r % 40;
        int tp = (ti < 2) ? ti : (30 + ti);
        h1s[(s * 36 + tp) * 40 + c] = 0;
    }
    // w2 B-fragments: Bfrag[co=l15][K=ci=quad*8+j], per dk, per cot (40 VGPR)
    short8 whf[2][5];
    #pragma unroll
    for (int cot = 0; cot < 2; cot++)
        #pragma unroll
        for (int dk = 0; dk < 5; dk++)
            #pragma unroll
            for (int j = 0; j < 8; j++)
                whf[cot][dk][j] = (short)f2bf(w2[(cot * 16 + l15) * 160 + (quad * 8 + j) * 5 + dk]);
    const float b2c0 = b2[l15], b2c1 = b2[16 + l15];   // bias per col (co)
    // conv1 mapping: thread = (sloc, ci-pair ci2, t-half th)
    const int ci2 = lane & 15, th = (lane >> 4) & 1, sloc = lane >> 5;
    float w1ra[5], w1rb[5];
    #pragma unroll
    for (int k = 0; k < 5; k++) {
        w1ra[k] = w1[(2 * ci2) * 5 + k];
        w1rb[k] = w1[(2 * ci2 + 1) * 5 + k];
    }
    const float b1a = b1[2 * ci2], b1b = b1[2 * ci2 + 1];
    float pbv[4];
    #pragma unroll
    for (int nt = 0; nt < 4; nt++) pbv[nt] = pb[nt * 16 + l15];
    ldsbar();

    for (int g = 0; g < 16; g++) {
        const int n1 = g * 8 + wv * 2 + sloc;
        // conv1: 15 t, 2 ci per thread, packed b32 writes
        {
            float xr[19];
            #pragma unroll
            for (int u = 0; u < 19; u++) {
                int p = th * 15 - 2 + u;
                xr[u] = ((unsigned)p < 30u) ? xs_all[p * 128 + n1] : 0.f;
            }
            const int rbase = (wv * 2 + sloc) * 36 + 2 + th * 15;
            #pragma unroll
            for (int tt = 0; tt < 15; tt++) {
                float aa = b1a, ab = b1b;
                #pragma unroll
                for (int k = 0; k < 5; k++) {
                    aa += xr[tt + k] * w1ra[k];
                    ab += xr[tt + k] * w1rb[k];
                }
                unsigned pk = (unsigned)f2bf(fmaxf(aa, 0.f))
                            | ((unsigned)f2bf(fmaxf(ab, 0.f)) << 16);
                *(unsigned*)&h1s[(rbase + tt) * 40 + 2 * ci2] = pk;
            }
        }
        __builtin_amdgcn_wave_barrier();
        // conv2 transposed: out[t][co]; A = h1 rows (shifted by dk), B = whf
        #pragma unroll
        for (int s2 = 0; s2 < 2; s2++) {
            const int sl = wv * 2 + s2;
            const int nn = g * 8 + sl;
            floatx4 c00 = {b2c0, b2c0, b2c0, b2c0};   // t 0..15,  cot0
            floatx4 c01 = {b2c1, b2c1, b2c1, b2c1};   // t 0..15,  cot1
            floatx4 c10 = {b2c0, b2c0, b2c0, b2c0};   // t 16..31, cot0
            floatx4 c11 = {b2c1, b2c1, b2c1, b2c1};   // t 16..31, cot1
            #pragma unroll
            for (int dk = 0; dk < 5; dk++) {
                short8 a0 = *(const short8*)&h1s[(sl * 36 + l15 + dk) * 40 + quad * 8];
                short8 a1 = *(const short8*)&h1s[(sl * 36 + 16 + l15 + dk) * 40 + quad * 8];
                c00 = __builtin_amdgcn_mfma_f32_16x16x32_bf16(a0, whf[0][dk], c00, 0, 0, 0);
                c01 = __builtin_amdgcn_mfma_f32_16x16x32_bf16(a0, whf[1][dk], c01, 0, 0, 0);
                c10 = __builtin_amdgcn_mfma_f32_16x16x32_bf16(a1, whf[0][dk], c10, 0, 0, 0);
                c11 = __builtin_amdgcn_mfma_f32_16x16x32_bf16(a1, whf[1][dk], c11, 0, 0, 0);
            }
            // relu + mean over t: rows t = quad*4+r (mt0) and 16+quad*4+r (mt1,
            // valid iff quad*4+r < 14).  In-lane sums + cross-quad xor.
            float s0 = 0.f, s1 = 0.f;
            #pragma unroll
            for (int r = 0; r < 4; r++) {
                s0 += fmaxf(c00[r], 0.f);
                s1 += fmaxf(c01[r], 0.f);
                float m0 = (quad * 4 + r < 14) ? fmaxf(c10[r], 0.f) : 0.f;
                float m1 = (quad * 4 + r < 14) ? fmaxf(c11[r], 0.f) : 0.f;
                s0 += m0; s1 += m1;
            }
            s0 += __shfl_xor(s0, 16); s0 += __shfl_xor(s0, 32);
            s1 += __shfl_xor(s1, 16); s1 += __shfl_xor(s1, 32);
            if (quad == 0) {
                Ms[nn * 40 + l15]      = s0 * (1.f / 30.f);
                Ms[nn * 40 + 16 + l15] = s1 * (1.f / 30.f);
            }
        }
        __builtin_amdgcn_wave_barrier();
    }
    ldsbar();
    // proj GEMM: Hs[n][d] = Ms @ pw + pb (3-pass hi/lo, once per block)
    short8 Ah[2], Al[2];
    #pragma unroll
    for (int i = 0; i < 2; i++) {
        const int mt = wv * 2 + i;
        float4 v0 = *(const float4*)&Ms[(mt * 16 + l15) * 40 + quad * 8];
        float4 v1 = *(const float4*)&Ms[(mt * 16 + l15) * 40 + quad * 8 + 4];
        float vv[8] = {v0.x, v0.y, v0.z, v0.w, v1.x, v1.y, v1.z, v1.w};
        #pragma unroll
        for (int j = 0; j < 8; j++) {
            us hi = f2bf(vv[j]);
            Ah[i][j] = (short)hi;
            Al[i][j] = (short)f2bf(vv[j] - bf2f(hi));
        }
    }
    us* hp = Hs + (size_t)win * 8192;
    #pragma unroll
    for (int id = 0; id < 8; id++) {
        const int i = id >> 2, nt = id & 3;
        short8 Bh = *(const short8*)&PwT_hi[(nt * 16 + l15) * 40 + quad * 8];
        short8 Bl = *(const short8*)&PwT_lo[(nt * 16 + l15) * 40 + quad * 8];
        floatx4 a = {pbv[nt], pbv[nt], pbv[nt], pbv[nt]};
        a = __builtin_amdgcn_mfma_f32_16x16x32_bf16(Ah[i], Bh, a, 0, 0, 0);
        a = __builtin_amdgcn_mfma_f32_16x16x32_bf16(Al[i], Bh, a, 0, 0, 0);
        a = __builtin_amdgcn_mfma_f32_16x16x32_bf16(Ah[i], Bl, a, 0, 0, 0);
        const int mt = wv * 2 + i;
        #pragma unroll
        for (int r = 0; r < 4; r++)
            hp[(mt * 16 + quad * 4 + r) * 64 + nt * 16 + l15] = f2bf(a[r]);
    }
}

// ---------------------------------------------------------------------------
// Kernel 2: prep — WhT[jj][h] bf16, WxT[jj][d] bf16, bs2[jj]=bx+bh.
// ---------------------------------------------------------------------------
__global__ __launch_bounds__(256) void prep_kernel(
    const float* __restrict__ Wh, const float* __restrict__ Wx,
    const float* __restrict__ bx, const float* __restrict__ bh,
    us* __restrict__ WhT, us* __restrict__ WxT, float* __restrict__ bs2)
{
    int i = blockIdx.x * 256 + threadIdx.x;
    if (i < 65536) {
        int jj = i >> 7, h = i & 127;
        int jg = (jj & 3) * HID_ + (jj >> 2);
        WhT[i] = f2bf(Wh[h * G4_ + jg]);
    } else if (i < 98304) {
        int j = i - 65536;
        int jj = j >> 6;
        int d = j & 63;
        int jg = (jj & 3) * HID_ + (jj >> 2);
        WxT[j] = f2bf(Wx[d * G4_ + jg]);
    } else if (i < 98816) {
        int jj = i - 98304;
        int jg = (jj & 3) * HID_ + (jj >> 2);
        bs2[jj] = bx[jg] + bh[jg];
    }
}

// ---------------------------------------------------------------------------
// Kernel 3: fused per-window — softmax S, Hsm, Xc = S^T@Hs, XWx = Xc@Wx+bias.
// (unchanged from round 8 — verified)
// ---------------------------------------------------------------------------
__global__ __launch_bounds__(256) void xcwx_kernel(
    const us* __restrict__ Hs, const float* __restrict__ proto,
    const us* __restrict__ WxT, const float* __restrict__ bs2,
    us* __restrict__ S_out, us* __restrict__ XWx, float* __restrict__ Hsm)
{
    __shared__ __align__(16) us Hnd[128 * 72];
    __shared__ __align__(16) us HsT[64 * 136];
    __shared__ __align__(16) us PT_hi[32 * 72];
    __shared__ __align__(16) us SsT_hi[32 * 136];
    __shared__ __align__(16) us XcA_hi[32 * 72];
    __shared__ float bias[512];
    const int tid = threadIdx.x;
    const int win = blockIdx.x;
    const int lane = tid & 63, wv = tid >> 6;
    const int l15 = lane & 15, quad = lane >> 4;

    {
        const uint2* hp = (const uint2*)(Hs + (size_t)win * 8192);
        #pragma unroll
        for (int it = 0; it < 8; it++) {
            int idx4 = tid + 256 * it;
            int n = idx4 >> 4, dpos = (idx4 & 15) * 4;
            uint2 v = hp[idx4];
            *(uint2*)&Hnd[n * 72 + dpos] = v;
            us s0 = (us)(v.x & 0xffff), s1 = (us)(v.x >> 16);
            us s2 = (us)(v.y & 0xffff), s3 = (us)(v.y >> 16);
            HsT[(dpos + 0) * 136 + n] = s0;
            HsT[(dpos + 1) * 136 + n] = s1;
            HsT[(dpos + 2) * 136 + n] = s2;
            HsT[(dpos + 3) * 136 + n] = s3;
        }
        for (int i = tid; i < 2048; i += 256) {
            int k = i >> 6, d = i & 63;
            PT_hi[k * 72 + d] = f2bf(proto[i]);
        }
        for (int i = tid; i < 512; i += 256) bias[i] = bs2[i];
    }
    __syncthreads();
    floatx4 lg[2][2];
    #pragma unroll
    for (int p = 0; p < 2; p++) {
        const int mt = wv * 2 + p;
        #pragma unroll
        for (int kt = 0; kt < 2; kt++) {
            floatx4 a = {0.f, 0.f, 0.f, 0.f};
            #pragma unroll
            for (int kb = 0; kb < 2; kb++) {
                short8 af  = *(const short8*)&Hnd[(mt * 16 + l15) * 72 + kb * 32 + quad * 8];
                short8 bhf = *(const short8*)&PT_hi[(kt * 16 + l15) * 72 + kb * 32 + quad * 8];
                a = __builtin_amdgcn_mfma_f32_16x16x32_bf16(af, bhf, a, 0, 0, 0);
            }
            lg[p][kt] = a;
        }
    }
    #pragma unroll
    for (int p = 0; p < 2; p++) {
        #pragma unroll
        for (int r = 0; r < 4; r++) {
            float v0 = lg[p][0][r], v1 = lg[p][1][r];
            float m = fmaxf(v0, v1);
            #pragma unroll
            for (int off = 8; off; off >>= 1) m = fmaxf(m, __shfl_xor(m, off));
            float e0 = expf(v0 - m), e1 = expf(v1 - m);
            float s = e0 + e1;
            #pragma unroll
            for (int off = 8; off; off >>= 1) s += __shfl_xor(s, off);
            float inv = 1.f / s;
            e0 *= inv; e1 *= inv;
            const int n = (wv * 2 + p) * 16 + quad * 4 + r;
            us h0 = f2bf(e0), h1 = f2bf(e1);
            SsT_hi[l15 * 136 + n]        = h0;
            SsT_hi[(16 + l15) * 136 + n] = h1;
            S_out[(size_t)win * 4096 + n * 32 + l15]      = h0;
            S_out[(size_t)win * 4096 + n * 32 + 16 + l15] = h1;
        }
    }
    __syncthreads();
    {
        const int d = tid >> 2, seg = tid & 3;
        float acc = 0.f;
        const unsigned* hp2 = (const unsigned*)&HsT[d * 136 + seg * 32];
        #pragma unroll
        for (int q = 0; q < 16; q++) {
            unsigned v = hp2[q];
            acc += bf2f((us)(v & 0xffff)) + bf2f((us)(v >> 16));
        }
        acc += __shfl_xor(acc, 1);
        acc += __shfl_xor(acc, 2);
        if (seg == 0) Hsm[(size_t)win * 64 + d] = acc * (1.f / 128.f);
    }
    #pragma unroll
    for (int p = 0; p < 2; p++) {
        const int id = wv * 2 + p, mt = id >> 2, nt = id & 3;
        floatx4 a = {0.f, 0.f, 0.f, 0.f};
        #pragma unroll
        for (int kb = 0; kb < 4; kb++) {
            short8 ah = *(const short8*)&SsT_hi[(mt * 16 + l15) * 136 + kb * 32 + quad * 8];
            short8 bf_ = *(const short8*)&HsT[(nt * 16 + l15) * 136 + kb * 32 + quad * 8];
            a = __builtin_amdgcn_mfma_f32_16x16x32_bf16(ah, bf_, a, 0, 0, 0);
        }
        #pragma unroll
        for (int r = 0; r < 4; r++) {
            const int k = mt * 16 + quad * 4 + r, d = nt * 16 + l15;
            XcA_hi[k * 72 + d] = f2bf(a[r]);
        }
    }
    __syncthreads();
    short8 Ah[2][2];
    #pragma unroll
    for (int mt = 0; mt < 2; mt++)
        #pragma unroll
        for (int kb = 0; kb < 2; kb++)
            Ah[mt][kb] = *(const short8*)&XcA_hi[(mt * 16 + l15) * 72 + kb * 32 + quad * 8];
    #pragma unroll 1
    for (int i = 0; i < 8; i++) {
        const int nt = wv + 4 * i;
        const float bv = bias[nt * 16 + l15];
        floatx4 acc[2];
        acc[0] = (floatx4){bv, bv, bv, bv};
        acc[1] = (floatx4){bv, bv, bv, bv};
        #pragma unroll
        for (int kb = 0; kb < 2; kb++) {
            short8 wh8 = *(const short8*)&WxT[(size_t)(nt * 16 + l15) * 64 + kb * 32 + quad * 8];
            #pragma unroll
            for (int mt = 0; mt < 2; mt++)
                acc[mt] = __builtin_amdgcn_mfma_f32_16x16x32_bf16(Ah[mt][kb], wh8, acc[mt], 0, 0, 0);
        }
        #pragma unroll
        for (int mt = 0; mt < 2; mt++) {
            uint2 pk;
            pk.x = (unsigned)f2bf(acc[mt][0]) | ((unsigned)f2bf(acc[mt][1]) << 16);
            pk.y = (unsigned)f2bf(acc[mt][2]) | ((unsigned)f2bf(acc[mt][3]) << 16);
            ((uint2*)XWx)[((size_t)win * 64 + mt * 32 + nt) * 64 + lane] = pk;
        }
    }
}

// ---------------------------------------------------------------------------
// Kernel 4: corr -> AS -> Ac -> normalize -> An.  XA aliased onto xs (staged
// through registers, +1 barrier): LDS 82.7 -> 72.4 KB => 2 blocks/CU.
// ---------------------------------------------------------------------------
__global__ __launch_bounds__(256) void corr_kernel(
    const float* __restrict__ x, const us* __restrict__ S_bf,
    us* __restrict__ An)
{
    __shared__ __align__(16) float xs[30 * 128];    // aliased by XA below
    __shared__ __align__(16) us SsT[32 * 136];
    __shared__ __align__(16) us CB[128 * 136];
    __shared__ __align__(16) us AST[32 * 136];
    __shared__ float Acs[32 * 33];
    __shared__ float sinv[128];
    __shared__ float dinv[32];
    us* XA = (us*)xs;                               // [128][40]
    const int tid = threadIdx.x;
    const int win = blockIdx.x;
    const int b = win / WN_, w = win - b * WN_;
    const float* xb = x + ((size_t)b * T_ + (size_t)w * WIN_) * N_;
    const int lane = tid & 63, wv = tid >> 6;
    const int l15 = lane & 15, quad = lane >> 4;
    const float inv29 = 1.f / (WIN_ - 1 + 1e-8f);

    for (int i = tid; i < 3840; i += 256) xs[i] = xb[i];
    for (int i = tid; i < 4096; i += 256) {
        int n = i >> 5, k = i & 31;
        SsT[k * 136 + n] = S_bf[(size_t)win * 4096 + i];
    }
    __syncthreads();
    float xr[30];
    if (tid < 128) {
        const int n = tid;
        float mean = 0.f;
        #pragma unroll
        for (int l = 0; l < 30; l++) { xr[l] = xs[l * 128 + n]; mean += xr[l]; }
        mean *= (1.f / 30.f);
        float var = 0.f;
        #pragma unroll
        for (int l = 0; l < 30; l++) {
            float v = xr[l] - mean;
            var += v * v;
            xr[l] = v;
        }
        var *= inv29;
        sinv[tid] = rsqrtf(fmaxf(var, 1e-8f));
    }
    __syncthreads();                                // all xs reads complete
    if (tid < 128) {
        #pragma unroll
        for (int l = 0; l < 30; l++) XA[tid * 40 + l] = f2bf(xr[l]);
        XA[tid * 40 + 30] = 0; XA[tid * 40 + 31] = 0;
    }
    __syncthreads();
    #pragma unroll 1
    for (int q = 0; q < 16; q++) {
        const int id = wv * 16 + q, mt = id >> 3, nt = id & 7;
        short8 a = *(const short8*)&XA[(mt * 16 + l15) * 40 + quad * 8];
        short8 bb = *(const short8*)&XA[(nt * 16 + l15) * 40 + quad * 8];
        floatx4 d = {0.f, 0.f, 0.f, 0.f};
        d = __builtin_amdgcn_mfma_f32_16x16x32_bf16(a, bb, d, 0, 0, 0);
        const int m = nt * 16 + l15;
        const float sm = sinv[m];
        #pragma unroll
        for (int r = 0; r < 4; r++) {
            const int n = mt * 16 + quad * 4 + r;
            float v = d[r] * inv29 * sinv[n] * sm;
            if (n == m) v = 1.f;
            CB[n * 136 + m] = f2bf(v);
        }
    }
    __syncthreads();
    #pragma unroll 1
    for (int q = 0; q < 4; q++) {
        const int id = wv * 4 + q, mt = id >> 1, lt = id & 1;
        floatx4 d = {0.f, 0.f, 0.f, 0.f};
        #pragma unroll
        for (int kb = 0; kb < 4; kb++) {
            short8 a = *(const short8*)&CB[(mt * 16 + l15) * 136 + kb * 32 + quad * 8];
            short8 bb = *(const short8*)&SsT[(lt * 16 + l15) * 136 + kb * 32 + quad * 8];
            d = __builtin_amdgcn_mfma_f32_16x16x32_bf16(a, bb, d, 0, 0, 0);
        }
        const int l = lt * 16 + l15;
        #pragma unroll
        for (int r = 0; r < 4; r++)
            AST[l * 136 + mt * 16 + quad * 4 + r] = f2bf(d[r]);
    }
    __syncthreads();
    {
        const int kt = wv >> 1, lt = wv & 1;
        floatx4 d = {0.f, 0.f, 0.f, 0.f};
        #pragma unroll
        for (int kb = 0; kb < 4; kb++) {
            short8 a = *(const short8*)&SsT[(kt * 16 + l15) * 136 + kb * 32 + quad * 8];
            short8 bb = *(const short8*)&AST[(lt * 16 + l15) * 136 + kb * 32 + quad * 8];
            d = __builtin_amdgcn_mfma_f32_16x16x32_bf16(a, bb, d, 0, 0, 0);
        }
        #pragma unroll
        for (int r = 0; r < 4; r++)
            Acs[(kt * 16 + quad * 4 + r) * 33 + lt * 16 + l15] = d[r];
    }
    __syncthreads();
    float symv[4];
    {
        int l = tid & 31, kb = tid >> 5;
        for (int r = 0; r < 4; r++) {
            int k = kb + 8 * r;
            symv[r] = 0.5f * (Acs[k * 33 + l] + Acs[l * 33 + k]) + ((k == l) ? 1.f : 0.f);
        }
    }
    __syncthreads();
    {
        int l = tid & 31, kb = tid >> 5;
        for (int r = 0; r < 4; r++) Acs[(kb + 8 * r) * 33 + l] = symv[r];
    }
    __syncthreads();
    if (tid < K_) {
        float s = 0.f;
        for (int l = 0; l < K_; l++) s += Acs[tid * 33 + l];
        dinv[tid] = rsqrtf(fmaxf(s, 1e-8f));
    }
    __syncthreads();
    us* Anw = An + (size_t)win * K_ * K_;
    for (int i = tid; i < K_ * K_; i += 256) {
        int k = i >> 5, l = i & 31;
        Anw[i] = f2bf(dinv[k] * Acs[k * 33 + l] * dinv[l]);
    }
}

// ---------------------------------------------------------------------------
// Kernel 5: fused 100-step GCLSTM scan (unchanged — r5/r6/r7/r8 variants all
// land 378-427 µs; VALU/LDS throughput-bound on its 16 active CUs).
// ---------------------------------------------------------------------------
__global__ __launch_bounds__(1024) void scan_kernel(
    const us* __restrict__ An_bf,   // [bt][k][m]
    const us* __restrict__ XWxS,    // swizzled C-frag layout
    const us* __restrict__ WhT,     // [jj][h]
    float* __restrict__ Hsqm)
{
    __shared__ __align__(16) us HpHi[2][32 * 136];
    __shared__ __align__(16) us TmpT[512 * 40];     // [col jj][row m]

    const int tid  = threadIdx.x;
    const int lane = tid & 63;
    const int wv   = tid >> 6;          // 0..15
    const int b    = blockIdx.x;
    const int l15  = lane & 15, quad = lane >> 4;

    short8 Bw[2][4];
    #pragma unroll
    for (int i = 0; i < 2; i++) {
        const int nt = wv + 16 * i;
        #pragma unroll
        for (int kb = 0; kb < 4; kb++)
            Bw[i][kb] = *(const short8*)&WhT[(size_t)(nt * 16 + l15) * 128 + kb * 32 + quad * 8];
    }
    float Cs_[2][2], Hs_[2][2], H2_[2][2];
    #pragma unroll
    for (int kt = 0; kt < 2; kt++)
        #pragma unroll
        for (int i = 0; i < 2; i++) { Cs_[kt][i] = 0.f; Hs_[kt][i] = 0.f; H2_[kt][i] = 0.f; }

    for (int i = tid; i < 32 * 136; i += 1024) HpHi[0][i] = 0;

    const size_t bt0 = (size_t)b * WN_;
    const uint2* xp = (const uint2*)XWxS;
    uint2 xw[2][2];
    short8 anf[2];
    #pragma unroll
    for (int mtp = 0; mtp < 2; mtp++)
        #pragma unroll
        for (int i = 0; i < 2; i++)
            xw[mtp][i] = xp[(bt0 * 64 + mtp * 32 + wv + 16 * i) * 64 + lane];
    #pragma unroll
    for (int kt = 0; kt < 2; kt++)
        anf[kt] = *(const short8*)&An_bf[bt0 * 1024 + (kt * 16 + l15) * 32 + quad * 8];

    #pragma unroll 1
    for (int t = 0; t < WN_; t++) {
        const int buf = t & 1;
        ldsbar();
        floatx4 acc[2][2];
        #pragma unroll
        for (int mtp = 0; mtp < 2; mtp++)
            #pragma unroll
            for (int i = 0; i < 2; i++) {
                acc[mtp][i][0] = bf2f((us)(xw[mtp][i].x & 0xffff));
                acc[mtp][i][1] = bf2f((us)(xw[mtp][i].x >> 16));
                acc[mtp][i][2] = bf2f((us)(xw[mtp][i].y & 0xffff));
                acc[mtp][i][3] = bf2f((us)(xw[mtp][i].y >> 16));
            }
        {
            const int tn = (t + 1 < WN_) ? (t + 1) : (WN_ - 1);
            const size_t base = (bt0 + tn) * 64;
            #pragma unroll
            for (int mtp = 0; mtp < 2; mtp++)
                #pragma unroll
                for (int i = 0; i < 2; i++)
                    xw[mtp][i] = xp[(base + mtp * 32 + wv + 16 * i) * 64 + lane];
        }
        #pragma unroll
        for (int kb = 0; kb < 4; kb++) {
            const int ko = kb * 32 + quad * 8;
            short8 a0 = *(const short8*)&HpHi[buf][l15 * 136 + ko];
            short8 a1 = *(const short8*)&HpHi[buf][(16 + l15) * 136 + ko];
            #pragma unroll
            for (int i = 0; i < 2; i++) {
                acc[0][i] = __builtin_amdgcn_mfma_f32_16x16x32_bf16(a0, Bw[i][kb], acc[0][i], 0, 0, 0);
                acc[1][i] = __builtin_amdgcn_mfma_f32_16x16x32_bf16(a1, Bw[i][kb], acc[1][i], 0, 0, 0);
            }
        }
        #pragma unroll
        for (int i = 0; i < 2; i++) {
            const int col = (wv + 16 * i) * 16 + l15;
            #pragma unroll
            for (int mtp = 0; mtp < 2; mtp++) {
                uint2 pk;
                pk.x = (unsigned)f2bf(acc[mtp][i][0]) | ((unsigned)f2bf(acc[mtp][i][1]) << 16);
                pk.y = (unsigned)f2bf(acc[mtp][i][2]) | ((unsigned)f2bf(acc[mtp][i][3]) << 16);
                *(uint2*)&TmpT[col * 40 + mtp * 16 + quad * 4] = pk;
            }
        }
        __builtin_amdgcn_wave_barrier();
        floatx4 g[2][2];
        #pragma unroll
        for (int i = 0; i < 2; i++) {
            const int jt = wv + 16 * i;
            short8 aT = *(const short8*)&TmpT[(jt * 16 + l15) * 40 + quad * 8];
            floatx4 z = {0.f, 0.f, 0.f, 0.f};
            g[0][i] = __builtin_amdgcn_mfma_f32_16x16x32_bf16(aT, anf[0], z, 0, 0, 0);
            g[1][i] = __builtin_amdgcn_mfma_f32_16x16x32_bf16(aT, anf[1], z, 0, 0, 0);
        }
        {
            const int tn = (t + 1 < WN_) ? (t + 1) : (WN_ - 1);
            #pragma unroll
            for (int kt = 0; kt < 2; kt++)
                anf[kt] = *(const short8*)&An_bf[(bt0 + tn) * 1024 + (kt * 16 + l15) * 32 + quad * 8];
        }
        #pragma unroll
        for (int kt = 0; kt < 2; kt++)
            #pragma unroll
            for (int i = 0; i < 2; i++) {
                float gi = g[kt][i][0], gf = g[kt][i][1];
                float go = g[kt][i][2], gc = g[kt][i][3];
                float cn = sigf(gf) * Cs_[kt][i] + sigf(gi) * tanhfast(gc);
                float hn = sigf(go) * tanhfast(cn);
                Cs_[kt][i] = cn;
                H2_[kt][i] = Hs_[kt][i];
                Hs_[kt][i] = hn;
            }
        #pragma unroll
        for (int i = 0; i < 2; i++) {
            float s = Hs_[0][i] + Hs_[1][i];
            s += __shfl_xor(s, 1); s += __shfl_xor(s, 2);
            s += __shfl_xor(s, 4); s += __shfl_xor(s, 8);
            if (l15 == 0)
                Hsqm[(bt0 + t) * HID_ + (wv + 16 * i) * 4 + quad] = s * (1.f / 32.f);
        }
        if (t + 1 < WN_) {
            const float dninv = (t + 1 == 1) ? 0.5f : (1.f / 3.f);
            #pragma unroll
            for (int kt = 0; kt < 2; kt++)
                #pragma unroll
                for (int i = 0; i < 2; i++) {
                    float v = (2.f * Hs_[kt][i] + H2_[kt][i]) * dninv;
                    HpHi[buf ^ 1][(kt * 16 + l15) * 136 + (wv + 16 * i) * 4 + quad] = f2bf(v);
                }
        }
    }
}

// ---------------------------------------------------------------------------
// Kernel 6: temporal attention pooling + classifier (unchanged).
// ---------------------------------------------------------------------------
__global__ __launch_bounds__(128) void final_kernel(
    const float* __restrict__ Hsqm, const float* __restrict__ Hsm,
    const float* __restrict__ q_t, const float* __restrict__ q_s,
    const float* __restrict__ cls_w, const float* __restrict__ cls_b,
    float* __restrict__ out)
{
    __shared__ float red[128];
    __shared__ float wt[WN_];
    const int b = blockIdx.x, tid = threadIdx.x;
    float v = q_t[tid];
    red[tid] = v * v;
    __syncthreads();
    for (int off = 64; off; off >>= 1) {
        if (tid < off) red[tid] += red[tid + off];
        __syncthreads();
    }
    const float qtn = sqrtf(red[0]) + 1e-8f;
    __syncthreads();
    float v2 = (tid < D_) ? q_s[tid] : 0.f;
    red[tid] = v2 * v2;
    __syncthreads();
    for (int off = 64; off; off >>= 1) {
        if (tid < off) red[tid] += red[tid + off];
        __syncthreads();
    }
    const float qsn = sqrtf(red[0]) + 1e-8f;
    __syncthreads();
    float sc_t = -1e30f;
    if (tid < WN_) {
        float s = 0.f;
        const float* zr = Hsqm + ((size_t)b * WN_ + tid) * HID_;
        for (int h = 0; h < HID_; h++) s += zr[h] * q_t[h];
        sc_t = s / qtn;
    }
    red[tid] = sc_t;
    __syncthreads();
    for (int off = 64; off; off >>= 1) {
        if (tid < off) red[tid] = fmaxf(red[tid], red[tid + off]);
        __syncthreads();
    }
    const float mt_ = red[0];
    __syncthreads();
    float e_t = (tid < WN_) ? expf(sc_t - mt_) : 0.f;
    red[tid] = e_t;
    __syncthreads();
    for (int off = 64; off; off >>= 1) {
        if (tid < off) red[tid] += red[tid + off];
        __syncthreads();
    }
    const float sinv_t = 1.f / red[0];
    __syncthreads();
    if (tid < WN_) wt[tid] = e_t * sinv_t;
    __syncthreads();
    float part = 0.f;
    {
        float z = 0.f;
        for (int w = 0; w < WN_; w++)
            z += wt[w] * Hsqm[((size_t)b * WN_ + w) * HID_ + tid];
        part += z * cls_w[tid];
    }
    __syncthreads();
    float sc_s = -1e30f;
    if (tid < WN_) {
        float s = 0.f;
        const float* zr = Hsm + ((size_t)b * WN_ + tid) * D_;
        for (int dd = 0; dd < D_; dd++) s += zr[dd] * q_s[dd];
        sc_s = s / qsn;
    }
    red[tid] = sc_s;
    __syncthreads();
    for (int off = 64; off; off >>= 1) {
        if (tid < off) red[tid] = fmaxf(red[tid], red[tid + off]);
        __syncthreads();
    }
    const float ms_ = red[0];
    __syncthreads();
    float e_s = (tid < WN_) ? expf(sc_s - ms_) : 0.f;
    red[tid] = e_s;
    __syncthreads();
    for (int off = 64; off; off >>= 1) {
        if (tid < off) red[tid] += red[tid + off];
        __syncthreads();
    }
    const float sinv_s = 1.f / red[0];
    __syncthreads();
    if (tid < WN_) wt[tid] = e_s * sinv_s;
    __syncthreads();
    if (tid < D_) {
        float z = 0.f;
        for (int w = 0; w < WN_; w++)
            z += wt[w] * Hsm[((size_t)b * WN_ + w) * D_ + tid];
        part += z * cls_w[HID_ + tid];
    }
    red[tid] = part;
    __syncthreads();
    for (int off = 64; off; off >>= 1) {
        if (tid < off) red[tid] += red[tid + off];
        __syncthreads();
    }
    if (tid == 0) out[b] = 1.f / (1.f + expf(-(red[0] + cls_b[0])));
}

// ---------------------------------------------------------------------------
extern "C" void kernel_launch(void* const* d_in, const int* in_sizes, int n_in,
                              void* d_out, int out_size, void* d_ws, size_t ws_size,
                              hipStream_t stream)
{
    (void)in_sizes; (void)n_in; (void)out_size; (void)ws_size;
    const float* x     = (const float*)d_in[0];
    const float* w1    = (const float*)d_in[1];
    const float* b1    = (const float*)d_in[2];
    const float* w2    = (const float*)d_in[3];
    const float* b2    = (const float*)d_in[4];
    const float* pw    = (const float*)d_in[5];
    const float* pb    = (const float*)d_in[6];
    const float* proto = (const float*)d_in[7];
    const float* Wx    = (const float*)d_in[8];
    const float* bx    = (const float*)d_in[9];
    const float* Wh    = (const float*)d_in[10];
    const float* bh    = (const float*)d_in[11];
    const float* q_t   = (const float*)d_in[12];
    const float* q_s   = (const float*)d_in[13];
    const float* clw   = (const float*)d_in[14];
    const float* clb   = (const float*)d_in[15];

    float* ws = (float*)d_ws;
    us*    Hs_bf  = (us*)d_ws;                      // [0, 6553600)
    us*    S_bf   = (us*)(ws + 6553600);            // [6553600, 9830400)
    us*    XWx    = (us*)(ws + 9830400);            // [9830400, 22937600)
    us*    An_bf  = (us*)(ws + 22937600);           // [22937600, 23756800)
    float* Hsm    = ws + 23756800;                  // [23756800, 23859200)
    float* Hsqm   = ws + 23859200;                  // [23859200, 24064000)
    us*    WhT    = (us*)(ws + 24064000);           // [24064000, 24096768)
    us*    WxT    = (us*)(ws + 24096768);           // [24096768, 24113152)
    float* bs2    = ws + 24129536;                  // [24129536, 24130048)

    prep_kernel<<<386, 256, 0, stream>>>(Wh, Wx, bx, bh, WhT, WxT, bs2);
    conv_kernel<<<B_ * WN_, 256, 0, stream>>>(x, w1, b1, w2, b2, pw, pb, Hs_bf);
    xcwx_kernel<<<B_ * WN_, 256, 0, stream>>>(Hs_bf, proto, WxT, bs2,
                                              S_bf, XWx, Hsm);
    corr_kernel<<<B_ * WN_, 256, 0, stream>>>(x, S_bf, An_bf);
    scan_kernel<<<B_, 1024, 0, stream>>>(An_bf, XWx, WhT, Hsqm);
    final_kernel<<<B_, 128, 0, stream>>>(Hsqm, Hsm, q_t, q_s, clw, clb,
                                         (float*)d_out);
}

// Round 10
// 702.099 us; speedup vs baseline: 4.5462x; 1.0017x over previous
//
#include <hip/hip_runtime.h>

#define B_   16
#define T_   3000
#define N_   128
#define WIN_ 30
#define WN_  100
#define D_   64
#define HID_ 128
#define K_   32
#define G4_  512   // 4*HID_

typedef unsigned short us;
typedef __attribute__((ext_vector_type(8))) short short8;
typedef __attribute__((ext_vector_type(4))) short short4v;
typedef __attribute__((ext_vector_type(4))) float floatx4;

__device__ __forceinline__ us f2bf(float f) {
    unsigned u = __float_as_uint(f);
    u += 0x7fffu + ((u >> 16) & 1u);
    return (us)(u >> 16);
}
__device__ __forceinline__ float bf2f(us h) {
    return __uint_as_float(((unsigned)h) << 16);
}
__device__ __forceinline__ float sigf(float x) { return 1.f / (1.f + __expf(-x)); }
__device__ __forceinline__ float tanhfast(float x) { return 2.f / (1.f + __expf(-2.f * x)) - 1.f; }
// Barrier WITHOUT vmcnt drain: LDS ordering only.  Safe when all global
// loads/stores crossing it are wave-private (consumed by issuing wave).
__device__ __forceinline__ void ldsbar() {
    __asm__ volatile("s_waitcnt lgkmcnt(0)\n\ts_barrier" ::: "memory");
}

// ---------------------------------------------------------------------------
// Kernel 1: SignalRep conv (unchanged from round 9 — verified).
// ---------------------------------------------------------------------------
__global__ __launch_bounds__(256) void conv_kernel(
    const float* __restrict__ x, const float* __restrict__ w1,
    const float* __restrict__ b1, const float* __restrict__ w2,
    const float* __restrict__ b2, const float* __restrict__ pw,
    const float* __restrict__ pb, us* __restrict__ Hs)
{
    __shared__ __align__(16) float xs_all[30 * 128];   // [t][n]
    __shared__ __align__(16) us h1s[8 * 36 * 40];      // [s][t'][ci]
    __shared__ __align__(16) float Ms[128 * 40];       // [n][co] means (/30)
    __shared__ __align__(16) us PwT_hi[64 * 40];       // [d][co]
    __shared__ __align__(16) us PwT_lo[64 * 40];
    const int tid = threadIdx.x;
    const int win = blockIdx.x;
    const int b = win / WN_, w = win - b * WN_;
    const float* xb = x + ((size_t)b * T_ + (size_t)w * WIN_) * N_;
    const int lane = tid & 63, wv = tid >> 6;
    const int l15 = lane & 15, quad = lane >> 4;

    {
        const float4* xb4 = (const float4*)xb;
        float4* xs4 = (float4*)xs_all;
        for (int i = tid; i < 960; i += 256) xs4[i] = xb4[i];
    }
    for (int i = tid; i < 2048; i += 256) {
        int co = i >> 6, d = i & 63;
        float v = pw[i];
        us hi = f2bf(v);
        PwT_hi[d * 40 + co] = hi;
        PwT_lo[d * 40 + co] = f2bf(v - bf2f(hi));
    }
    for (int i = tid; i < 1920; i += 256) {            // zero h1 pad rows
        int s = i / 240, r = i % 240;
        int ti = r / 40, c = r % 40;
        int tp = (ti < 2) ? ti : (30 + ti);
        h1s[(s * 36 + tp) * 40 + c] = 0;
    }
    short8 whf[2][5];
    #pragma unroll
    for (int cot = 0; cot < 2; cot++)
        #pragma unroll
        for (int dk = 0; dk < 5; dk++)
            #pragma unroll
            for (int j = 0; j < 8; j++)
                whf[cot][dk][j] = (short)f2bf(w2[(cot * 16 + l15) * 160 + (quad * 8 + j) * 5 + dk]);
    const float b2c0 = b2[l15], b2c1 = b2[16 + l15];
    const int ci2 = lane & 15, th = (lane >> 4) & 1, sloc = lane >> 5;
    float w1ra[5], w1rb[5];
    #pragma unroll
    for (int k = 0; k < 5; k++) {
        w1ra[k] = w1[(2 * ci2) * 5 + k];
        w1rb[k] = w1[(2 * ci2 + 1) * 5 + k];
    }
    const float b1a = b1[2 * ci2], b1b = b1[2 * ci2 + 1];
    float pbv[4];
    #pragma unroll
    for (int nt = 0; nt < 4; nt++) pbv[nt] = pb[nt * 16 + l15];
    ldsbar();

    for (int g = 0; g < 16; g++) {
        const int n1 = g * 8 + wv * 2 + sloc;
        {
            float xr[19];
            #pragma unroll
            for (int u = 0; u < 19; u++) {
                int p = th * 15 - 2 + u;
                xr[u] = ((unsigned)p < 30u) ? xs_all[p * 128 + n1] : 0.f;
            }
            const int rbase = (wv * 2 + sloc) * 36 + 2 + th * 15;
            #pragma unroll
            for (int tt = 0; tt < 15; tt++) {
                float aa = b1a, ab = b1b;
                #pragma unroll
                for (int k = 0; k < 5; k++) {
                    aa += xr[tt + k] * w1ra[k];
                    ab += xr[tt + k] * w1rb[k];
                }
                unsigned pk = (unsigned)f2bf(fmaxf(aa, 0.f))
                            | ((unsigned)f2bf(fmaxf(ab, 0.f)) << 16);
                *(unsigned*)&h1s[(rbase + tt) * 40 + 2 * ci2] = pk;
            }
        }
        __builtin_amdgcn_wave_barrier();
        #pragma unroll
        for (int s2 = 0; s2 < 2; s2++) {
            const int sl = wv * 2 + s2;
            const int nn = g * 8 + sl;
            floatx4 c00 = {b2c0, b2c0, b2c0, b2c0};
            floatx4 c01 = {b2c1, b2c1, b2c1, b2c1};
            floatx4 c10 = {b2c0, b2c0, b2c0, b2c0};
            floatx4 c11 = {b2c1, b2c1, b2c1, b2c1};
            #pragma unroll
            for (int dk = 0; dk < 5; dk++) {
                short8 a0 = *(const short8*)&h1s[(sl * 36 + l15 + dk) * 40 + quad * 8];
                short8 a1 = *(const short8*)&h1s[(sl * 36 + 16 + l15 + dk) * 40 + quad * 8];
                c00 = __builtin_amdgcn_mfma_f32_16x16x32_bf16(a0, whf[0][dk], c00, 0, 0, 0);
                c01 = __builtin_amdgcn_mfma_f32_16x16x32_bf16(a0, whf[1][dk], c01, 0, 0, 0);
                c10 = __builtin_amdgcn_mfma_f32_16x16x32_bf16(a1, whf[0][dk], c10, 0, 0, 0);
                c11 = __builtin_amdgcn_mfma_f32_16x16x32_bf16(a1, whf[1][dk], c11, 0, 0, 0);
            }
            float s0 = 0.f, s1 = 0.f;
            #pragma unroll
            for (int r = 0; r < 4; r++) {
                s0 += fmaxf(c00[r], 0.f);
                s1 += fmaxf(c01[r], 0.f);
                float m0 = (quad * 4 + r < 14) ? fmaxf(c10[r], 0.f) : 0.f;
                float m1 = (quad * 4 + r < 14) ? fmaxf(c11[r], 0.f) : 0.f;
                s0 += m0; s1 += m1;
            }
            s0 += __shfl_xor(s0, 16); s0 += __shfl_xor(s0, 32);
            s1 += __shfl_xor(s1, 16); s1 += __shfl_xor(s1, 32);
            if (quad == 0) {
                Ms[nn * 40 + l15]      = s0 * (1.f / 30.f);
                Ms[nn * 40 + 16 + l15] = s1 * (1.f / 30.f);
            }
        }
        __builtin_amdgcn_wave_barrier();
    }
    ldsbar();
    short8 Ah[2], Al[2];
    #pragma unroll
    for (int i = 0; i < 2; i++) {
        const int mt = wv * 2 + i;
        float4 v0 = *(const float4*)&Ms[(mt * 16 + l15) * 40 + quad * 8];
        float4 v1 = *(const float4*)&Ms[(mt * 16 + l15) * 40 + quad * 8 + 4];
        float vv[8] = {v0.x, v0.y, v0.z, v0.w, v1.x, v1.y, v1.z, v1.w};
        #pragma unroll
        for (int j = 0; j < 8; j++) {
            us hi = f2bf(vv[j]);
            Ah[i][j] = (short)hi;
            Al[i][j] = (short)f2bf(vv[j] - bf2f(hi));
        }
    }
    us* hp = Hs + (size_t)win * 8192;
    #pragma unroll
    for (int id = 0; id < 8; id++) {
        const int i = id >> 2, nt = id & 3;
        short8 Bh = *(const short8*)&PwT_hi[(nt * 16 + l15) * 40 + quad * 8];
        short8 Bl = *(const short8*)&PwT_lo[(nt * 16 + l15) * 40 + quad * 8];
        floatx4 a = {pbv[nt], pbv[nt], pbv[nt], pbv[nt]};
        a = __builtin_amdgcn_mfma_f32_16x16x32_bf16(Ah[i], Bh, a, 0, 0, 0);
        a = __builtin_amdgcn_mfma_f32_16x16x32_bf16(Al[i], Bh, a, 0, 0, 0);
        a = __builtin_amdgcn_mfma_f32_16x16x32_bf16(Ah[i], Bl, a, 0, 0, 0);
        const int mt = wv * 2 + i;
        #pragma unroll
        for (int r = 0; r < 4; r++)
            hp[(mt * 16 + quad * 4 + r) * 64 + nt * 16 + l15] = f2bf(a[r]);
    }
}

// ---------------------------------------------------------------------------
// Kernel 2: prep — gate-MAJOR jj (identity: jg == jj).  WhT[jj][h] bf16,
// WxT[jj][d] bf16, bs2[jj] = bx+bh.
// ---------------------------------------------------------------------------
__global__ __launch_bounds__(256) void prep_kernel(
    const float* __restrict__ Wh, const float* __restrict__ Wx,
    const float* __restrict__ bx, const float* __restrict__ bh,
    us* __restrict__ WhT, us* __restrict__ WxT, float* __restrict__ bs2)
{
    int i = blockIdx.x * 256 + threadIdx.x;
    if (i < 65536) {
        int jj = i >> 7, h = i & 127;
        WhT[i] = f2bf(Wh[h * G4_ + jj]);
    } else if (i < 98304) {
        int j = i - 65536;
        int jj = j >> 6, d = j & 63;
        WxT[j] = f2bf(Wx[d * G4_ + jj]);
    } else if (i < 98816) {
        int jj = i - 98304;
        bs2[jj] = bx[jj] + bh[jj];
    }
}

// ---------------------------------------------------------------------------
// Kernel 3: fused per-window — softmax S, Hsm, Xc = S^T@Hs,
// XWxb = Xc@Wx + bias (swizzled C-frag layout).  (code identical to r9;
// jj meaning is now plain/gate-major via prep).
// ---------------------------------------------------------------------------
__global__ __launch_bounds__(256) void xcwx_kernel(
    const us* __restrict__ Hs, const float* __restrict__ proto,
    const us* __restrict__ WxT, const float* __restrict__ bs2,
    us* __restrict__ S_out, us* __restrict__ XWx, float* __restrict__ Hsm)
{
    __shared__ __align__(16) us Hnd[128 * 72];
    __shared__ __align__(16) us HsT[64 * 136];
    __shared__ __align__(16) us PT_hi[32 * 72];
    __shared__ __align__(16) us SsT_hi[32 * 136];
    __shared__ __align__(16) us XcA_hi[32 * 72];
    __shared__ float bias[512];
    const int tid = threadIdx.x;
    const int win = blockIdx.x;
    const int lane = tid & 63, wv = tid >> 6;
    const int l15 = lane & 15, quad = lane >> 4;

    {
        const uint2* hp = (const uint2*)(Hs + (size_t)win * 8192);
        #pragma unroll
        for (int it = 0; it < 8; it++) {
            int idx4 = tid + 256 * it;
            int n = idx4 >> 4, dpos = (idx4 & 15) * 4;
            uint2 v = hp[idx4];
            *(uint2*)&Hnd[n * 72 + dpos] = v;
            us s0 = (us)(v.x & 0xffff), s1 = (us)(v.x >> 16);
            us s2 = (us)(v.y & 0xffff), s3 = (us)(v.y >> 16);
            HsT[(dpos + 0) * 136 + n] = s0;
            HsT[(dpos + 1) * 136 + n] = s1;
            HsT[(dpos + 2) * 136 + n] = s2;
            HsT[(dpos + 3) * 136 + n] = s3;
        }
        for (int i = tid; i < 2048; i += 256) {
            int k = i >> 6, d = i & 63;
            PT_hi[k * 72 + d] = f2bf(proto[i]);
        }
        for (int i = tid; i < 512; i += 256) bias[i] = bs2[i];
    }
    __syncthreads();
    floatx4 lg[2][2];
    #pragma unroll
    for (int p = 0; p < 2; p++) {
        const int mt = wv * 2 + p;
        #pragma unroll
        for (int kt = 0; kt < 2; kt++) {
            floatx4 a = {0.f, 0.f, 0.f, 0.f};
            #pragma unroll
            for (int kb = 0; kb < 2; kb++) {
                short8 af  = *(const short8*)&Hnd[(mt * 16 + l15) * 72 + kb * 32 + quad * 8];
                short8 bhf = *(const short8*)&PT_hi[(kt * 16 + l15) * 72 + kb * 32 + quad * 8];
                a = __builtin_amdgcn_mfma_f32_16x16x32_bf16(af, bhf, a, 0, 0, 0);
            }
            lg[p][kt] = a;
        }
    }
    #pragma unroll
    for (int p = 0; p < 2; p++) {
        #pragma unroll
        for (int r = 0; r < 4; r++) {
            float v0 = lg[p][0][r], v1 = lg[p][1][r];
            float m = fmaxf(v0, v1);
            #pragma unroll
            for (int off = 8; off; off >>= 1) m = fmaxf(m, __shfl_xor(m, off));
            float e0 = expf(v0 - m), e1 = expf(v1 - m);
            float s = e0 + e1;
            #pragma unroll
            for (int off = 8; off; off >>= 1) s += __shfl_xor(s, off);
            float inv = 1.f / s;
            e0 *= inv; e1 *= inv;
            const int n = (wv * 2 + p) * 16 + quad * 4 + r;
            us h0 = f2bf(e0), h1 = f2bf(e1);
            SsT_hi[l15 * 136 + n]        = h0;
            SsT_hi[(16 + l15) * 136 + n] = h1;
            S_out[(size_t)win * 4096 + n * 32 + l15]      = h0;
            S_out[(size_t)win * 4096 + n * 32 + 16 + l15] = h1;
        }
    }
    __syncthreads();
    {
        const int d = tid >> 2, seg = tid & 3;
        float acc = 0.f;
        const unsigned* hp2 = (const unsigned*)&HsT[d * 136 + seg * 32];
        #pragma unroll
        for (int q = 0; q < 16; q++) {
            unsigned v = hp2[q];
            acc += bf2f((us)(v & 0xffff)) + bf2f((us)(v >> 16));
        }
        acc += __shfl_xor(acc, 1);
        acc += __shfl_xor(acc, 2);
        if (seg == 0) Hsm[(size_t)win * 64 + d] = acc * (1.f / 128.f);
    }
    #pragma unroll
    for (int p = 0; p < 2; p++) {
        const int id = wv * 2 + p, mt = id >> 2, nt = id & 3;
        floatx4 a = {0.f, 0.f, 0.f, 0.f};
        #pragma unroll
        for (int kb = 0; kb < 4; kb++) {
            short8 ah = *(const short8*)&SsT_hi[(mt * 16 + l15) * 136 + kb * 32 + quad * 8];
            short8 bf_ = *(const short8*)&HsT[(nt * 16 + l15) * 136 + kb * 32 + quad * 8];
            a = __builtin_amdgcn_mfma_f32_16x16x32_bf16(ah, bf_, a, 0, 0, 0);
        }
        #pragma unroll
        for (int r = 0; r < 4; r++) {
            const int k = mt * 16 + quad * 4 + r, d = nt * 16 + l15;
            XcA_hi[k * 72 + d] = f2bf(a[r]);
        }
    }
    __syncthreads();
    short8 Ah[2][2];
    #pragma unroll
    for (int mt = 0; mt < 2; mt++)
        #pragma unroll
        for (int kb = 0; kb < 2; kb++)
            Ah[mt][kb] = *(const short8*)&XcA_hi[(mt * 16 + l15) * 72 + kb * 32 + quad * 8];
    #pragma unroll 1
    for (int i = 0; i < 8; i++) {
        const int nt = wv + 4 * i;
        const float bv = bias[nt * 16 + l15];
        floatx4 acc[2];
        acc[0] = (floatx4){bv, bv, bv, bv};
        acc[1] = (floatx4){bv, bv, bv, bv};
        #pragma unroll
        for (int kb = 0; kb < 2; kb++) {
            short8 wh8 = *(const short8*)&WxT[(size_t)(nt * 16 + l15) * 64 + kb * 32 + quad * 8];
            #pragma unroll
            for (int mt = 0; mt < 2; mt++)
                acc[mt] = __builtin_amdgcn_mfma_f32_16x16x32_bf16(Ah[mt][kb], wh8, acc[mt], 0, 0, 0);
        }
        #pragma unroll
        for (int mt = 0; mt < 2; mt++) {
            uint2 pk;
            pk.x = (unsigned)f2bf(acc[mt][0]) | ((unsigned)f2bf(acc[mt][1]) << 16);
            pk.y = (unsigned)f2bf(acc[mt][2]) | ((unsigned)f2bf(acc[mt][3]) << 16);
            ((uint2*)XWx)[((size_t)win * 64 + mt * 32 + nt) * 64 + lane] = pk;
        }
    }
}

// ---------------------------------------------------------------------------
// Kernel 4: corr -> AS -> Ac -> normalize -> An, THEN AXWx = An @ XWxb
// (in-place overwrite of the XWx slot) — moves the recurrence-independent
// An-multiply out of the 16-CU scan onto all 256 CUs.
// ---------------------------------------------------------------------------
__global__ __launch_bounds__(256) void corr_kernel(
    const float* __restrict__ x, const us* __restrict__ S_bf,
    us* __restrict__ An, us* __restrict__ XWx)
{
    __shared__ __align__(16) float xs[30 * 128];    // aliased by XA
    __shared__ __align__(16) us SsT[32 * 136];
    __shared__ __align__(16) us pool[21760];        // CB | AST, later XWT
    __shared__ float Acs[32 * 33];
    __shared__ __align__(16) us AnL[32 * 40];
    __shared__ float sinv[128];
    __shared__ float dinv[32];
    us* XA  = (us*)xs;                              // [128][40]
    us* CB  = pool;                                 // [128][136]
    us* AST = pool + 17408;                         // [32][136]
    us* XWT = pool;                                 // [512][40]
    const int tid = threadIdx.x;
    const int win = blockIdx.x;
    const int b = win / WN_, w = win - b * WN_;
    const float* xb = x + ((size_t)b * T_ + (size_t)w * WIN_) * N_;
    const int lane = tid & 63, wv = tid >> 6;
    const int l15 = lane & 15, quad = lane >> 4;
    const float inv29 = 1.f / (WIN_ - 1 + 1e-8f);

    for (int i = tid; i < 3840; i += 256) xs[i] = xb[i];
    for (int i = tid; i < 4096; i += 256) {
        int n = i >> 5, k = i & 31;
        SsT[k * 136 + n] = S_bf[(size_t)win * 4096 + i];
    }
    __syncthreads();
    float xr[30];
    if (tid < 128) {
        const int n = tid;
        float mean = 0.f;
        #pragma unroll
        for (int l = 0; l < 30; l++) { xr[l] = xs[l * 128 + n]; mean += xr[l]; }
        mean *= (1.f / 30.f);
        float var = 0.f;
        #pragma unroll
        for (int l = 0; l < 30; l++) {
            float v = xr[l] - mean;
            var += v * v;
            xr[l] = v;
        }
        var *= inv29;
        sinv[tid] = rsqrtf(fmaxf(var, 1e-8f));
    }
    __syncthreads();
    if (tid < 128) {
        #pragma unroll
        for (int l = 0; l < 30; l++) XA[tid * 40 + l] = f2bf(xr[l]);
        XA[tid * 40 + 30] = 0; XA[tid * 40 + 31] = 0;
    }
    __syncthreads();
    #pragma unroll 1
    for (int q = 0; q < 16; q++) {
        const int id = wv * 16 + q, mt = id >> 3, nt = id & 7;
        short8 a = *(const short8*)&XA[(mt * 16 + l15) * 40 + quad * 8];
        short8 bb = *(const short8*)&XA[(nt * 16 + l15) * 40 + quad * 8];
        floatx4 d = {0.f, 0.f, 0.f, 0.f};
        d = __builtin_amdgcn_mfma_f32_16x16x32_bf16(a, bb, d, 0, 0, 0);
        const int m = nt * 16 + l15;
        const float sm = sinv[m];
        #pragma unroll
        for (int r = 0; r < 4; r++) {
            const int n = mt * 16 + quad * 4 + r;
            float v = d[r] * inv29 * sinv[n] * sm;
            if (n == m) v = 1.f;
            CB[n * 136 + m] = f2bf(v);
        }
    }
    __syncthreads();
    #pragma unroll 1
    for (int q = 0; q < 4; q++) {
        const int id = wv * 4 + q, mt = id >> 1, lt = id & 1;
        floatx4 d = {0.f, 0.f, 0.f, 0.f};
        #pragma unroll
        for (int kb = 0; kb < 4; kb++) {
            short8 a = *(const short8*)&CB[(mt * 16 + l15) * 136 + kb * 32 + quad * 8];
            short8 bb = *(const short8*)&SsT[(lt * 16 + l15) * 136 + kb * 32 + quad * 8];
            d = __builtin_amdgcn_mfma_f32_16x16x32_bf16(a, bb, d, 0, 0, 0);
        }
        const int l = lt * 16 + l15;
        #pragma unroll
        for (int r = 0; r < 4; r++)
            AST[l * 136 + mt * 16 + quad * 4 + r] = f2bf(d[r]);
    }
    __syncthreads();
    {
        const int kt = wv >> 1, lt = wv & 1;
        floatx4 d = {0.f, 0.f, 0.f, 0.f};
        #pragma unroll
        for (int kb = 0; kb < 4; kb++) {
            short8 a = *(const short8*)&SsT[(kt * 16 + l15) * 136 + kb * 32 + quad * 8];
            short8 bb = *(const short8*)&AST[(lt * 16 + l15) * 136 + kb * 32 + quad * 8];
            d = __builtin_amdgcn_mfma_f32_16x16x32_bf16(a, bb, d, 0, 0, 0);
        }
        #pragma unroll
        for (int r = 0; r < 4; r++)
            Acs[(kt * 16 + quad * 4 + r) * 33 + lt * 16 + l15] = d[r];
    }
    __syncthreads();
    float symv[4];
    {
        int l = tid & 31, kb = tid >> 5;
        for (int r = 0; r < 4; r++) {
            int k = kb + 8 * r;
            symv[r] = 0.5f * (Acs[k * 33 + l] + Acs[l * 33 + k]) + ((k == l) ? 1.f : 0.f);
        }
    }
    __syncthreads();
    {
        int l = tid & 31, kb = tid >> 5;
        for (int r = 0; r < 4; r++) Acs[(kb + 8 * r) * 33 + l] = symv[r];
    }
    __syncthreads();
    if (tid < K_) {
        float s = 0.f;
        for (int l = 0; l < K_; l++) s += Acs[tid * 33 + l];
        dinv[tid] = rsqrtf(fmaxf(s, 1e-8f));
    }
    __syncthreads();
    us* Anw = An + (size_t)win * K_ * K_;
    for (int i = tid; i < K_ * K_; i += 256) {
        int k = i >> 5, l = i & 31;
        us v = f2bf(dinv[k] * Acs[k * 33 + l] * dinv[l]);
        Anw[i] = v;
        AnL[k * 40 + l] = v;
    }
    __syncthreads();
    // ---- stage XWxb (swizzled uint2) -> XWT[jj][m] (pool reuse) ----
    {
        const uint2* xw2 = (const uint2*)XWx + (size_t)win * 4096;
        for (int i = tid; i < 4096; i += 256) {
            uint2 v = xw2[i];
            int tile = i >> 6, lane2 = i & 63;
            int mt2 = tile >> 5, nt2 = tile & 31;
            int jj = nt2 * 16 + (lane2 & 15);
            int m0 = mt2 * 16 + (lane2 >> 4) * 4;
            *(uint2*)&XWT[jj * 40 + m0] = v;
        }
    }
    __syncthreads();
    // ---- AXWx = An @ XWxb, stored back in-place (swizzled) ----
    short8 anA[2];
    anA[0] = *(const short8*)&AnL[l15 * 40 + quad * 8];
    anA[1] = *(const short8*)&AnL[(16 + l15) * 40 + quad * 8];
    #pragma unroll 1
    for (int i = 0; i < 8; i++) {
        const int nt = wv + 4 * i;
        short8 bfr = *(const short8*)&XWT[(nt * 16 + l15) * 40 + quad * 8];
        #pragma unroll
        for (int mt2 = 0; mt2 < 2; mt2++) {
            floatx4 a = {0.f, 0.f, 0.f, 0.f};
            a = __builtin_amdgcn_mfma_f32_16x16x32_bf16(anA[mt2], bfr, a, 0, 0, 0);
            uint2 pk;
            pk.x = (unsigned)f2bf(a[0]) | ((unsigned)f2bf(a[1]) << 16);
            pk.y = (unsigned)f2bf(a[2]) | ((unsigned)f2bf(a[3]) << 16);
            ((uint2*)XWx)[((size_t)win * 64 + mt2 * 32 + nt) * 64 + lane] = pk;
        }
    }
}

// ---------------------------------------------------------------------------
// Kernel 5: GCLSTM scan, restructured: g = AXWx + (An@Hp)@Wh.
// 16 blocks x 1024 thr.  Wave (mt = wv>>3, hb = wv&7) owns gates 0-3 of its
// (mt, hb) tile -> LSTM fully in-lane.  P = An@Hp is the only transpose
// (4K elems vs 16K before); GEMM2-with-An is gone (precomputed in corr).
// ---------------------------------------------------------------------------
__global__ __launch_bounds__(1024) void scan_kernel(
    const us* __restrict__ An_bf,   // [bt][k][m]
    const us* __restrict__ AXWx,    // swizzled C-frag layout (gate-major jj)
    const us* __restrict__ WhT,     // [jj][h]
    float* __restrict__ Hsqm)       // zero-initialized; atomicAdd
{
    __shared__ __align__(16) us HpT[2][128 * 40];   // [h][k]
    __shared__ __align__(16) us P_lds[32 * 136];    // [k][h]

    const int tid  = threadIdx.x;
    const int lane = tid & 63;
    const int wv   = tid >> 6;          // 0..15
    const int b    = blockIdx.x;
    const int l15  = lane & 15, quad = lane >> 4;
    const int mt   = wv >> 3, hb = wv & 7;

    // Wh B-fragments: 4 gates x 4 kb = 64 VGPR
    short8 Bw[4][4];
    #pragma unroll
    for (int g4 = 0; g4 < 4; g4++) {
        const int jj = g4 * 128 + hb * 16 + l15;
        #pragma unroll
        for (int kb = 0; kb < 4; kb++)
            Bw[g4][kb] = *(const short8*)&WhT[(size_t)jj * 128 + kb * 32 + quad * 8];
    }
    // state: cells (k = mt*16 + quad*4 + r, h = hb*16 + l15)
    float Cst[4] = {0.f, 0.f, 0.f, 0.f};
    float Hst[4] = {0.f, 0.f, 0.f, 0.f};
    float H2t[4] = {0.f, 0.f, 0.f, 0.f};

    for (int i = tid; i < 2560; i += 1024) ((unsigned*)HpT[0])[i] = 0;

    const size_t bt0 = (size_t)b * WN_;
    const uint2* xp = (const uint2*)AXWx;
    uint2 xw[4];
    #pragma unroll
    for (int g4 = 0; g4 < 4; g4++)
        xw[g4] = xp[(bt0 * 64 + mt * 32 + g4 * 8 + hb) * 64 + lane];

    #pragma unroll 1
    for (int t = 0; t < WN_; t++) {
        const int buf = t & 1;
        ldsbar();                                   // HpT[buf] ready
        // ---- P = An @ Hp (1 MFMA/wave) ----
        short8 anf = *(const short8*)&An_bf[(bt0 + t) * 1024 + (mt * 16 + l15) * 32 + quad * 8];
        short8 hpB = *(const short8*)&HpT[buf][(hb * 16 + l15) * 40 + quad * 8];
        floatx4 Pa = {0.f, 0.f, 0.f, 0.f};
        Pa = __builtin_amdgcn_mfma_f32_16x16x32_bf16(anf, hpB, Pa, 0, 0, 0);
        #pragma unroll
        for (int r = 0; r < 4; r++)
            P_lds[(mt * 16 + quad * 4 + r) * 136 + hb * 16 + l15] = f2bf(Pa[r]);
        // ---- g acc init from AXWx; then prefetch t+1 ----
        floatx4 gacc[4];
        #pragma unroll
        for (int g4 = 0; g4 < 4; g4++) {
            gacc[g4][0] = bf2f((us)(xw[g4].x & 0xffff));
            gacc[g4][1] = bf2f((us)(xw[g4].x >> 16));
            gacc[g4][2] = bf2f((us)(xw[g4].y & 0xffff));
            gacc[g4][3] = bf2f((us)(xw[g4].y >> 16));
        }
        {
            const int tn = (t + 1 < WN_) ? (t + 1) : (WN_ - 1);
            #pragma unroll
            for (int g4 = 0; g4 < 4; g4++)
                xw[g4] = xp[((bt0 + tn) * 64 + mt * 32 + g4 * 8 + hb) * 64 + lane];
        }
        ldsbar();                                   // P ready
        // ---- g += P @ Wh' ----
        #pragma unroll
        for (int kb = 0; kb < 4; kb++) {
            short8 pA = *(const short8*)&P_lds[(mt * 16 + l15) * 136 + kb * 32 + quad * 8];
            #pragma unroll
            for (int g4 = 0; g4 < 4; g4++)
                gacc[g4] = __builtin_amdgcn_mfma_f32_16x16x32_bf16(pA, Bw[g4][kb], gacc[g4], 0, 0, 0);
        }
        // ---- gates + state (fully in-lane) ----
        #pragma unroll
        for (int r = 0; r < 4; r++) {
            float gi = gacc[0][r], gf = gacc[1][r];
            float go = gacc[2][r], gc = gacc[3][r];
            float cn = sigf(gf) * Cst[r] + sigf(gi) * tanhfast(gc);
            float hn = sigf(go) * tanhfast(cn);
            Cst[r] = cn;
            H2t[r] = Hst[r];
            Hst[r] = hn;
        }
        // ---- Hsqm partial (sum over this wave's 16 k) ----
        {
            float s = Hst[0] + Hst[1] + Hst[2] + Hst[3];
            s += __shfl_xor(s, 16); s += __shfl_xor(s, 32);
            if (quad == 0)
                atomicAdd(&Hsqm[(bt0 + t) * HID_ + hb * 16 + l15], s * (1.f / 32.f));
        }
        // ---- HpT(t+1): packed b64 write [h][4 consecutive k] ----
        if (t + 1 < WN_) {
            const float dninv = (t + 1 == 1) ? 0.5f : (1.f / 3.f);
            short4v hv;
            #pragma unroll
            for (int r = 0; r < 4; r++)
                hv[r] = (short)f2bf((2.f * Hst[r] + H2t[r]) * dninv);
            *(short4v*)&HpT[buf ^ 1][(hb * 16 + l15) * 40 + mt * 16 + quad * 4] = hv;
        }
    }
}

// ---------------------------------------------------------------------------
// Kernel 6: temporal attention pooling + classifier (unchanged).
// ---------------------------------------------------------------------------
__global__ __launch_bounds__(128) void final_kernel(
    const float* __restrict__ Hsqm, const float* __restrict__ Hsm,
    const float* __restrict__ q_t, const float* __restrict__ q_s,
    const float* __restrict__ cls_w, const float* __restrict__ cls_b,
    float* __restrict__ out)
{
    __shared__ float red[128];
    __shared__ float wt[WN_];
    const int b = blockIdx.x, tid = threadIdx.x;
    float v = q_t[tid];
    red[tid] = v * v;
    __syncthreads();
    for (int off = 64; off; off >>= 1) {
        if (tid < off) red[tid] += red[tid + off];
        __syncthreads();
    }
    const float qtn = sqrtf(red[0]) + 1e-8f;
    __syncthreads();
    float v2 = (tid < D_) ? q_s[tid] : 0.f;
    red[tid] = v2 * v2;
    __syncthreads();
    for (int off = 64; off; off >>= 1) {
        if (tid < off) red[tid] += red[tid + off];
        __syncthreads();
    }
    const float qsn = sqrtf(red[0]) + 1e-8f;
    __syncthreads();
    float sc_t = -1e30f;
    if (tid < WN_) {
        float s = 0.f;
        const float* zr = Hsqm + ((size_t)b * WN_ + tid) * HID_;
        for (int h = 0; h < HID_; h++) s += zr[h] * q_t[h];
        sc_t = s / qtn;
    }
    red[tid] = sc_t;
    __syncthreads();
    for (int off = 64; off; off >>= 1) {
        if (tid < off) red[tid] = fmaxf(red[tid], red[tid + off]);
        __syncthreads();
    }
    const float mt_ = red[0];
    __syncthreads();
    float e_t = (tid < WN_) ? expf(sc_t - mt_) : 0.f;
    red[tid] = e_t;
    __syncthreads();
    for (int off = 64; off; off >>= 1) {
        if (tid < off) red[tid] += red[tid + off];
        __syncthreads();
    }
    const float sinv_t = 1.f / red[0];
    __syncthreads();
    if (tid < WN_) wt[tid] = e_t * sinv_t;
    __syncthreads();
    float part = 0.f;
    {
        float z = 0.f;
        for (int w = 0; w < WN_; w++)
            z += wt[w] * Hsqm[((size_t)b * WN_ + w) * HID_ + tid];
        part += z * cls_w[tid];
    }
    __syncthreads();
    float sc_s = -1e30f;
    if (tid < WN_) {
        float s = 0.f;
        const float* zr = Hsm + ((size_t)b * WN_ + tid) * D_;
        for (int dd = 0; dd < D_; dd++) s += zr[dd] * q_s[dd];
        sc_s = s / qsn;
    }
    red[tid] = sc_s;
    __syncthreads();
    for (int off = 64; off; off >>= 1) {
        if (tid < off) red[tid] = fmaxf(red[tid], red[tid + off]);
        __syncthreads();
    }
    const float ms_ = red[0];
    __syncthreads();
    float e_s = (tid < WN_) ? expf(sc_s - ms_) : 0.f;
    red[tid] = e_s;
    __syncthreads();
    for (int off = 64; off; off >>= 1) {
        if (tid < off) red[tid] += red[tid + off];
        __syncthreads();
    }
    const float sinv_s = 1.f / red[0];
    __syncthreads();
    if (tid < WN_) wt[tid] = e_s * sinv_s;
    __syncthreads();
    if (tid < D_) {
        float z = 0.f;
        for (int w = 0; w < WN_; w++)
            z += wt[w] * Hsm[((size_t)b * WN_ + w) * D_ + tid];
        part += z * cls_w[HID_ + tid];
    }
    red[tid] = part;
    __syncthreads();
    for (int off = 64; off; off >>= 1) {
        if (tid < off) red[tid] += red[tid + off];
        __syncthreads();
    }
    if (tid == 0) out[b] = 1.f / (1.f + expf(-(red[0] + cls_b[0])));
}

// ---------------------------------------------------------------------------
extern "C" void kernel_launch(void* const* d_in, const int* in_sizes, int n_in,
                              void* d_out, int out_size, void* d_ws, size_t ws_size,
                              hipStream_t stream)
{
    (void)in_sizes; (void)n_in; (void)out_size; (void)ws_size;
    const float* x     = (const float*)d_in[0];
    const float* w1    = (const float*)d_in[1];
    const float* b1    = (const float*)d_in[2];
    const float* w2    = (const float*)d_in[3];
    const float* b2    = (const float*)d_in[4];
    const float* pw    = (const float*)d_in[5];
    const float* pb    = (const float*)d_in[6];
    const float* proto = (const float*)d_in[7];
    const float* Wx    = (const float*)d_in[8];
    const float* bx    = (const float*)d_in[9];
    const float* Wh    = (const float*)d_in[10];
    const float* bh    = (const float*)d_in[11];
    const float* q_t   = (const float*)d_in[12];
    const float* q_s   = (const float*)d_in[13];
    const float* clw   = (const float*)d_in[14];
    const float* clb   = (const float*)d_in[15];

    float* ws = (float*)d_ws;
    us*    Hs_bf  = (us*)d_ws;                      // [0, 6553600)
    us*    S_bf   = (us*)(ws + 6553600);            // [6553600, 9830400)
    us*    XWx    = (us*)(ws + 9830400);            // XWxb, then AXWx in place
    us*    An_bf  = (us*)(ws + 22937600);           // [22937600, 23756800)
    float* Hsm    = ws + 23756800;                  // [23756800, 23859200)
    float* Hsqm   = ws + 23859200;                  // [23859200, 24064000)
    us*    WhT    = (us*)(ws + 24064000);           // [24064000, 24096768)
    us*    WxT    = (us*)(ws + 24096768);           // [24096768, 24113152)
    float* bs2    = ws + 24129536;                  // [24129536, 24130048)

    hipMemsetAsync(Hsqm, 0, (size_t)B_ * WN_ * HID_ * sizeof(float), stream);
    prep_kernel<<<386, 256, 0, stream>>>(Wh, Wx, bx, bh, WhT, WxT, bs2);
    conv_kernel<<<B_ * WN_, 256, 0, stream>>>(x, w1, b1, w2, b2, pw, pb, Hs_bf);
    xcwx_kernel<<<B_ * WN_, 256, 0, stream>>>(Hs_bf, proto, WxT, bs2,
                                              S_bf, XWx, Hsm);
    corr_kernel<<<B_ * WN_, 256, 0, stream>>>(x, S_bf, An_bf, XWx);
    scan_kernel<<<B_, 1024, 0, stream>>>(An_bf, XWx, WhT, Hsqm);
    final_kernel<<<B_, 128, 0, stream>>>(Hsqm, Hsm, q_t, q_s, clw, clb,
                                         (float*)d_out);
}